// Round 1
// baseline (1881.707 us; speedup 1.0000x reference)
//
#include <hip/hip_runtime.h>
#include <hip/hip_bf16.h>

#define IN_DIM 128
#define HID    64
#define NH     4
#define F1     256   // NH*HID
#define OUTD   64
#define NEG    0.2f

// ---------------- layer-1 GEMM: xl = x@W1l + b1l, xr = x@W1r + b1r ----------
__global__ __launch_bounds__(256) void k_gemm1(
    const float* __restrict__ x,
    const float* __restrict__ Wl, const float* __restrict__ bl,
    const float* __restrict__ Wr, const float* __restrict__ br,
    float* __restrict__ xl, float* __restrict__ xr, int n_nodes) {
  __shared__ float xs[8][IN_DIM];
  int tid = threadIdx.x;
  int node0 = blockIdx.x * 8;
  for (int i = tid; i < 8 * IN_DIM; i += 256) {
    int n = i >> 7, k = i & 127;
    xs[n][k] = x[(size_t)(node0 + n) * IN_DIM + k];
  }
  __syncthreads();
  float accl[8], accr[8];
#pragma unroll
  for (int n = 0; n < 8; n++) { accl[n] = 0.f; accr[n] = 0.f; }
  int j = tid;  // output column 0..255
  for (int k = 0; k < IN_DIM; k++) {
    float wl = Wl[k * F1 + j];
    float wr = Wr[k * F1 + j];
#pragma unroll
    for (int n = 0; n < 8; n++) {
      accl[n] = fmaf(xs[n][k], wl, accl[n]);
      accr[n] = fmaf(xs[n][k], wr, accr[n]);
    }
  }
  float blj = bl[j], brj = br[j];
#pragma unroll
  for (int n = 0; n < 8; n++) {
    xl[(size_t)(node0 + n) * F1 + j] = accl[n] + blj;
    xr[(size_t)(node0 + n) * F1 + j] = accr[n] + brj;
  }
}

// ---------------- layer-1 edge scores + segment max -------------------------
__global__ __launch_bounds__(256) void k_score1(
    const float* __restrict__ xl, const float* __restrict__ xr,
    const int* __restrict__ ei, int E, int n_nodes,
    const float* __restrict__ att, float* __restrict__ score,
    unsigned* __restrict__ mkey) {
  int tid = threadIdx.x, lane = tid & 63;
  int e = blockIdx.x * 4 + (tid >> 6);
  int Etot = E + n_nodes;
  if (e >= Etot) return;
  int s, d;
  if (e < E) { s = ei[e]; d = ei[E + e]; } else { s = e - E; d = s; }
  const float* xls = xl + (size_t)s * F1;
  const float* xrd = xr + (size_t)d * F1;
#pragma unroll
  for (int h = 0; h < NH; h++) {
    float v = xls[h * 64 + lane] + xrd[h * 64 + lane];
    v = v > 0.f ? v : NEG * v;
    float p = v * att[h * 64 + lane];
#pragma unroll
    for (int m = 32; m >= 1; m >>= 1) p += __shfl_xor(p, m, 64);
    if (lane == 0) {
      score[(size_t)e * NH + h] = p;
      unsigned u = __float_as_uint(p);
      unsigned key = (u & 0x80000000u) ? ~u : (u | 0x80000000u);
      atomicMax(&mkey[d * NH + h], key);
    }
  }
}

// ---------------- layer-1 exp + segment sum ---------------------------------
__global__ __launch_bounds__(256) void k_ex1(
    float* __restrict__ score, const unsigned* __restrict__ mkey,
    const int* __restrict__ ei, int E, int n_nodes,
    float* __restrict__ denom) {
  int idx = blockIdx.x * 256 + threadIdx.x;  // (e,h)
  int Etot = E + n_nodes;
  if (idx >= Etot * NH) return;
  int e = idx >> 2, h = idx & 3;
  int d = (e < E) ? ei[E + e] : (e - E);
  unsigned key = mkey[d * NH + h];
  unsigned u = (key & 0x80000000u) ? (key & 0x7FFFFFFFu) : ~key;
  float ex = expf(score[idx] - __uint_as_float(u));
  score[idx] = ex;
  atomicAdd(&denom[d * NH + h], ex);
}

// ---------------- layer-1 aggregation (scatter-add) -------------------------
__global__ __launch_bounds__(256) void k_agg1(
    const float* __restrict__ xl, const float* __restrict__ ex,
    const float* __restrict__ denom, const int* __restrict__ ei,
    int E, int n_nodes, float* __restrict__ out) {
  int tid = threadIdx.x, lane = tid & 63;
  int e = blockIdx.x * 4 + (tid >> 6);
  int Etot = E + n_nodes;
  if (e >= Etot) return;
  int s, d;
  if (e < E) { s = ei[e]; d = ei[E + e]; } else { s = e - E; d = s; }
  const float* xls = xl + (size_t)s * F1;
  float* od = out + (size_t)d * F1;
#pragma unroll
  for (int h = 0; h < NH; h++) {
    float alpha = ex[(size_t)e * NH + h] / denom[d * NH + h];
    atomicAdd(&od[h * 64 + lane], alpha * xls[h * 64 + lane]);
  }
}

// ---------------- bias + relu ----------------------------------------------
__global__ __launch_bounds__(256) void k_biasrelu(
    float* __restrict__ z, const float* __restrict__ bias, int total) {
  int i = blockIdx.x * 256 + threadIdx.x;
  if (i >= total) return;
  float v = z[i] + bias[i & (F1 - 1)];
  z[i] = v > 0.f ? v : 0.f;
}

// ---------------- layer-2 GEMM: (N,256)x(256,64) x2 ------------------------
__global__ __launch_bounds__(256) void k_gemm2(
    const float* __restrict__ z,
    const float* __restrict__ Wl, const float* __restrict__ bl,
    const float* __restrict__ Wr, const float* __restrict__ br,
    float* __restrict__ xl2, float* __restrict__ xr2, int n_nodes) {
  __shared__ float zs[8][F1];
  int tid = threadIdx.x;
  int node0 = blockIdx.x * 8;
  for (int i = tid; i < 8 * F1; i += 256) {
    int n = i >> 8, k = i & 255;
    zs[n][k] = z[(size_t)(node0 + n) * F1 + k];
  }
  __syncthreads();
  int col = tid & 63;
  int half = (tid >> 6) & 1;  // 0 -> l, 1 -> r
  int grp = tid >> 7;         // 0..1
  const float* W = half ? Wr : Wl;
  float acc[4] = {0.f, 0.f, 0.f, 0.f};
  for (int k = 0; k < F1; k++) {
    float w = W[k * 64 + col];
#pragma unroll
    for (int q = 0; q < 4; q++) acc[q] = fmaf(zs[grp + 2 * q][k], w, acc[q]);
  }
  float b = (half ? br : bl)[col];
  float* dst = half ? xr2 : xl2;
#pragma unroll
  for (int q = 0; q < 4; q++)
    dst[(size_t)(node0 + grp + 2 * q) * OUTD + col] = acc[q] + b;
}

// ---------------- layer-2 edge scores (H=1) --------------------------------
__global__ __launch_bounds__(256) void k_score2(
    const float* __restrict__ xl, const float* __restrict__ xr,
    const int* __restrict__ ei, int E, int n_nodes,
    const float* __restrict__ att, float* __restrict__ score,
    unsigned* __restrict__ mkey) {
  int tid = threadIdx.x, lane = tid & 63;
  int e = blockIdx.x * 4 + (tid >> 6);
  int Etot = E + n_nodes;
  if (e >= Etot) return;
  int s, d;
  if (e < E) { s = ei[e]; d = ei[E + e]; } else { s = e - E; d = s; }
  float v = xl[(size_t)s * OUTD + lane] + xr[(size_t)d * OUTD + lane];
  v = v > 0.f ? v : NEG * v;
  float p = v * att[lane];
#pragma unroll
  for (int m = 32; m >= 1; m >>= 1) p += __shfl_xor(p, m, 64);
  if (lane == 0) {
    score[e] = p;
    unsigned u = __float_as_uint(p);
    unsigned key = (u & 0x80000000u) ? ~u : (u | 0x80000000u);
    atomicMax(&mkey[d], key);
  }
}

__global__ __launch_bounds__(256) void k_ex2(
    float* __restrict__ score, const unsigned* __restrict__ mkey,
    const int* __restrict__ ei, int E, int n_nodes,
    float* __restrict__ denom) {
  int e = blockIdx.x * 256 + threadIdx.x;
  int Etot = E + n_nodes;
  if (e >= Etot) return;
  int d = (e < E) ? ei[E + e] : (e - E);
  unsigned key = mkey[d];
  unsigned u = (key & 0x80000000u) ? (key & 0x7FFFFFFFu) : ~key;
  float ex = expf(score[e] - __uint_as_float(u));
  score[e] = ex;
  atomicAdd(&denom[d], ex);
}

__global__ __launch_bounds__(256) void k_agg2(
    const float* __restrict__ xl2, const float* __restrict__ ex,
    const float* __restrict__ denom, const int* __restrict__ ei,
    int E, int n_nodes, float* __restrict__ z2) {
  int tid = threadIdx.x, lane = tid & 63;
  int e = blockIdx.x * 4 + (tid >> 6);
  int Etot = E + n_nodes;
  if (e >= Etot) return;
  int s, d;
  if (e < E) { s = ei[e]; d = ei[E + e]; } else { s = e - E; d = s; }
  float alpha = ex[e] / denom[d];
  atomicAdd(&z2[(size_t)d * OUTD + lane], alpha * xl2[(size_t)s * OUTD + lane]);
}

// ---------------- decoder: concat -> 64 relu -> 1 ---------------------------
__global__ __launch_bounds__(256) void k_decode(
    const float* __restrict__ z2, const float* __restrict__ bias2,
    const int* __restrict__ eli, int EL,
    const float* __restrict__ Wm1, const float* __restrict__ bm1,
    const float* __restrict__ Wm2, const float* __restrict__ bm2,
    float* __restrict__ out) {
  __shared__ float feat[4][2 * OUTD];
  int tid = threadIdx.x, lane = tid & 63, w = tid >> 6;
  int l = blockIdx.x * 4 + w;
  if (l < EL) {
    int a = eli[l], b = eli[EL + l];
    feat[w][lane] = z2[(size_t)a * OUTD + lane] + bias2[lane];
    feat[w][64 + lane] = z2[(size_t)b * OUTD + lane] + bias2[lane];
  }
  __syncthreads();
  if (l >= EL) return;
  float acc = bm1[lane];
  for (int k = 0; k < 2 * OUTD; k++)
    acc = fmaf(feat[w][k], Wm1[k * OUTD + lane], acc);
  acc = acc > 0.f ? acc : 0.f;
  float p = acc * Wm2[lane];
#pragma unroll
  for (int m = 32; m >= 1; m >>= 1) p += __shfl_xor(p, m, 64);
  if (lane == 0) out[l] = p + bm2[0];
}

extern "C" void kernel_launch(void* const* d_in, const int* in_sizes, int n_in,
                              void* d_out, int out_size, void* d_ws, size_t ws_size,
                              hipStream_t stream) {
  const float* x     = (const float*)d_in[0];
  const int*   ei    = (const int*)d_in[1];
  const int*   eli   = (const int*)d_in[2];
  const float* W1l   = (const float*)d_in[3];
  const float* b1l   = (const float*)d_in[4];
  const float* W1r   = (const float*)d_in[5];
  const float* b1r   = (const float*)d_in[6];
  const float* att1  = (const float*)d_in[7];
  const float* bias1 = (const float*)d_in[8];
  const float* W2l   = (const float*)d_in[9];
  const float* b2l   = (const float*)d_in[10];
  const float* W2r   = (const float*)d_in[11];
  const float* b2r   = (const float*)d_in[12];
  const float* att2  = (const float*)d_in[13];
  const float* bias2 = (const float*)d_in[14];
  const float* Wm1   = (const float*)d_in[15];
  const float* bm1   = (const float*)d_in[16];
  const float* Wm2   = (const float*)d_in[17];
  const float* bm2   = (const float*)d_in[18];

  int N = in_sizes[0] / IN_DIM;   // 50000
  int E = in_sizes[1] / 2;        // 800000
  int EL = in_sizes[2] / 2;       // 200000
  int Etot = E + N;               // self-loops appended

  // ---- workspace layout (bytes) ----
  // [0, 51.2M)   A: xl1  (later: xl2 @0, xr2 @12.8M, z2 @25.6M)
  // [51.2M,102.4M) B: xr1 -> out1 -> z
  // [102.4M,116M)  S: score1/ex1 (later score2)
  // [116M,116.8M)  M: m1 keys (later m2)
  // [116.8M,117.6M) D: denom1 (later denom2)
  char* ws = (char*)d_ws;
  float*    xl1    = (float*)(ws);
  float*    bufB   = (float*)(ws + 51200000);
  float*    score1 = (float*)(ws + 102400000);
  unsigned* m1     = (unsigned*)(ws + 116000000);
  float*    denom1 = (float*)(ws + 116800000);
  float*    xl2    = (float*)(ws);
  float*    xr2    = (float*)(ws + 12800000);
  float*    z2     = (float*)(ws + 25600000);
  float*    score2 = score1;
  unsigned* m2     = m1;
  float*    denom2 = denom1;

  // ---- layer 1 ----
  hipMemsetAsync(m1, 0, (size_t)N * NH * 4, stream);
  hipMemsetAsync(denom1, 0, (size_t)N * NH * 4, stream);
  k_gemm1<<<N / 8, 256, 0, stream>>>(x, W1l, b1l, W1r, b1r, xl1, bufB, N);
  k_score1<<<(Etot + 3) / 4, 256, 0, stream>>>(xl1, bufB, ei, E, N, att1, score1, m1);
  k_ex1<<<((size_t)Etot * NH + 255) / 256, 256, 0, stream>>>(score1, m1, ei, E, N, denom1);
  hipMemsetAsync(bufB, 0, (size_t)N * F1 * 4, stream);
  k_agg1<<<(Etot + 3) / 4, 256, 0, stream>>>(xl1, score1, denom1, ei, E, N, bufB);
  k_biasrelu<<<((size_t)N * F1 + 255) / 256, 256, 0, stream>>>(bufB, bias1, N * F1);

  // ---- layer 2 ----
  k_gemm2<<<N / 8, 256, 0, stream>>>(bufB, W2l, b2l, W2r, b2r, xl2, xr2, N);
  hipMemsetAsync(m2, 0, (size_t)N * 4, stream);
  hipMemsetAsync(denom2, 0, (size_t)N * 4, stream);
  k_score2<<<(Etot + 3) / 4, 256, 0, stream>>>(xl2, xr2, ei, E, N, att2, score2, m2);
  k_ex2<<<(Etot + 255) / 256, 256, 0, stream>>>(score2, m2, ei, E, N, denom2);
  hipMemsetAsync(z2, 0, (size_t)N * OUTD * 4, stream);
  k_agg2<<<(Etot + 3) / 4, 256, 0, stream>>>(xl2, score2, denom2, ei, E, N, z2);

  // ---- decoder ----
  k_decode<<<(EL + 3) / 4, 256, 0, stream>>>(z2, bias2, eli, EL, Wm1, bm1, Wm2, bm2,
                                             (float*)d_out);
}

// Round 2
// 816.950 us; speedup vs baseline: 2.3033x; 2.3033x over previous
//
#include <hip/hip_runtime.h>
#include <hip/hip_bf16.h>

#define IN_DIM 128
#define HID    64
#define NH     4
#define F1     256   // NH*HID
#define OUTD   64
#define NEG    0.2f

// ---------------- layer-1 GEMM: xl = x@W1l + b1l, xr = x@W1r + b1r ----------
__global__ __launch_bounds__(256) void k_gemm1(
    const float* __restrict__ x,
    const float* __restrict__ Wl, const float* __restrict__ bl,
    const float* __restrict__ Wr, const float* __restrict__ br,
    float* __restrict__ xl, float* __restrict__ xr, int n_nodes) {
  __shared__ float xs[8][IN_DIM];
  int tid = threadIdx.x;
  int node0 = blockIdx.x * 8;
  for (int i = tid; i < 8 * IN_DIM; i += 256) {
    int n = i >> 7, k = i & 127;
    xs[n][k] = x[(size_t)(node0 + n) * IN_DIM + k];
  }
  __syncthreads();
  float accl[8], accr[8];
#pragma unroll
  for (int n = 0; n < 8; n++) { accl[n] = 0.f; accr[n] = 0.f; }
  int j = tid;
  for (int k = 0; k < IN_DIM; k++) {
    float wl = Wl[k * F1 + j];
    float wr = Wr[k * F1 + j];
#pragma unroll
    for (int n = 0; n < 8; n++) {
      accl[n] = fmaf(xs[n][k], wl, accl[n]);
      accr[n] = fmaf(xs[n][k], wr, accr[n]);
    }
  }
  float blj = bl[j], brj = br[j];
#pragma unroll
  for (int n = 0; n < 8; n++) {
    xl[(size_t)(node0 + n) * F1 + j] = accl[n] + blj;
    xr[(size_t)(node0 + n) * F1 + j] = accr[n] + brj;
  }
}

// ---------------- CSR build: histogram -> scan -> scatter -------------------
__global__ __launch_bounds__(256) void k_hist(
    const int* __restrict__ ei, int E, int N, int* __restrict__ cnt) {
  int e = blockIdx.x * 256 + threadIdx.x;
  if (e >= E + N) return;
  int d = (e < E) ? ei[E + e] : (e - E);
  atomicAdd(&cnt[d], 1);
}

__global__ __launch_bounds__(1024) void k_scan(
    const int* __restrict__ cnt, int* __restrict__ row_start,
    int* __restrict__ cursor, int N, int Etot) {
  __shared__ int buf[1024];
  __shared__ int carry;
  int tx = threadIdx.x;
  if (tx == 0) carry = 0;
  __syncthreads();
  for (int base = 0; base < N; base += 1024) {
    int i = base + tx;
    int v = (i < N) ? cnt[i] : 0;
    buf[tx] = v;
    __syncthreads();
    for (int off = 1; off < 1024; off <<= 1) {
      int t = (tx >= off) ? buf[tx - off] : 0;
      __syncthreads();
      buf[tx] += t;
      __syncthreads();
    }
    int excl = buf[tx] - v + carry;
    if (i < N) { row_start[i] = excl; cursor[i] = excl; }
    __syncthreads();
    if (tx == 1023) carry += buf[1023];
    __syncthreads();
  }
  if (tx == 0) row_start[N] = Etot;
}

__global__ __launch_bounds__(256) void k_scatter(
    const int* __restrict__ ei, int E, int N,
    int* __restrict__ cursor, int* __restrict__ csr_src) {
  int e = blockIdx.x * 256 + threadIdx.x;
  if (e >= E + N) return;
  int s, d;
  if (e < E) { s = ei[e]; d = ei[E + e]; } else { s = e - E; d = s; }
  int pos = atomicAdd(&cursor[d], 1);
  csr_src[pos] = s;
}

// ---------------- fused layer-1: score+softmax+agg+bias+relu ----------------
// One wave per dst node. Lane l owns float4 channels [4l..4l+3] (head l>>4).
// out aliases xr (row-private: wave i reads xr[i] into regs, writes out[i]).
__global__ __launch_bounds__(256) void k_fused1(
    const float* __restrict__ xl, const float* xr,
    const int* __restrict__ row_start, const int* __restrict__ csr_src,
    const float* __restrict__ att, const float* __restrict__ bias,
    float* out, int N) {
  int tid = threadIdx.x, lane = tid & 63, w = tid >> 6;
  int i = blockIdx.x * 4 + w;
  if (i >= N) return;
  float4 xri = *(const float4*)(xr + (size_t)i * F1 + lane * 4);
  float4 a4  = *(const float4*)(att + lane * 4);
  float m = -1e30f, den = 0.f;
  float4 acc = {0.f, 0.f, 0.f, 0.f};
  int b = row_start[i], e = row_start[i + 1];
  for (int k = b; k < e; k++) {
    int s = csr_src[k];
    float4 xs = *(const float4*)(xl + (size_t)s * F1 + lane * 4);
    float4 v;
    v.x = xs.x + xri.x; v.x = v.x > 0.f ? v.x : NEG * v.x;
    v.y = xs.y + xri.y; v.y = v.y > 0.f ? v.y : NEG * v.y;
    v.z = xs.z + xri.z; v.z = v.z > 0.f ? v.z : NEG * v.z;
    v.w = xs.w + xri.w; v.w = v.w > 0.f ? v.w : NEG * v.w;
    float p = v.x * a4.x + v.y * a4.y + v.z * a4.z + v.w * a4.w;
    p += __shfl_xor(p, 1, 64);
    p += __shfl_xor(p, 2, 64);
    p += __shfl_xor(p, 4, 64);
    p += __shfl_xor(p, 8, 64);   // p = score of this lane's head
    float mn = fmaxf(m, p);
    float cs = __expf(m - mn);
    float wt = __expf(p - mn);
    den = den * cs + wt;
    acc.x = acc.x * cs + wt * xs.x;
    acc.y = acc.y * cs + wt * xs.y;
    acc.z = acc.z * cs + wt * xs.z;
    acc.w = acc.w * cs + wt * xs.w;
    m = mn;
  }
  float inv = 1.f / den;
  float4 bz = *(const float4*)(bias + lane * 4);
  float4 o;
  o.x = fmaxf(acc.x * inv + bz.x, 0.f);
  o.y = fmaxf(acc.y * inv + bz.y, 0.f);
  o.z = fmaxf(acc.z * inv + bz.z, 0.f);
  o.w = fmaxf(acc.w * inv + bz.w, 0.f);
  *(float4*)(out + (size_t)i * F1 + lane * 4) = o;
}

// ---------------- layer-2 GEMM: (N,256)x(256,64) x2 ------------------------
__global__ __launch_bounds__(256) void k_gemm2(
    const float* __restrict__ z,
    const float* __restrict__ Wl, const float* __restrict__ bl,
    const float* __restrict__ Wr, const float* __restrict__ br,
    float* __restrict__ xl2, float* __restrict__ xr2, int n_nodes) {
  __shared__ float zs[8][F1];
  int tid = threadIdx.x;
  int node0 = blockIdx.x * 8;
  for (int i = tid; i < 8 * F1; i += 256) {
    int n = i >> 8, k = i & 255;
    zs[n][k] = z[(size_t)(node0 + n) * F1 + k];
  }
  __syncthreads();
  int col = tid & 63;
  int half = (tid >> 6) & 1;
  int grp = tid >> 7;
  const float* W = half ? Wr : Wl;
  float acc[4] = {0.f, 0.f, 0.f, 0.f};
  for (int k = 0; k < F1; k++) {
    float w = W[k * 64 + col];
#pragma unroll
    for (int q = 0; q < 4; q++) acc[q] = fmaf(zs[grp + 2 * q][k], w, acc[q]);
  }
  float b = (half ? br : bl)[col];
  float* dst = half ? xr2 : xl2;
#pragma unroll
  for (int q = 0; q < 4; q++)
    dst[(size_t)(node0 + grp + 2 * q) * OUTD + col] = acc[q] + b;
}

// ---------------- fused layer-2 (H=1) + bias2 -------------------------------
// z2 aliases xr2 (row-private).
__global__ __launch_bounds__(256) void k_fused2(
    const float* __restrict__ xl, const float* xr,
    const int* __restrict__ row_start, const int* __restrict__ csr_src,
    const float* __restrict__ att, const float* __restrict__ bias,
    float* out, int N) {
  int tid = threadIdx.x, lane = tid & 63, w = tid >> 6;
  int i = blockIdx.x * 4 + w;
  if (i >= N) return;
  float xri = xr[(size_t)i * OUTD + lane];
  float a = att[lane];
  float m = -1e30f, den = 0.f, acc = 0.f;
  int b = row_start[i], e = row_start[i + 1];
  for (int k = b; k < e; k++) {
    int s = csr_src[k];
    float xs = xl[(size_t)s * OUTD + lane];
    float v = xs + xri;
    v = v > 0.f ? v : NEG * v;
    float p = v * a;
#pragma unroll
    for (int mm = 32; mm >= 1; mm >>= 1) p += __shfl_xor(p, mm, 64);
    float mn = fmaxf(m, p);
    float cs = __expf(m - mn);
    float wt = __expf(p - mn);
    den = den * cs + wt;
    acc = acc * cs + wt * xs;
    m = mn;
  }
  out[(size_t)i * OUTD + lane] = acc / den + bias[lane];
}

// ---------------- decoder: concat -> 64 relu -> 1 ---------------------------
__global__ __launch_bounds__(256) void k_decode(
    const float* __restrict__ z2,
    const int* __restrict__ eli, int EL,
    const float* __restrict__ Wm1, const float* __restrict__ bm1,
    const float* __restrict__ Wm2, const float* __restrict__ bm2,
    float* __restrict__ out) {
  __shared__ float feat[4][2 * OUTD];
  int tid = threadIdx.x, lane = tid & 63, w = tid >> 6;
  int l = blockIdx.x * 4 + w;
  if (l < EL) {
    int a = eli[l], b = eli[EL + l];
    feat[w][lane] = z2[(size_t)a * OUTD + lane];
    feat[w][64 + lane] = z2[(size_t)b * OUTD + lane];
  }
  __syncthreads();
  if (l >= EL) return;
  float acc = bm1[lane];
  for (int k = 0; k < 2 * OUTD; k++)
    acc = fmaf(feat[w][k], Wm1[k * OUTD + lane], acc);
  acc = acc > 0.f ? acc : 0.f;
  float p = acc * Wm2[lane];
#pragma unroll
  for (int m = 32; m >= 1; m >>= 1) p += __shfl_xor(p, m, 64);
  if (lane == 0) out[l] = p + bm2[0];
}

extern "C" void kernel_launch(void* const* d_in, const int* in_sizes, int n_in,
                              void* d_out, int out_size, void* d_ws, size_t ws_size,
                              hipStream_t stream) {
  const float* x     = (const float*)d_in[0];
  const int*   ei    = (const int*)d_in[1];
  const int*   eli   = (const int*)d_in[2];
  const float* W1l   = (const float*)d_in[3];
  const float* b1l   = (const float*)d_in[4];
  const float* W1r   = (const float*)d_in[5];
  const float* b1r   = (const float*)d_in[6];
  const float* att1  = (const float*)d_in[7];
  const float* bias1 = (const float*)d_in[8];
  const float* W2l   = (const float*)d_in[9];
  const float* b2l   = (const float*)d_in[10];
  const float* W2r   = (const float*)d_in[11];
  const float* b2r   = (const float*)d_in[12];
  const float* att2  = (const float*)d_in[13];
  const float* bias2 = (const float*)d_in[14];
  const float* Wm1   = (const float*)d_in[15];
  const float* bm1   = (const float*)d_in[16];
  const float* Wm2   = (const float*)d_in[17];
  const float* bm2   = (const float*)d_in[18];

  int N = in_sizes[0] / IN_DIM;   // 50000
  int E = in_sizes[1] / 2;        // 800000
  int EL = in_sizes[2] / 2;       // 200000
  int Etot = E + N;               // +self-loops

  // ---- workspace layout (bytes) ----
  // [0, 51.2M)        xl1   (layer2: xl2 @0, xr2/z2 @12.8M)
  // [51.2M, 102.4M)   xr1 -> out1(z)  (fused1 writes over xr1, row-private)
  // [102.4M, ...)     row_start (N+1), cursor (N), csr_src (Etot)
  char* ws = (char*)d_ws;
  float* xl1       = (float*)(ws);
  float* bufB      = (float*)(ws + 51200000);
  int*   row_start = (int*)(ws + 102400000);
  int*   cursor    = (int*)(ws + 102700000);
  int*   csr_src   = (int*)(ws + 103000000);
  float* xl2       = (float*)(ws);
  float* xr2       = (float*)(ws + 12800000);

  // ---- CSR build (reused by both layers) ----
  hipMemsetAsync(cursor, 0, (size_t)N * 4, stream);
  k_gemm1<<<N / 8, 256, 0, stream>>>(x, W1l, b1l, W1r, b1r, xl1, bufB, N);
  k_hist<<<(Etot + 255) / 256, 256, 0, stream>>>(ei, E, N, cursor);
  k_scan<<<1, 1024, 0, stream>>>(cursor, row_start, cursor, N, Etot);
  k_scatter<<<(Etot + 255) / 256, 256, 0, stream>>>(ei, E, N, cursor, csr_src);

  // ---- layer 1 (fused) ----
  k_fused1<<<(N + 3) / 4, 256, 0, stream>>>(xl1, bufB, row_start, csr_src,
                                            att1, bias1, bufB, N);
  // ---- layer 2 ----
  k_gemm2<<<N / 8, 256, 0, stream>>>(bufB, W2l, b2l, W2r, b2r, xl2, xr2, N);
  k_fused2<<<(N + 3) / 4, 256, 0, stream>>>(xl2, xr2, row_start, csr_src,
                                            att2, bias2, xr2, N);
  // ---- decoder ----
  k_decode<<<(EL + 3) / 4, 256, 0, stream>>>(xr2, eli, EL, Wm1, bm1, Wm2, bm2,
                                             (float*)d_out);
}

// Round 3
// 675.303 us; speedup vs baseline: 2.7865x; 1.2098x over previous
//
#include <hip/hip_runtime.h>
#include <hip/hip_bf16.h>

#define IN_DIM 128
#define HID    64
#define NH     4
#define F1     256   // NH*HID
#define OUTD   64
#define NEG    0.2f

// ---------------- layer-1 GEMM: xl = x@W1l + b1l, xr = x@W1r + b1r ----------
__global__ __launch_bounds__(256) void k_gemm1(
    const float* __restrict__ x,
    const float* __restrict__ Wl, const float* __restrict__ bl,
    const float* __restrict__ Wr, const float* __restrict__ br,
    float* __restrict__ xl, float* __restrict__ xr, int n_nodes) {
  __shared__ float xs[8][IN_DIM];
  int tid = threadIdx.x;
  int node0 = blockIdx.x * 8;
  for (int i = tid; i < 8 * IN_DIM; i += 256) {
    int n = i >> 7, k = i & 127;
    xs[n][k] = x[(size_t)(node0 + n) * IN_DIM + k];
  }
  __syncthreads();
  float accl[8], accr[8];
#pragma unroll
  for (int n = 0; n < 8; n++) { accl[n] = 0.f; accr[n] = 0.f; }
  int j = tid;
  for (int k = 0; k < IN_DIM; k++) {
    float wl = Wl[k * F1 + j];
    float wr = Wr[k * F1 + j];
#pragma unroll
    for (int n = 0; n < 8; n++) {
      accl[n] = fmaf(xs[n][k], wl, accl[n]);
      accr[n] = fmaf(xs[n][k], wr, accr[n]);
    }
  }
  float blj = bl[j], brj = br[j];
#pragma unroll
  for (int n = 0; n < 8; n++) {
    xl[(size_t)(node0 + n) * F1 + j] = accl[n] + blj;
    xr[(size_t)(node0 + n) * F1 + j] = accr[n] + brj;
  }
}

// ---------------- CSR build: histogram -> scan -> scatter -------------------
__global__ __launch_bounds__(256) void k_hist(
    const int* __restrict__ ei, int E, int N, int* __restrict__ cnt) {
  int e = blockIdx.x * 256 + threadIdx.x;
  if (e >= E + N) return;
  int d = (e < E) ? ei[E + e] : (e - E);
  atomicAdd(&cnt[d], 1);
}

__global__ __launch_bounds__(1024) void k_scan(
    const int* __restrict__ cnt, int* __restrict__ row_start,
    int* __restrict__ cursor, int N, int Etot) {
  __shared__ int buf[1024];
  __shared__ int carry;
  int tx = threadIdx.x;
  if (tx == 0) carry = 0;
  __syncthreads();
  for (int base = 0; base < N; base += 1024) {
    int i = base + tx;
    int v = (i < N) ? cnt[i] : 0;
    buf[tx] = v;
    __syncthreads();
    for (int off = 1; off < 1024; off <<= 1) {
      int t = (tx >= off) ? buf[tx - off] : 0;
      __syncthreads();
      buf[tx] += t;
      __syncthreads();
    }
    int excl = buf[tx] - v + carry;
    if (i < N) { row_start[i] = excl; cursor[i] = excl; }
    __syncthreads();
    if (tx == 1023) carry += buf[1023];
    __syncthreads();
  }
  if (tx == 0) row_start[N] = Etot;
}

__global__ __launch_bounds__(256) void k_scatter(
    const int* __restrict__ ei, int E, int N,
    int* __restrict__ cursor, int* __restrict__ csr_src) {
  int e = blockIdx.x * 256 + threadIdx.x;
  if (e >= E + N) return;
  int s, d;
  if (e < E) { s = ei[e]; d = ei[E + e]; } else { s = e - E; d = s; }
  int pos = atomicAdd(&cursor[d], 1);
  csr_src[pos] = s;
}

// ---------------- fused layer-1: score+softmax+agg+bias+relu ----------------
__global__ __launch_bounds__(256) void k_fused1(
    const float* __restrict__ xl, const float* xr,
    const int* __restrict__ row_start, const int* __restrict__ csr_src,
    const float* __restrict__ att, const float* __restrict__ bias,
    float* out, int N) {
  int tid = threadIdx.x, lane = tid & 63, w = tid >> 6;
  int i = blockIdx.x * 4 + w;
  if (i >= N) return;
  float4 xri = *(const float4*)(xr + (size_t)i * F1 + lane * 4);
  float4 a4  = *(const float4*)(att + lane * 4);
  float m = -1e30f, den = 0.f;
  float4 acc = {0.f, 0.f, 0.f, 0.f};
  int b = row_start[i], e = row_start[i + 1];
  for (int k = b; k < e; k++) {
    int s = csr_src[k];
    float4 xs = *(const float4*)(xl + (size_t)s * F1 + lane * 4);
    float4 v;
    v.x = xs.x + xri.x; v.x = v.x > 0.f ? v.x : NEG * v.x;
    v.y = xs.y + xri.y; v.y = v.y > 0.f ? v.y : NEG * v.y;
    v.z = xs.z + xri.z; v.z = v.z > 0.f ? v.z : NEG * v.z;
    v.w = xs.w + xri.w; v.w = v.w > 0.f ? v.w : NEG * v.w;
    float p = v.x * a4.x + v.y * a4.y + v.z * a4.z + v.w * a4.w;
    p += __shfl_xor(p, 1, 64);
    p += __shfl_xor(p, 2, 64);
    p += __shfl_xor(p, 4, 64);
    p += __shfl_xor(p, 8, 64);
    float mn = fmaxf(m, p);
    float cs = __expf(m - mn);
    float wt = __expf(p - mn);
    den = den * cs + wt;
    acc.x = acc.x * cs + wt * xs.x;
    acc.y = acc.y * cs + wt * xs.y;
    acc.z = acc.z * cs + wt * xs.z;
    acc.w = acc.w * cs + wt * xs.w;
    m = mn;
  }
  float inv = 1.f / den;
  float4 bz = *(const float4*)(bias + lane * 4);
  float4 o;
  o.x = fmaxf(acc.x * inv + bz.x, 0.f);
  o.y = fmaxf(acc.y * inv + bz.y, 0.f);
  o.z = fmaxf(acc.z * inv + bz.z, 0.f);
  o.w = fmaxf(acc.w * inv + bz.w, 0.f);
  *(float4*)(out + (size_t)i * F1 + lane * 4) = o;
}

// ---------------- layer-2 GEMM: (N,256)x(256,64) x2 ------------------------
__global__ __launch_bounds__(256) void k_gemm2(
    const float* __restrict__ z,
    const float* __restrict__ Wl, const float* __restrict__ bl,
    const float* __restrict__ Wr, const float* __restrict__ br,
    float* __restrict__ xl2, float* __restrict__ xr2, int n_nodes) {
  __shared__ float zs[8][F1];
  int tid = threadIdx.x;
  int node0 = blockIdx.x * 8;
  for (int i = tid; i < 8 * F1; i += 256) {
    int n = i >> 8, k = i & 255;
    zs[n][k] = z[(size_t)(node0 + n) * F1 + k];
  }
  __syncthreads();
  int col = tid & 63;
  int half = (tid >> 6) & 1;
  int grp = tid >> 7;
  const float* W = half ? Wr : Wl;
  float acc[4] = {0.f, 0.f, 0.f, 0.f};
  for (int k = 0; k < F1; k++) {
    float w = W[k * 64 + col];
#pragma unroll
    for (int q = 0; q < 4; q++) acc[q] = fmaf(zs[grp + 2 * q][k], w, acc[q]);
  }
  float b = (half ? br : bl)[col];
  float* dst = half ? xr2 : xl2;
#pragma unroll
  for (int q = 0; q < 4; q++)
    dst[(size_t)(node0 + grp + 2 * q) * OUTD + col] = acc[q] + b;
}

// ---------------- fused layer-2 (H=1) + bias2 -------------------------------
__global__ __launch_bounds__(256) void k_fused2(
    const float* __restrict__ xl, const float* xr,
    const int* __restrict__ row_start, const int* __restrict__ csr_src,
    const float* __restrict__ att, const float* __restrict__ bias,
    float* out, int N) {
  int tid = threadIdx.x, lane = tid & 63, w = tid >> 6;
  int i = blockIdx.x * 4 + w;
  if (i >= N) return;
  float xri = xr[(size_t)i * OUTD + lane];
  float a = att[lane];
  float m = -1e30f, den = 0.f, acc = 0.f;
  int b = row_start[i], e = row_start[i + 1];
  for (int k = b; k < e; k++) {
    int s = csr_src[k];
    float xs = xl[(size_t)s * OUTD + lane];
    float v = xs + xri;
    v = v > 0.f ? v : NEG * v;
    float p = v * a;
#pragma unroll
    for (int mm = 32; mm >= 1; mm >>= 1) p += __shfl_xor(p, mm, 64);
    float mn = fmaxf(m, p);
    float cs = __expf(m - mn);
    float wt = __expf(p - mn);
    den = den * cs + wt;
    acc = acc * cs + wt * xs;
    m = mn;
  }
  out[(size_t)i * OUTD + lane] = acc / den + bias[lane];
}

// ---------------- decoder stage A: u = z2@Wm1[:64], v = z2@Wm1[64:] ---------
// 16 nodes per block. half=0 computes u (W rows 0..63), half=1 computes v.
__global__ __launch_bounds__(256) void k_gemm_uv(
    const float* __restrict__ z2, const float* __restrict__ Wm1,
    float* __restrict__ u, float* __restrict__ v, int N) {
  __shared__ float zs[16][OUTD];
  int tid = threadIdx.x;
  int node0 = blockIdx.x * 16;
  for (int i = tid; i < 16 * OUTD; i += 256) {
    int n = i >> 6, k = i & 63;
    int node = node0 + n;
    zs[n][k] = (node < N) ? z2[(size_t)node * OUTD + k] : 0.f;
  }
  __syncthreads();
  int col = tid & 63;
  int half = tid >> 7;           // 0 -> u, 1 -> v
  int grp = (tid >> 6) & 1;      // node parity
  const float* W = Wm1 + (size_t)half * 64 * OUTD;
  float acc[8];
#pragma unroll
  for (int q = 0; q < 8; q++) acc[q] = 0.f;
  for (int k = 0; k < OUTD; k++) {
    float w = W[k * OUTD + col];
#pragma unroll
    for (int q = 0; q < 8; q++) acc[q] = fmaf(zs[2 * q + grp][k], w, acc[q]);
  }
  float* dst = half ? v : u;
#pragma unroll
  for (int q = 0; q < 8; q++) {
    int node = node0 + 2 * q + grp;
    if (node < N) dst[(size_t)node * OUTD + col] = acc[q];
  }
}

// ---------------- decoder stage B: out = relu(u[a]+v[b]+bm1) . Wm2 + bm2 ----
// 16 lanes per link (float4 channels), 4 links per wave, 16 links per block.
__global__ __launch_bounds__(256) void k_link(
    const float* __restrict__ u, const float* __restrict__ v,
    const int* __restrict__ eli, int EL,
    const float* __restrict__ bm1, const float* __restrict__ Wm2,
    const float* __restrict__ bm2, float* __restrict__ out) {
  int tid = threadIdx.x, lane = tid & 63, w = tid >> 6;
  int li = lane >> 4, c4 = (lane & 15) * 4;
  int l = (blockIdx.x * 4 + w) * 4 + li;
  if (l >= EL) return;
  int a = eli[l], b = eli[EL + l];
  float4 uu = *(const float4*)(u + (size_t)a * OUTD + c4);
  float4 vv = *(const float4*)(v + (size_t)b * OUTD + c4);
  float4 bb = *(const float4*)(bm1 + c4);
  float4 ww = *(const float4*)(Wm2 + c4);
  float p = fmaxf(uu.x + vv.x + bb.x, 0.f) * ww.x
          + fmaxf(uu.y + vv.y + bb.y, 0.f) * ww.y
          + fmaxf(uu.z + vv.z + bb.z, 0.f) * ww.z
          + fmaxf(uu.w + vv.w + bb.w, 0.f) * ww.w;
  p += __shfl_xor(p, 1, 64);
  p += __shfl_xor(p, 2, 64);
  p += __shfl_xor(p, 4, 64);
  p += __shfl_xor(p, 8, 64);
  if ((lane & 15) == 0) out[l] = p + bm2[0];
}

extern "C" void kernel_launch(void* const* d_in, const int* in_sizes, int n_in,
                              void* d_out, int out_size, void* d_ws, size_t ws_size,
                              hipStream_t stream) {
  const float* x     = (const float*)d_in[0];
  const int*   ei    = (const int*)d_in[1];
  const int*   eli   = (const int*)d_in[2];
  const float* W1l   = (const float*)d_in[3];
  const float* b1l   = (const float*)d_in[4];
  const float* W1r   = (const float*)d_in[5];
  const float* b1r   = (const float*)d_in[6];
  const float* att1  = (const float*)d_in[7];
  const float* bias1 = (const float*)d_in[8];
  const float* W2l   = (const float*)d_in[9];
  const float* b2l   = (const float*)d_in[10];
  const float* W2r   = (const float*)d_in[11];
  const float* b2r   = (const float*)d_in[12];
  const float* att2  = (const float*)d_in[13];
  const float* bias2 = (const float*)d_in[14];
  const float* Wm1   = (const float*)d_in[15];
  const float* bm1   = (const float*)d_in[16];
  const float* Wm2   = (const float*)d_in[17];
  const float* bm2   = (const float*)d_in[18];

  int N = in_sizes[0] / IN_DIM;   // 50000
  int E = in_sizes[1] / 2;        // 800000
  int EL = in_sizes[2] / 2;       // 200000
  int Etot = E + N;

  // ---- workspace layout (bytes) ----
  // [0, 51.2M)        xl1   (layer2: xl2 @0, xr2/z2 @12.8M)
  // [51.2M, 102.4M)   xr1 -> out1(z)   (decoder: u @51.2M, v @64M)
  // [102.4M, ...)     row_start (N+1), cursor (N), csr_src (Etot)
  char* ws = (char*)d_ws;
  float* xl1       = (float*)(ws);
  float* bufB      = (float*)(ws + 51200000);
  int*   row_start = (int*)(ws + 102400000);
  int*   cursor    = (int*)(ws + 102700000);
  int*   csr_src   = (int*)(ws + 103000000);
  float* xl2       = (float*)(ws);
  float* xr2       = (float*)(ws + 12800000);
  float* u_buf     = (float*)(ws + 51200000);
  float* v_buf     = (float*)(ws + 64000000);

  // ---- CSR build (reused by both layers) ----
  hipMemsetAsync(cursor, 0, (size_t)N * 4, stream);
  k_gemm1<<<N / 8, 256, 0, stream>>>(x, W1l, b1l, W1r, b1r, xl1, bufB, N);
  k_hist<<<(Etot + 255) / 256, 256, 0, stream>>>(ei, E, N, cursor);
  k_scan<<<1, 1024, 0, stream>>>(cursor, row_start, cursor, N, Etot);
  k_scatter<<<(Etot + 255) / 256, 256, 0, stream>>>(ei, E, N, cursor, csr_src);

  // ---- layer 1 (fused) ----
  k_fused1<<<(N + 3) / 4, 256, 0, stream>>>(xl1, bufB, row_start, csr_src,
                                            att1, bias1, bufB, N);
  // ---- layer 2 ----
  k_gemm2<<<N / 8, 256, 0, stream>>>(bufB, W2l, b2l, W2r, b2r, xl2, xr2, N);
  k_fused2<<<(N + 3) / 4, 256, 0, stream>>>(xl2, xr2, row_start, csr_src,
                                            att2, bias2, xr2, N);
  // ---- decoder ----
  k_gemm_uv<<<(N + 15) / 16, 256, 0, stream>>>(xr2, Wm1, u_buf, v_buf, N);
  k_link<<<(EL + 15) / 16, 256, 0, stream>>>(u_buf, v_buf, eli, EL,
                                             bm1, Wm2, bm2, (float*)d_out);
}

// Round 4
// 625.251 us; speedup vs baseline: 3.0095x; 1.0801x over previous
//
#include <hip/hip_runtime.h>
#include <hip/hip_bf16.h>

#define IN_DIM 128
#define HID    64
#define NH     4
#define F1     256   // NH*HID
#define OUTD   64
#define NEG    0.2f

// ---------------- layer-1 GEMM: xl = x@W1l + b1l, xr = x@W1r + b1r ----------
// 16 nodes/block; LDS tile k-major [128][20] so per-k node vector reads are
// float4 broadcasts; each thread owns one output column j for all 16 nodes.
__global__ __launch_bounds__(256) void k_gemm1(
    const float* __restrict__ x,
    const float* __restrict__ Wl, const float* __restrict__ bl,
    const float* __restrict__ Wr, const float* __restrict__ br,
    float* __restrict__ xl, float* __restrict__ xr, int n_nodes) {
  __shared__ __align__(16) float xs[IN_DIM][20];  // pad 20: 80B rows, 16B-aligned
  int tid = threadIdx.x;
  int node0 = blockIdx.x * 16;
  for (int i = tid; i < 16 * IN_DIM; i += 256) {
    int n = i >> 7, k = i & 127;
    xs[k][n] = x[(size_t)(node0 + n) * IN_DIM + k];
  }
  __syncthreads();
  int j = tid;  // output column 0..255
  float accl[16], accr[16];
#pragma unroll
  for (int n = 0; n < 16; n++) { accl[n] = 0.f; accr[n] = 0.f; }
#pragma unroll 4
  for (int k = 0; k < IN_DIM; k++) {
    float wl = Wl[k * F1 + j];
    float wr = Wr[k * F1 + j];
#pragma unroll
    for (int g = 0; g < 4; g++) {
      float4 xv = *reinterpret_cast<const float4*>(&xs[k][g * 4]);
      accl[g * 4 + 0] = fmaf(xv.x, wl, accl[g * 4 + 0]);
      accl[g * 4 + 1] = fmaf(xv.y, wl, accl[g * 4 + 1]);
      accl[g * 4 + 2] = fmaf(xv.z, wl, accl[g * 4 + 2]);
      accl[g * 4 + 3] = fmaf(xv.w, wl, accl[g * 4 + 3]);
      accr[g * 4 + 0] = fmaf(xv.x, wr, accr[g * 4 + 0]);
      accr[g * 4 + 1] = fmaf(xv.y, wr, accr[g * 4 + 1]);
      accr[g * 4 + 2] = fmaf(xv.z, wr, accr[g * 4 + 2]);
      accr[g * 4 + 3] = fmaf(xv.w, wr, accr[g * 4 + 3]);
    }
  }
  float blj = bl[j], brj = br[j];
#pragma unroll
  for (int n = 0; n < 16; n++) {
    xl[(size_t)(node0 + n) * F1 + j] = accl[n] + blj;
    xr[(size_t)(node0 + n) * F1 + j] = accr[n] + brj;
  }
}

// ---------------- CSR build: histogram -> scan -> scatter -------------------
__global__ __launch_bounds__(256) void k_hist(
    const int* __restrict__ ei, int E, int N, int* __restrict__ cnt) {
  int e = blockIdx.x * 256 + threadIdx.x;
  if (e >= E + N) return;
  int d = (e < E) ? ei[E + e] : (e - E);
  atomicAdd(&cnt[d], 1);
}

__global__ __launch_bounds__(1024) void k_scan(
    const int* __restrict__ cnt, int* __restrict__ row_start,
    int* __restrict__ cursor, int N, int Etot) {
  __shared__ int buf[1024];
  __shared__ int carry;
  int tx = threadIdx.x;
  if (tx == 0) carry = 0;
  __syncthreads();
  for (int base = 0; base < N; base += 1024) {
    int i = base + tx;
    int v = (i < N) ? cnt[i] : 0;
    buf[tx] = v;
    __syncthreads();
    for (int off = 1; off < 1024; off <<= 1) {
      int t = (tx >= off) ? buf[tx - off] : 0;
      __syncthreads();
      buf[tx] += t;
      __syncthreads();
    }
    int excl = buf[tx] - v + carry;
    if (i < N) { row_start[i] = excl; cursor[i] = excl; }
    __syncthreads();
    if (tx == 1023) carry += buf[1023];
    __syncthreads();
  }
  if (tx == 0) row_start[N] = Etot;
}

__global__ __launch_bounds__(256) void k_scatter(
    const int* __restrict__ ei, int E, int N,
    int* __restrict__ cursor, int* __restrict__ csr_src) {
  int e = blockIdx.x * 256 + threadIdx.x;
  if (e >= E + N) return;
  int s, d;
  if (e < E) { s = ei[e]; d = ei[E + e]; } else { s = e - E; d = s; }
  int pos = atomicAdd(&cursor[d], 1);
  csr_src[pos] = s;
}

// ---------------- fused layer-1: score+softmax+agg+bias+relu ----------------
__global__ __launch_bounds__(256) void k_fused1(
    const float* __restrict__ xl, const float* xr,
    const int* __restrict__ row_start, const int* __restrict__ csr_src,
    const float* __restrict__ att, const float* __restrict__ bias,
    float* out, int N) {
  int tid = threadIdx.x, lane = tid & 63, w = tid >> 6;
  int i = blockIdx.x * 4 + w;
  if (i >= N) return;
  float4 xri = *(const float4*)(xr + (size_t)i * F1 + lane * 4);
  float4 a4  = *(const float4*)(att + lane * 4);
  float m = -1e30f, den = 0.f;
  float4 acc = {0.f, 0.f, 0.f, 0.f};
  int b = row_start[i], e = row_start[i + 1];
  for (int k = b; k < e; k++) {
    int s = csr_src[k];
    float4 xs = *(const float4*)(xl + (size_t)s * F1 + lane * 4);
    float4 v;
    v.x = xs.x + xri.x; v.x = v.x > 0.f ? v.x : NEG * v.x;
    v.y = xs.y + xri.y; v.y = v.y > 0.f ? v.y : NEG * v.y;
    v.z = xs.z + xri.z; v.z = v.z > 0.f ? v.z : NEG * v.z;
    v.w = xs.w + xri.w; v.w = v.w > 0.f ? v.w : NEG * v.w;
    float p = v.x * a4.x + v.y * a4.y + v.z * a4.z + v.w * a4.w;
    p += __shfl_xor(p, 1, 64);
    p += __shfl_xor(p, 2, 64);
    p += __shfl_xor(p, 4, 64);
    p += __shfl_xor(p, 8, 64);
    float mn = fmaxf(m, p);
    float cs = __expf(m - mn);
    float wt = __expf(p - mn);
    den = den * cs + wt;
    acc.x = acc.x * cs + wt * xs.x;
    acc.y = acc.y * cs + wt * xs.y;
    acc.z = acc.z * cs + wt * xs.z;
    acc.w = acc.w * cs + wt * xs.w;
    m = mn;
  }
  float inv = 1.f / den;
  float4 bz = *(const float4*)(bias + lane * 4);
  float4 o;
  o.x = fmaxf(acc.x * inv + bz.x, 0.f);
  o.y = fmaxf(acc.y * inv + bz.y, 0.f);
  o.z = fmaxf(acc.z * inv + bz.z, 0.f);
  o.w = fmaxf(acc.w * inv + bz.w, 0.f);
  *(float4*)(out + (size_t)i * F1 + lane * 4) = o;
}

// ---------------- layer-2 GEMM: (N,256)x(256,64) x2 ------------------------
// 32 nodes/block; LDS k-major [256][36]; threads = 64 cols x 2 half x 2 grp,
// each thread accumulates 16 nodes for one column of (l or r).
__global__ __launch_bounds__(256) void k_gemm2(
    const float* __restrict__ z,
    const float* __restrict__ Wl, const float* __restrict__ bl,
    const float* __restrict__ Wr, const float* __restrict__ br,
    float* __restrict__ xl2, float* __restrict__ xr2, int n_nodes) {
  __shared__ __align__(16) float zs[F1][36];  // 144B rows, 16B-aligned
  int tid = threadIdx.x;
  int node0 = blockIdx.x * 32;
  for (int i = tid; i < 32 * F1; i += 256) {
    int n = i >> 8, k = i & 255;
    int node = node0 + n;
    zs[k][n] = (node < n_nodes) ? z[(size_t)node * F1 + k] : 0.f;
  }
  __syncthreads();
  int col = tid & 63;
  int half = (tid >> 6) & 1;  // 0 -> l, 1 -> r
  int grp = tid >> 7;         // 16-node group
  const float* W = half ? Wr : Wl;
  float acc[16];
#pragma unroll
  for (int q = 0; q < 16; q++) acc[q] = 0.f;
#pragma unroll 4
  for (int k = 0; k < F1; k++) {
    float w = W[k * 64 + col];
#pragma unroll
    for (int g = 0; g < 4; g++) {
      float4 zv = *reinterpret_cast<const float4*>(&zs[k][grp * 16 + g * 4]);
      acc[g * 4 + 0] = fmaf(zv.x, w, acc[g * 4 + 0]);
      acc[g * 4 + 1] = fmaf(zv.y, w, acc[g * 4 + 1]);
      acc[g * 4 + 2] = fmaf(zv.z, w, acc[g * 4 + 2]);
      acc[g * 4 + 3] = fmaf(zv.w, w, acc[g * 4 + 3]);
    }
  }
  float b = (half ? br : bl)[col];
  float* dst = half ? xr2 : xl2;
#pragma unroll
  for (int q = 0; q < 16; q++) {
    int node = node0 + grp * 16 + q;
    if (node < n_nodes) dst[(size_t)node * OUTD + col] = acc[q] + b;
  }
}

// ---------------- fused layer-2 (H=1) + bias2 -------------------------------
__global__ __launch_bounds__(256) void k_fused2(
    const float* __restrict__ xl, const float* xr,
    const int* __restrict__ row_start, const int* __restrict__ csr_src,
    const float* __restrict__ att, const float* __restrict__ bias,
    float* out, int N) {
  int tid = threadIdx.x, lane = tid & 63, w = tid >> 6;
  int i = blockIdx.x * 4 + w;
  if (i >= N) return;
  float xri = xr[(size_t)i * OUTD + lane];
  float a = att[lane];
  float m = -1e30f, den = 0.f, acc = 0.f;
  int b = row_start[i], e = row_start[i + 1];
  for (int k = b; k < e; k++) {
    int s = csr_src[k];
    float xs = xl[(size_t)s * OUTD + lane];
    float v = xs + xri;
    v = v > 0.f ? v : NEG * v;
    float p = v * a;
#pragma unroll
    for (int mm = 32; mm >= 1; mm >>= 1) p += __shfl_xor(p, mm, 64);
    float mn = fmaxf(m, p);
    float cs = __expf(m - mn);
    float wt = __expf(p - mn);
    den = den * cs + wt;
    acc = acc * cs + wt * xs;
    m = mn;
  }
  out[(size_t)i * OUTD + lane] = acc / den + bias[lane];
}

// ---------------- decoder stage A: u = z2@Wm1[:64], v = z2@Wm1[64:] ---------
// 32 nodes/block; LDS k-major [64][36]; 64 cols x 2 half(u/v) x 2 grp.
__global__ __launch_bounds__(256) void k_gemm_uv(
    const float* __restrict__ z2, const float* __restrict__ Wm1,
    float* __restrict__ u, float* __restrict__ v, int N) {
  __shared__ __align__(16) float zs[OUTD][36];
  int tid = threadIdx.x;
  int node0 = blockIdx.x * 32;
  for (int i = tid; i < 32 * OUTD; i += 256) {
    int n = i >> 6, k = i & 63;
    int node = node0 + n;
    zs[k][n] = (node < N) ? z2[(size_t)node * OUTD + k] : 0.f;
  }
  __syncthreads();
  int col = tid & 63;
  int half = (tid >> 6) & 1;  // 0 -> u, 1 -> v
  int grp = tid >> 7;
  const float* W = Wm1 + (size_t)half * 64 * OUTD;
  float acc[16];
#pragma unroll
  for (int q = 0; q < 16; q++) acc[q] = 0.f;
#pragma unroll 4
  for (int k = 0; k < OUTD; k++) {
    float w = W[k * OUTD + col];
#pragma unroll
    for (int g = 0; g < 4; g++) {
      float4 zv = *reinterpret_cast<const float4*>(&zs[k][grp * 16 + g * 4]);
      acc[g * 4 + 0] = fmaf(zv.x, w, acc[g * 4 + 0]);
      acc[g * 4 + 1] = fmaf(zv.y, w, acc[g * 4 + 1]);
      acc[g * 4 + 2] = fmaf(zv.z, w, acc[g * 4 + 2]);
      acc[g * 4 + 3] = fmaf(zv.w, w, acc[g * 4 + 3]);
    }
  }
  float* dst = half ? v : u;
#pragma unroll
  for (int q = 0; q < 16; q++) {
    int node = node0 + grp * 16 + q;
    if (node < N) dst[(size_t)node * OUTD + col] = acc[q];
  }
}

// ---------------- decoder stage B: out = relu(u[a]+v[b]+bm1) . Wm2 + bm2 ----
__global__ __launch_bounds__(256) void k_link(
    const float* __restrict__ u, const float* __restrict__ v,
    const int* __restrict__ eli, int EL,
    const float* __restrict__ bm1, const float* __restrict__ Wm2,
    const float* __restrict__ bm2, float* __restrict__ out) {
  int tid = threadIdx.x, lane = tid & 63, w = tid >> 6;
  int li = lane >> 4, c4 = (lane & 15) * 4;
  int l = (blockIdx.x * 4 + w) * 4 + li;
  if (l >= EL) return;
  int a = eli[l], b = eli[EL + l];
  float4 uu = *(const float4*)(u + (size_t)a * OUTD + c4);
  float4 vv = *(const float4*)(v + (size_t)b * OUTD + c4);
  float4 bb = *(const float4*)(bm1 + c4);
  float4 ww = *(const float4*)(Wm2 + c4);
  float p = fmaxf(uu.x + vv.x + bb.x, 0.f) * ww.x
          + fmaxf(uu.y + vv.y + bb.y, 0.f) * ww.y
          + fmaxf(uu.z + vv.z + bb.z, 0.f) * ww.z
          + fmaxf(uu.w + vv.w + bb.w, 0.f) * ww.w;
  p += __shfl_xor(p, 1, 64);
  p += __shfl_xor(p, 2, 64);
  p += __shfl_xor(p, 4, 64);
  p += __shfl_xor(p, 8, 64);
  if ((lane & 15) == 0) out[l] = p + bm2[0];
}

extern "C" void kernel_launch(void* const* d_in, const int* in_sizes, int n_in,
                              void* d_out, int out_size, void* d_ws, size_t ws_size,
                              hipStream_t stream) {
  const float* x     = (const float*)d_in[0];
  const int*   ei    = (const int*)d_in[1];
  const int*   eli   = (const int*)d_in[2];
  const float* W1l   = (const float*)d_in[3];
  const float* b1l   = (const float*)d_in[4];
  const float* W1r   = (const float*)d_in[5];
  const float* b1r   = (const float*)d_in[6];
  const float* att1  = (const float*)d_in[7];
  const float* bias1 = (const float*)d_in[8];
  const float* W2l   = (const float*)d_in[9];
  const float* b2l   = (const float*)d_in[10];
  const float* W2r   = (const float*)d_in[11];
  const float* b2r   = (const float*)d_in[12];
  const float* att2  = (const float*)d_in[13];
  const float* bias2 = (const float*)d_in[14];
  const float* Wm1   = (const float*)d_in[15];
  const float* bm1   = (const float*)d_in[16];
  const float* Wm2   = (const float*)d_in[17];
  const float* bm2   = (const float*)d_in[18];

  int N = in_sizes[0] / IN_DIM;   // 50000
  int E = in_sizes[1] / 2;        // 800000
  int EL = in_sizes[2] / 2;       // 200000
  int Etot = E + N;

  // ---- workspace layout (bytes) ----
  // [0, 51.2M)        xl1   (layer2: xl2 @0, xr2/z2 @12.8M)
  // [51.2M, 102.4M)   xr1 -> out1(z)   (decoder: u @51.2M, v @64M)
  // [102.4M, ...)     row_start (N+1), cursor (N), csr_src (Etot)
  char* ws = (char*)d_ws;
  float* xl1       = (float*)(ws);
  float* bufB      = (float*)(ws + 51200000);
  int*   row_start = (int*)(ws + 102400000);
  int*   cursor    = (int*)(ws + 102700000);
  int*   csr_src   = (int*)(ws + 103000000);
  float* xl2       = (float*)(ws);
  float* xr2       = (float*)(ws + 12800000);
  float* u_buf     = (float*)(ws + 51200000);
  float* v_buf     = (float*)(ws + 64000000);

  // ---- CSR build (reused by both layers) ----
  hipMemsetAsync(cursor, 0, (size_t)N * 4, stream);
  k_gemm1<<<N / 16, 256, 0, stream>>>(x, W1l, b1l, W1r, b1r, xl1, bufB, N);
  k_hist<<<(Etot + 255) / 256, 256, 0, stream>>>(ei, E, N, cursor);
  k_scan<<<1, 1024, 0, stream>>>(cursor, row_start, cursor, N, Etot);
  k_scatter<<<(Etot + 255) / 256, 256, 0, stream>>>(ei, E, N, cursor, csr_src);

  // ---- layer 1 (fused) ----
  k_fused1<<<(N + 3) / 4, 256, 0, stream>>>(xl1, bufB, row_start, csr_src,
                                            att1, bias1, bufB, N);
  // ---- layer 2 ----
  k_gemm2<<<(N + 31) / 32, 256, 0, stream>>>(bufB, W2l, b2l, W2r, b2r, xl2, xr2, N);
  k_fused2<<<(N + 3) / 4, 256, 0, stream>>>(xl2, xr2, row_start, csr_src,
                                            att2, bias2, xr2, N);
  // ---- decoder ----
  k_gemm_uv<<<(N + 31) / 32, 256, 0, stream>>>(xr2, Wm1, u_buf, v_buf, N);
  k_link<<<(EL + 15) / 16, 256, 0, stream>>>(u_buf, v_buf, eli, EL,
                                             bm1, Wm2, bm2, (float*)d_out);
}

// Round 5
// 584.587 us; speedup vs baseline: 3.2189x; 1.0696x over previous
//
#include <hip/hip_runtime.h>
#include <hip/hip_bf16.h>

#define IN_DIM 128
#define HID    64
#define NH     4
#define F1     256   // NH*HID
#define OUTD   64
#define NEG    0.2f

// ---------------- layer-1 GEMM: xl = x@W1l + b1l, xr = x@W1r + b1r ----------
__global__ __launch_bounds__(256) void k_gemm1(
    const float* __restrict__ x,
    const float* __restrict__ Wl, const float* __restrict__ bl,
    const float* __restrict__ Wr, const float* __restrict__ br,
    float* __restrict__ xl, float* __restrict__ xr, int n_nodes) {
  __shared__ __align__(16) float xs[IN_DIM][20];
  int tid = threadIdx.x;
  int node0 = blockIdx.x * 16;
  for (int i = tid; i < 16 * IN_DIM; i += 256) {
    int n = i >> 7, k = i & 127;
    xs[k][n] = x[(size_t)(node0 + n) * IN_DIM + k];
  }
  __syncthreads();
  int j = tid;
  float accl[16], accr[16];
#pragma unroll
  for (int n = 0; n < 16; n++) { accl[n] = 0.f; accr[n] = 0.f; }
#pragma unroll 4
  for (int k = 0; k < IN_DIM; k++) {
    float wl = Wl[k * F1 + j];
    float wr = Wr[k * F1 + j];
#pragma unroll
    for (int g = 0; g < 4; g++) {
      float4 xv = *reinterpret_cast<const float4*>(&xs[k][g * 4]);
      accl[g * 4 + 0] = fmaf(xv.x, wl, accl[g * 4 + 0]);
      accl[g * 4 + 1] = fmaf(xv.y, wl, accl[g * 4 + 1]);
      accl[g * 4 + 2] = fmaf(xv.z, wl, accl[g * 4 + 2]);
      accl[g * 4 + 3] = fmaf(xv.w, wl, accl[g * 4 + 3]);
      accr[g * 4 + 0] = fmaf(xv.x, wr, accr[g * 4 + 0]);
      accr[g * 4 + 1] = fmaf(xv.y, wr, accr[g * 4 + 1]);
      accr[g * 4 + 2] = fmaf(xv.z, wr, accr[g * 4 + 2]);
      accr[g * 4 + 3] = fmaf(xv.w, wr, accr[g * 4 + 3]);
    }
  }
  float blj = bl[j], brj = br[j];
#pragma unroll
  for (int n = 0; n < 16; n++) {
    xl[(size_t)(node0 + n) * F1 + j] = accl[n] + blj;
    xr[(size_t)(node0 + n) * F1 + j] = accr[n] + brj;
  }
}

// ---------------- CSR build: histogram -> scan -> scatter -------------------
__global__ __launch_bounds__(256) void k_hist(
    const int* __restrict__ ei, int E, int N, int* __restrict__ cnt) {
  int e = blockIdx.x * 256 + threadIdx.x;
  if (e >= E + N) return;
  int d = (e < E) ? ei[E + e] : (e - E);
  atomicAdd(&cnt[d], 1);
}

// chunked scan: thread t owns cnt[t*C..t*C+C); wave-shuffle scan of the
// per-thread sums; 2 barriers total.
__global__ __launch_bounds__(1024) void k_scan(
    const int* __restrict__ cnt, int* __restrict__ row_start,
    int* __restrict__ cursor, int N, int Etot) {
  const int C = (N + 1023) / 1024;
  int t = threadIdx.x, lane = t & 63, wid = t >> 6;
  int lo = t * C, hi = lo + C; if (hi > N) hi = N;
  int s = 0;
  for (int i = lo; i < hi; i++) s += cnt[i];
  int v = s;
#pragma unroll
  for (int off = 1; off < 64; off <<= 1) {
    int u = __shfl_up(v, off, 64);
    if (lane >= off) v += u;
  }
  __shared__ int wsum[16];
  if (lane == 63) wsum[wid] = v;
  __syncthreads();
  if (t < 16) {
    int w = wsum[t];
#pragma unroll
    for (int off = 1; off < 16; off <<= 1) {
      int u = __shfl_up(w, off, 64);
      if (t >= off) w += u;
    }
    wsum[t] = w;
  }
  __syncthreads();
  int run = ((wid == 0) ? 0 : wsum[wid - 1]) + v - s;  // exclusive prefix
  for (int i = lo; i < hi; i++) {
    row_start[i] = run; cursor[i] = run; run += cnt[i];
  }
  if (t == 0) row_start[N] = Etot;
}

__global__ __launch_bounds__(256) void k_scatter(
    const int* __restrict__ ei, int E, int N,
    int* __restrict__ cursor, int* __restrict__ csr_src) {
  int e = blockIdx.x * 256 + threadIdx.x;
  if (e >= E + N) return;
  int s, d;
  if (e < E) { s = ei[e]; d = ei[E + e]; } else { s = e - E; d = s; }
  int pos = atomicAdd(&cursor[d], 1);
  csr_src[pos] = s;
}

// ---------------- fused layer-1: score+softmax+agg+bias+relu ----------------
// One wave per dst node; edge loop unrolled x4 with batched online softmax.
#define LEAKY4(v, xs, xri)                                   \
  v.x = xs.x + xri.x; v.x = v.x > 0.f ? v.x : NEG * v.x;     \
  v.y = xs.y + xri.y; v.y = v.y > 0.f ? v.y : NEG * v.y;     \
  v.z = xs.z + xri.z; v.z = v.z > 0.f ? v.z : NEG * v.z;     \
  v.w = xs.w + xri.w; v.w = v.w > 0.f ? v.w : NEG * v.w;

#define RED16(p)                 \
  p += __shfl_xor(p, 1, 64);     \
  p += __shfl_xor(p, 2, 64);     \
  p += __shfl_xor(p, 4, 64);     \
  p += __shfl_xor(p, 8, 64);

__global__ __launch_bounds__(256) void k_fused1(
    const float* __restrict__ xl, const float* xr,
    const int* __restrict__ row_start, const int* __restrict__ csr_src,
    const float* __restrict__ att, const float* __restrict__ bias,
    float* out, int N) {
  int tid = threadIdx.x, lane = tid & 63, w = tid >> 6;
  int i = blockIdx.x * 4 + w;
  if (i >= N) return;
  float4 xri = *(const float4*)(xr + (size_t)i * F1 + lane * 4);
  float4 a4  = *(const float4*)(att + lane * 4);
  float m = -1e30f, den = 0.f;
  float4 acc = {0.f, 0.f, 0.f, 0.f};
  int b = row_start[i], e = row_start[i + 1];
  int k = b;
  for (; k + 3 < e; k += 4) {
    int s0 = csr_src[k], s1 = csr_src[k + 1];
    int s2 = csr_src[k + 2], s3 = csr_src[k + 3];
    float4 x0 = *(const float4*)(xl + (size_t)s0 * F1 + lane * 4);
    float4 x1 = *(const float4*)(xl + (size_t)s1 * F1 + lane * 4);
    float4 x2 = *(const float4*)(xl + (size_t)s2 * F1 + lane * 4);
    float4 x3 = *(const float4*)(xl + (size_t)s3 * F1 + lane * 4);
    float4 v0, v1, v2, v3;
    LEAKY4(v0, x0, xri); LEAKY4(v1, x1, xri);
    LEAKY4(v2, x2, xri); LEAKY4(v3, x3, xri);
    float p0 = v0.x * a4.x + v0.y * a4.y + v0.z * a4.z + v0.w * a4.w;
    float p1 = v1.x * a4.x + v1.y * a4.y + v1.z * a4.z + v1.w * a4.w;
    float p2 = v2.x * a4.x + v2.y * a4.y + v2.z * a4.z + v2.w * a4.w;
    float p3 = v3.x * a4.x + v3.y * a4.y + v3.z * a4.z + v3.w * a4.w;
    RED16(p0); RED16(p1); RED16(p2); RED16(p3);
    float mn = fmaxf(fmaxf(m, p0), fmaxf(fmaxf(p1, p2), p3));
    float cs = __expf(m - mn);
    float w0 = __expf(p0 - mn), w1 = __expf(p1 - mn);
    float w2 = __expf(p2 - mn), w3 = __expf(p3 - mn);
    den = den * cs + (w0 + w1) + (w2 + w3);
    acc.x = acc.x * cs + w0 * x0.x + w1 * x1.x + w2 * x2.x + w3 * x3.x;
    acc.y = acc.y * cs + w0 * x0.y + w1 * x1.y + w2 * x2.y + w3 * x3.y;
    acc.z = acc.z * cs + w0 * x0.z + w1 * x1.z + w2 * x2.z + w3 * x3.z;
    acc.w = acc.w * cs + w0 * x0.w + w1 * x1.w + w2 * x2.w + w3 * x3.w;
    m = mn;
  }
  for (; k < e; k++) {
    int s = csr_src[k];
    float4 xs = *(const float4*)(xl + (size_t)s * F1 + lane * 4);
    float4 v;
    LEAKY4(v, xs, xri);
    float p = v.x * a4.x + v.y * a4.y + v.z * a4.z + v.w * a4.w;
    RED16(p);
    float mn = fmaxf(m, p);
    float cs = __expf(m - mn);
    float wt = __expf(p - mn);
    den = den * cs + wt;
    acc.x = acc.x * cs + wt * xs.x;
    acc.y = acc.y * cs + wt * xs.y;
    acc.z = acc.z * cs + wt * xs.z;
    acc.w = acc.w * cs + wt * xs.w;
    m = mn;
  }
  float inv = 1.f / den;
  float4 bz = *(const float4*)(bias + lane * 4);
  float4 o;
  o.x = fmaxf(acc.x * inv + bz.x, 0.f);
  o.y = fmaxf(acc.y * inv + bz.y, 0.f);
  o.z = fmaxf(acc.z * inv + bz.z, 0.f);
  o.w = fmaxf(acc.w * inv + bz.w, 0.f);
  *(float4*)(out + (size_t)i * F1 + lane * 4) = o;
}

// ---------------- layer-2 GEMM ---------------------------------------------
__global__ __launch_bounds__(256) void k_gemm2(
    const float* __restrict__ z,
    const float* __restrict__ Wl, const float* __restrict__ bl,
    const float* __restrict__ Wr, const float* __restrict__ br,
    float* __restrict__ xl2, float* __restrict__ xr2, int n_nodes) {
  __shared__ __align__(16) float zs[F1][36];
  int tid = threadIdx.x;
  int node0 = blockIdx.x * 32;
  for (int i = tid; i < 32 * F1; i += 256) {
    int n = i >> 8, k = i & 255;
    int node = node0 + n;
    zs[k][n] = (node < n_nodes) ? z[(size_t)node * F1 + k] : 0.f;
  }
  __syncthreads();
  int col = tid & 63;
  int half = (tid >> 6) & 1;
  int grp = tid >> 7;
  const float* W = half ? Wr : Wl;
  float acc[16];
#pragma unroll
  for (int q = 0; q < 16; q++) acc[q] = 0.f;
#pragma unroll 4
  for (int k = 0; k < F1; k++) {
    float w = W[k * 64 + col];
#pragma unroll
    for (int g = 0; g < 4; g++) {
      float4 zv = *reinterpret_cast<const float4*>(&zs[k][grp * 16 + g * 4]);
      acc[g * 4 + 0] = fmaf(zv.x, w, acc[g * 4 + 0]);
      acc[g * 4 + 1] = fmaf(zv.y, w, acc[g * 4 + 1]);
      acc[g * 4 + 2] = fmaf(zv.z, w, acc[g * 4 + 2]);
      acc[g * 4 + 3] = fmaf(zv.w, w, acc[g * 4 + 3]);
    }
  }
  float b = (half ? br : bl)[col];
  float* dst = half ? xr2 : xl2;
#pragma unroll
  for (int q = 0; q < 16; q++) {
    int node = node0 + grp * 16 + q;
    if (node < n_nodes) dst[(size_t)node * OUTD + col] = acc[q] + b;
  }
}

// ---------------- fused layer-2 (H=1) + bias2, unroll x4 --------------------
#define RED64(p)                 \
  p += __shfl_xor(p, 1, 64);     \
  p += __shfl_xor(p, 2, 64);     \
  p += __shfl_xor(p, 4, 64);     \
  p += __shfl_xor(p, 8, 64);     \
  p += __shfl_xor(p, 16, 64);    \
  p += __shfl_xor(p, 32, 64);

__global__ __launch_bounds__(256) void k_fused2(
    const float* __restrict__ xl, const float* xr,
    const int* __restrict__ row_start, const int* __restrict__ csr_src,
    const float* __restrict__ att, const float* __restrict__ bias,
    float* out, int N) {
  int tid = threadIdx.x, lane = tid & 63, w = tid >> 6;
  int i = blockIdx.x * 4 + w;
  if (i >= N) return;
  float xri = xr[(size_t)i * OUTD + lane];
  float a = att[lane];
  float m = -1e30f, den = 0.f, acc = 0.f;
  int b = row_start[i], e = row_start[i + 1];
  int k = b;
  for (; k + 3 < e; k += 4) {
    int s0 = csr_src[k], s1 = csr_src[k + 1];
    int s2 = csr_src[k + 2], s3 = csr_src[k + 3];
    float x0 = xl[(size_t)s0 * OUTD + lane];
    float x1 = xl[(size_t)s1 * OUTD + lane];
    float x2 = xl[(size_t)s2 * OUTD + lane];
    float x3 = xl[(size_t)s3 * OUTD + lane];
    float v0 = x0 + xri; v0 = v0 > 0.f ? v0 : NEG * v0;
    float v1 = x1 + xri; v1 = v1 > 0.f ? v1 : NEG * v1;
    float v2 = x2 + xri; v2 = v2 > 0.f ? v2 : NEG * v2;
    float v3 = x3 + xri; v3 = v3 > 0.f ? v3 : NEG * v3;
    float p0 = v0 * a, p1 = v1 * a, p2 = v2 * a, p3 = v3 * a;
    RED64(p0); RED64(p1); RED64(p2); RED64(p3);
    float mn = fmaxf(fmaxf(m, p0), fmaxf(fmaxf(p1, p2), p3));
    float cs = __expf(m - mn);
    float w0 = __expf(p0 - mn), w1 = __expf(p1 - mn);
    float w2 = __expf(p2 - mn), w3 = __expf(p3 - mn);
    den = den * cs + (w0 + w1) + (w2 + w3);
    acc = acc * cs + w0 * x0 + w1 * x1 + w2 * x2 + w3 * x3;
    m = mn;
  }
  for (; k < e; k++) {
    int s = csr_src[k];
    float xs = xl[(size_t)s * OUTD + lane];
    float v = xs + xri;
    v = v > 0.f ? v : NEG * v;
    float p = v * a;
    RED64(p);
    float mn = fmaxf(m, p);
    float cs = __expf(m - mn);
    float wt = __expf(p - mn);
    den = den * cs + wt;
    acc = acc * cs + wt * xs;
    m = mn;
  }
  out[(size_t)i * OUTD + lane] = acc / den + bias[lane];
}

// ---------------- decoder stage A ------------------------------------------
__global__ __launch_bounds__(256) void k_gemm_uv(
    const float* __restrict__ z2, const float* __restrict__ Wm1,
    float* __restrict__ u, float* __restrict__ v, int N) {
  __shared__ __align__(16) float zs[OUTD][36];
  int tid = threadIdx.x;
  int node0 = blockIdx.x * 32;
  for (int i = tid; i < 32 * OUTD; i += 256) {
    int n = i >> 6, k = i & 63;
    int node = node0 + n;
    zs[k][n] = (node < N) ? z2[(size_t)node * OUTD + k] : 0.f;
  }
  __syncthreads();
  int col = tid & 63;
  int half = (tid >> 6) & 1;
  int grp = tid >> 7;
  const float* W = Wm1 + (size_t)half * 64 * OUTD;
  float acc[16];
#pragma unroll
  for (int q = 0; q < 16; q++) acc[q] = 0.f;
#pragma unroll 4
  for (int k = 0; k < OUTD; k++) {
    float w = W[k * OUTD + col];
#pragma unroll
    for (int g = 0; g < 4; g++) {
      float4 zv = *reinterpret_cast<const float4*>(&zs[k][grp * 16 + g * 4]);
      acc[g * 4 + 0] = fmaf(zv.x, w, acc[g * 4 + 0]);
      acc[g * 4 + 1] = fmaf(zv.y, w, acc[g * 4 + 1]);
      acc[g * 4 + 2] = fmaf(zv.z, w, acc[g * 4 + 2]);
      acc[g * 4 + 3] = fmaf(zv.w, w, acc[g * 4 + 3]);
    }
  }
  float* dst = half ? v : u;
#pragma unroll
  for (int q = 0; q < 16; q++) {
    int node = node0 + grp * 16 + q;
    if (node < N) dst[(size_t)node * OUTD + col] = acc[q];
  }
}

// ---------------- decoder stage B ------------------------------------------
__global__ __launch_bounds__(256) void k_link(
    const float* __restrict__ u, const float* __restrict__ v,
    const int* __restrict__ eli, int EL,
    const float* __restrict__ bm1, const float* __restrict__ Wm2,
    const float* __restrict__ bm2, float* __restrict__ out) {
  int tid = threadIdx.x, lane = tid & 63, w = tid >> 6;
  int li = lane >> 4, c4 = (lane & 15) * 4;
  int l = (blockIdx.x * 4 + w) * 4 + li;
  if (l >= EL) return;
  int a = eli[l], b = eli[EL + l];
  float4 uu = *(const float4*)(u + (size_t)a * OUTD + c4);
  float4 vv = *(const float4*)(v + (size_t)b * OUTD + c4);
  float4 bb = *(const float4*)(bm1 + c4);
  float4 ww = *(const float4*)(Wm2 + c4);
  float p = fmaxf(uu.x + vv.x + bb.x, 0.f) * ww.x
          + fmaxf(uu.y + vv.y + bb.y, 0.f) * ww.y
          + fmaxf(uu.z + vv.z + bb.z, 0.f) * ww.z
          + fmaxf(uu.w + vv.w + bb.w, 0.f) * ww.w;
  p += __shfl_xor(p, 1, 64);
  p += __shfl_xor(p, 2, 64);
  p += __shfl_xor(p, 4, 64);
  p += __shfl_xor(p, 8, 64);
  if ((lane & 15) == 0) out[l] = p + bm2[0];
}

extern "C" void kernel_launch(void* const* d_in, const int* in_sizes, int n_in,
                              void* d_out, int out_size, void* d_ws, size_t ws_size,
                              hipStream_t stream) {
  const float* x     = (const float*)d_in[0];
  const int*   ei    = (const int*)d_in[1];
  const int*   eli   = (const int*)d_in[2];
  const float* W1l   = (const float*)d_in[3];
  const float* b1l   = (const float*)d_in[4];
  const float* W1r   = (const float*)d_in[5];
  const float* b1r   = (const float*)d_in[6];
  const float* att1  = (const float*)d_in[7];
  const float* bias1 = (const float*)d_in[8];
  const float* W2l   = (const float*)d_in[9];
  const float* b2l   = (const float*)d_in[10];
  const float* W2r   = (const float*)d_in[11];
  const float* b2r   = (const float*)d_in[12];
  const float* att2  = (const float*)d_in[13];
  const float* bias2 = (const float*)d_in[14];
  const float* Wm1   = (const float*)d_in[15];
  const float* bm1   = (const float*)d_in[16];
  const float* Wm2   = (const float*)d_in[17];
  const float* bm2   = (const float*)d_in[18];

  int N = in_sizes[0] / IN_DIM;   // 50000
  int E = in_sizes[1] / 2;        // 800000
  int EL = in_sizes[2] / 2;       // 200000
  int Etot = E + N;

  char* ws = (char*)d_ws;
  float* xl1       = (float*)(ws);
  float* bufB      = (float*)(ws + 51200000);
  int*   row_start = (int*)(ws + 102400000);
  int*   cursor    = (int*)(ws + 102700000);
  int*   csr_src   = (int*)(ws + 103000000);
  float* xl2       = (float*)(ws);
  float* xr2       = (float*)(ws + 12800000);
  float* u_buf     = (float*)(ws + 51200000);
  float* v_buf     = (float*)(ws + 64000000);

  // ---- CSR build (reused by both layers) ----
  hipMemsetAsync(cursor, 0, (size_t)N * 4, stream);
  k_gemm1<<<N / 16, 256, 0, stream>>>(x, W1l, b1l, W1r, b1r, xl1, bufB, N);
  k_hist<<<(Etot + 255) / 256, 256, 0, stream>>>(ei, E, N, cursor);
  k_scan<<<1, 1024, 0, stream>>>(cursor, row_start, cursor, N, Etot);
  k_scatter<<<(Etot + 255) / 256, 256, 0, stream>>>(ei, E, N, cursor, csr_src);

  // ---- layer 1 (fused) ----
  k_fused1<<<(N + 3) / 4, 256, 0, stream>>>(xl1, bufB, row_start, csr_src,
                                            att1, bias1, bufB, N);
  // ---- layer 2 ----
  k_gemm2<<<(N + 31) / 32, 256, 0, stream>>>(bufB, W2l, b2l, W2r, b2r, xl2, xr2, N);
  k_fused2<<<(N + 3) / 4, 256, 0, stream>>>(xl2, xr2, row_start, csr_src,
                                            att2, bias2, xr2, N);
  // ---- decoder ----
  k_gemm_uv<<<(N + 31) / 32, 256, 0, stream>>>(xr2, Wm1, u_buf, v_buf, N);
  k_link<<<(EL + 15) / 16, 256, 0, stream>>>(u_buf, v_buf, eli, EL,
                                             bm1, Wm2, bm2, (float*)d_out);
}

// Round 6
// 547.547 us; speedup vs baseline: 3.4366x; 1.0676x over previous
//
#include <hip/hip_runtime.h>
#include <hip/hip_bf16.h>

#define IN_DIM 128
#define HID    64
#define NH     4
#define F1     256   // NH*HID
#define OUTD   64
#define NEG    0.2f

__device__ __forceinline__ float bf2f(unsigned short h) {
  return __uint_as_float((unsigned)h << 16);
}
__device__ __forceinline__ unsigned short f2bf(float f) {
  unsigned u = __float_as_uint(f);
  u += 0x7fffu + ((u >> 16) & 1u);   // RTNE
  return (unsigned short)(u >> 16);
}

// ---------------- layer-1 GEMM: xl(bf16) = x@W1l+b1l, xr(f32) = x@W1r+b1r ---
// 32 nodes/block; LDS k-major [128][36]; each thread owns column j for 32 nodes.
__global__ __launch_bounds__(256) void k_gemm1(
    const float* __restrict__ x,
    const float* __restrict__ Wl, const float* __restrict__ bl,
    const float* __restrict__ Wr, const float* __restrict__ br,
    unsigned short* __restrict__ xlh, float* __restrict__ xr, int n_nodes) {
  __shared__ __align__(16) float xs[IN_DIM][36];
  int tid = threadIdx.x;
  int node0 = blockIdx.x * 32;
  for (int i = tid; i < 32 * IN_DIM; i += 256) {
    int n = i >> 7, k = i & 127;
    int node = node0 + n;
    xs[k][n] = (node < n_nodes) ? x[(size_t)node * IN_DIM + k] : 0.f;
  }
  __syncthreads();
  int j = tid;
  float accl[32], accr[32];
#pragma unroll
  for (int n = 0; n < 32; n++) { accl[n] = 0.f; accr[n] = 0.f; }
#pragma unroll 2
  for (int k = 0; k < IN_DIM; k++) {
    float wl = Wl[k * F1 + j];
    float wr = Wr[k * F1 + j];
#pragma unroll
    for (int g = 0; g < 8; g++) {
      float4 xv = *reinterpret_cast<const float4*>(&xs[k][g * 4]);
      accl[g * 4 + 0] = fmaf(xv.x, wl, accl[g * 4 + 0]);
      accl[g * 4 + 1] = fmaf(xv.y, wl, accl[g * 4 + 1]);
      accl[g * 4 + 2] = fmaf(xv.z, wl, accl[g * 4 + 2]);
      accl[g * 4 + 3] = fmaf(xv.w, wl, accl[g * 4 + 3]);
      accr[g * 4 + 0] = fmaf(xv.x, wr, accr[g * 4 + 0]);
      accr[g * 4 + 1] = fmaf(xv.y, wr, accr[g * 4 + 1]);
      accr[g * 4 + 2] = fmaf(xv.z, wr, accr[g * 4 + 2]);
      accr[g * 4 + 3] = fmaf(xv.w, wr, accr[g * 4 + 3]);
    }
  }
  float blj = bl[j], brj = br[j];
#pragma unroll
  for (int n = 0; n < 32; n++) {
    int node = node0 + n;
    if (node < n_nodes) {
      xlh[(size_t)node * F1 + j] = f2bf(accl[n] + blj);
      xr[(size_t)node * F1 + j] = accr[n] + brj;
    }
  }
}

// ---------------- CSR build: histogram -> scan -> scatter -------------------
__global__ __launch_bounds__(256) void k_hist(
    const int* __restrict__ ei, int E, int N, int* __restrict__ cnt) {
  int e = blockIdx.x * 256 + threadIdx.x;
  if (e >= E + N) return;
  int d = (e < E) ? ei[E + e] : (e - E);
  atomicAdd(&cnt[d], 1);
}

__global__ __launch_bounds__(1024) void k_scan(
    const int* __restrict__ cnt, int* __restrict__ row_start,
    int* __restrict__ cursor, int N, int Etot) {
  const int C = (N + 1023) / 1024;
  int t = threadIdx.x, lane = t & 63, wid = t >> 6;
  int lo = t * C, hi = lo + C; if (hi > N) hi = N;
  int s = 0;
  for (int i = lo; i < hi; i++) s += cnt[i];
  int v = s;
#pragma unroll
  for (int off = 1; off < 64; off <<= 1) {
    int u = __shfl_up(v, off, 64);
    if (lane >= off) v += u;
  }
  __shared__ int wsum[16];
  if (lane == 63) wsum[wid] = v;
  __syncthreads();
  if (t < 16) {
    int w = wsum[t];
#pragma unroll
    for (int off = 1; off < 16; off <<= 1) {
      int u = __shfl_up(w, off, 64);
      if (t >= off) w += u;
    }
    wsum[t] = w;
  }
  __syncthreads();
  int run = ((wid == 0) ? 0 : wsum[wid - 1]) + v - s;
  for (int i = lo; i < hi; i++) {
    row_start[i] = run; cursor[i] = run; run += cnt[i];
  }
  if (t == 0) row_start[N] = Etot;
}

__global__ __launch_bounds__(256) void k_scatter(
    const int* __restrict__ ei, int E, int N,
    int* __restrict__ cursor, int* __restrict__ csr_src) {
  int e = blockIdx.x * 256 + threadIdx.x;
  if (e >= E + N) return;
  int s, d;
  if (e < E) { s = ei[e]; d = ei[E + e]; } else { s = e - E; d = s; }
  int pos = atomicAdd(&cursor[d], 1);
  csr_src[pos] = s;
}

// ---------------- fused layer-1 (bf16 xl gathers) ---------------------------
#define LEAKY4(v, xs, xri)                                   \
  v.x = xs.x + xri.x; v.x = v.x > 0.f ? v.x : NEG * v.x;     \
  v.y = xs.y + xri.y; v.y = v.y > 0.f ? v.y : NEG * v.y;     \
  v.z = xs.z + xri.z; v.z = v.z > 0.f ? v.z : NEG * v.z;     \
  v.w = xs.w + xri.w; v.w = v.w > 0.f ? v.w : NEG * v.w;

#define RED16(p)                 \
  p += __shfl_xor(p, 1, 64);     \
  p += __shfl_xor(p, 2, 64);     \
  p += __shfl_xor(p, 4, 64);     \
  p += __shfl_xor(p, 8, 64);

#define BF4(dst, h)                                \
  dst.x = bf2f(h.x); dst.y = bf2f(h.y);            \
  dst.z = bf2f(h.z); dst.w = bf2f(h.w);

__global__ __launch_bounds__(256) void k_fused1(
    const unsigned short* __restrict__ xlh, const float* xr,
    const int* __restrict__ row_start, const int* __restrict__ csr_src,
    const float* __restrict__ att, const float* __restrict__ bias,
    float* out, int N) {
  int tid = threadIdx.x, lane = tid & 63, w = tid >> 6;
  int i = blockIdx.x * 4 + w;
  if (i >= N) return;
  float4 xri = *(const float4*)(xr + (size_t)i * F1 + lane * 4);
  float4 a4  = *(const float4*)(att + lane * 4);
  float m = -1e30f, den = 0.f;
  float4 acc = {0.f, 0.f, 0.f, 0.f};
  int b = row_start[i], e = row_start[i + 1];
  int k = b;
  for (; k + 3 < e; k += 4) {
    int s0 = csr_src[k], s1 = csr_src[k + 1];
    int s2 = csr_src[k + 2], s3 = csr_src[k + 3];
    ushort4 h0 = *(const ushort4*)(xlh + (size_t)s0 * F1 + lane * 4);
    ushort4 h1 = *(const ushort4*)(xlh + (size_t)s1 * F1 + lane * 4);
    ushort4 h2 = *(const ushort4*)(xlh + (size_t)s2 * F1 + lane * 4);
    ushort4 h3 = *(const ushort4*)(xlh + (size_t)s3 * F1 + lane * 4);
    float4 x0, x1, x2, x3;
    BF4(x0, h0); BF4(x1, h1); BF4(x2, h2); BF4(x3, h3);
    float4 v0, v1, v2, v3;
    LEAKY4(v0, x0, xri); LEAKY4(v1, x1, xri);
    LEAKY4(v2, x2, xri); LEAKY4(v3, x3, xri);
    float p0 = v0.x * a4.x + v0.y * a4.y + v0.z * a4.z + v0.w * a4.w;
    float p1 = v1.x * a4.x + v1.y * a4.y + v1.z * a4.z + v1.w * a4.w;
    float p2 = v2.x * a4.x + v2.y * a4.y + v2.z * a4.z + v2.w * a4.w;
    float p3 = v3.x * a4.x + v3.y * a4.y + v3.z * a4.z + v3.w * a4.w;
    RED16(p0); RED16(p1); RED16(p2); RED16(p3);
    float mn = fmaxf(fmaxf(m, p0), fmaxf(fmaxf(p1, p2), p3));
    float cs = __expf(m - mn);
    float w0 = __expf(p0 - mn), w1 = __expf(p1 - mn);
    float w2 = __expf(p2 - mn), w3 = __expf(p3 - mn);
    den = den * cs + (w0 + w1) + (w2 + w3);
    acc.x = acc.x * cs + w0 * x0.x + w1 * x1.x + w2 * x2.x + w3 * x3.x;
    acc.y = acc.y * cs + w0 * x0.y + w1 * x1.y + w2 * x2.y + w3 * x3.y;
    acc.z = acc.z * cs + w0 * x0.z + w1 * x1.z + w2 * x2.z + w3 * x3.z;
    acc.w = acc.w * cs + w0 * x0.w + w1 * x1.w + w2 * x2.w + w3 * x3.w;
    m = mn;
  }
  for (; k < e; k++) {
    int s = csr_src[k];
    ushort4 hh = *(const ushort4*)(xlh + (size_t)s * F1 + lane * 4);
    float4 xs;
    BF4(xs, hh);
    float4 v;
    LEAKY4(v, xs, xri);
    float p = v.x * a4.x + v.y * a4.y + v.z * a4.z + v.w * a4.w;
    RED16(p);
    float mn = fmaxf(m, p);
    float cs = __expf(m - mn);
    float wt = __expf(p - mn);
    den = den * cs + wt;
    acc.x = acc.x * cs + wt * xs.x;
    acc.y = acc.y * cs + wt * xs.y;
    acc.z = acc.z * cs + wt * xs.z;
    acc.w = acc.w * cs + wt * xs.w;
    m = mn;
  }
  float inv = 1.f / den;
  float4 bz = *(const float4*)(bias + lane * 4);
  float4 o;
  o.x = fmaxf(acc.x * inv + bz.x, 0.f);
  o.y = fmaxf(acc.y * inv + bz.y, 0.f);
  o.z = fmaxf(acc.z * inv + bz.z, 0.f);
  o.w = fmaxf(acc.w * inv + bz.w, 0.f);
  *(float4*)(out + (size_t)i * F1 + lane * 4) = o;
}

// ---------------- layer-2 GEMM ---------------------------------------------
__global__ __launch_bounds__(256) void k_gemm2(
    const float* __restrict__ z,
    const float* __restrict__ Wl, const float* __restrict__ bl,
    const float* __restrict__ Wr, const float* __restrict__ br,
    float* __restrict__ xl2, float* __restrict__ xr2, int n_nodes) {
  __shared__ __align__(16) float zs[F1][36];
  int tid = threadIdx.x;
  int node0 = blockIdx.x * 32;
  for (int i = tid; i < 32 * F1; i += 256) {
    int n = i >> 8, k = i & 255;
    int node = node0 + n;
    zs[k][n] = (node < n_nodes) ? z[(size_t)node * F1 + k] : 0.f;
  }
  __syncthreads();
  int col = tid & 63;
  int half = (tid >> 6) & 1;
  int grp = tid >> 7;
  const float* W = half ? Wr : Wl;
  float acc[16];
#pragma unroll
  for (int q = 0; q < 16; q++) acc[q] = 0.f;
#pragma unroll 4
  for (int k = 0; k < F1; k++) {
    float w = W[k * 64 + col];
#pragma unroll
    for (int g = 0; g < 4; g++) {
      float4 zv = *reinterpret_cast<const float4*>(&zs[k][grp * 16 + g * 4]);
      acc[g * 4 + 0] = fmaf(zv.x, w, acc[g * 4 + 0]);
      acc[g * 4 + 1] = fmaf(zv.y, w, acc[g * 4 + 1]);
      acc[g * 4 + 2] = fmaf(zv.z, w, acc[g * 4 + 2]);
      acc[g * 4 + 3] = fmaf(zv.w, w, acc[g * 4 + 3]);
    }
  }
  float b = (half ? br : bl)[col];
  float* dst = half ? xr2 : xl2;
#pragma unroll
  for (int q = 0; q < 16; q++) {
    int node = node0 + grp * 16 + q;
    if (node < n_nodes) dst[(size_t)node * OUTD + col] = acc[q] + b;
  }
}

// ---------------- fused layer-2 (H=1) + bias2, unroll x4 --------------------
#define RED64(p)                 \
  p += __shfl_xor(p, 1, 64);     \
  p += __shfl_xor(p, 2, 64);     \
  p += __shfl_xor(p, 4, 64);     \
  p += __shfl_xor(p, 8, 64);     \
  p += __shfl_xor(p, 16, 64);    \
  p += __shfl_xor(p, 32, 64);

__global__ __launch_bounds__(256) void k_fused2(
    const float* __restrict__ xl, const float* xr,
    const int* __restrict__ row_start, const int* __restrict__ csr_src,
    const float* __restrict__ att, const float* __restrict__ bias,
    float* out, int N) {
  int tid = threadIdx.x, lane = tid & 63, w = tid >> 6;
  int i = blockIdx.x * 4 + w;
  if (i >= N) return;
  float xri = xr[(size_t)i * OUTD + lane];
  float a = att[lane];
  float m = -1e30f, den = 0.f, acc = 0.f;
  int b = row_start[i], e = row_start[i + 1];
  int k = b;
  for (; k + 3 < e; k += 4) {
    int s0 = csr_src[k], s1 = csr_src[k + 1];
    int s2 = csr_src[k + 2], s3 = csr_src[k + 3];
    float x0 = xl[(size_t)s0 * OUTD + lane];
    float x1 = xl[(size_t)s1 * OUTD + lane];
    float x2 = xl[(size_t)s2 * OUTD + lane];
    float x3 = xl[(size_t)s3 * OUTD + lane];
    float v0 = x0 + xri; v0 = v0 > 0.f ? v0 : NEG * v0;
    float v1 = x1 + xri; v1 = v1 > 0.f ? v1 : NEG * v1;
    float v2 = x2 + xri; v2 = v2 > 0.f ? v2 : NEG * v2;
    float v3 = x3 + xri; v3 = v3 > 0.f ? v3 : NEG * v3;
    float p0 = v0 * a, p1 = v1 * a, p2 = v2 * a, p3 = v3 * a;
    RED64(p0); RED64(p1); RED64(p2); RED64(p3);
    float mn = fmaxf(fmaxf(m, p0), fmaxf(fmaxf(p1, p2), p3));
    float cs = __expf(m - mn);
    float w0 = __expf(p0 - mn), w1 = __expf(p1 - mn);
    float w2 = __expf(p2 - mn), w3 = __expf(p3 - mn);
    den = den * cs + (w0 + w1) + (w2 + w3);
    acc = acc * cs + w0 * x0 + w1 * x1 + w2 * x2 + w3 * x3;
    m = mn;
  }
  for (; k < e; k++) {
    int s = csr_src[k];
    float xs = xl[(size_t)s * OUTD + lane];
    float v = xs + xri;
    v = v > 0.f ? v : NEG * v;
    float p = v * a;
    RED64(p);
    float mn = fmaxf(m, p);
    float cs = __expf(m - mn);
    float wt = __expf(p - mn);
    den = den * cs + wt;
    acc = acc * cs + wt * xs;
    m = mn;
  }
  out[(size_t)i * OUTD + lane] = acc / den + bias[lane];
}

// ---------------- decoder stage A ------------------------------------------
__global__ __launch_bounds__(256) void k_gemm_uv(
    const float* __restrict__ z2, const float* __restrict__ Wm1,
    float* __restrict__ u, float* __restrict__ v, int N) {
  __shared__ __align__(16) float zs[OUTD][36];
  int tid = threadIdx.x;
  int node0 = blockIdx.x * 32;
  for (int i = tid; i < 32 * OUTD; i += 256) {
    int n = i >> 6, k = i & 63;
    int node = node0 + n;
    zs[k][n] = (node < N) ? z2[(size_t)node * OUTD + k] : 0.f;
  }
  __syncthreads();
  int col = tid & 63;
  int half = (tid >> 6) & 1;
  int grp = tid >> 7;
  const float* W = Wm1 + (size_t)half * 64 * OUTD;
  float acc[16];
#pragma unroll
  for (int q = 0; q < 16; q++) acc[q] = 0.f;
#pragma unroll 4
  for (int k = 0; k < OUTD; k++) {
    float w = W[k * OUTD + col];
#pragma unroll
    for (int g = 0; g < 4; g++) {
      float4 zv = *reinterpret_cast<const float4*>(&zs[k][grp * 16 + g * 4]);
      acc[g * 4 + 0] = fmaf(zv.x, w, acc[g * 4 + 0]);
      acc[g * 4 + 1] = fmaf(zv.y, w, acc[g * 4 + 1]);
      acc[g * 4 + 2] = fmaf(zv.z, w, acc[g * 4 + 2]);
      acc[g * 4 + 3] = fmaf(zv.w, w, acc[g * 4 + 3]);
    }
  }
  float* dst = half ? v : u;
#pragma unroll
  for (int q = 0; q < 16; q++) {
    int node = node0 + grp * 16 + q;
    if (node < N) dst[(size_t)node * OUTD + col] = acc[q];
  }
}

// ---------------- decoder stage B ------------------------------------------
__global__ __launch_bounds__(256) void k_link(
    const float* __restrict__ u, const float* __restrict__ v,
    const int* __restrict__ eli, int EL,
    const float* __restrict__ bm1, const float* __restrict__ Wm2,
    const float* __restrict__ bm2, float* __restrict__ out) {
  int tid = threadIdx.x, lane = tid & 63, w = tid >> 6;
  int li = lane >> 4, c4 = (lane & 15) * 4;
  int l = (blockIdx.x * 4 + w) * 4 + li;
  if (l >= EL) return;
  int a = eli[l], b = eli[EL + l];
  float4 uu = *(const float4*)(u + (size_t)a * OUTD + c4);
  float4 vv = *(const float4*)(v + (size_t)b * OUTD + c4);
  float4 bb = *(const float4*)(bm1 + c4);
  float4 ww = *(const float4*)(Wm2 + c4);
  float p = fmaxf(uu.x + vv.x + bb.x, 0.f) * ww.x
          + fmaxf(uu.y + vv.y + bb.y, 0.f) * ww.y
          + fmaxf(uu.z + vv.z + bb.z, 0.f) * ww.z
          + fmaxf(uu.w + vv.w + bb.w, 0.f) * ww.w;
  p += __shfl_xor(p, 1, 64);
  p += __shfl_xor(p, 2, 64);
  p += __shfl_xor(p, 4, 64);
  p += __shfl_xor(p, 8, 64);
  if ((lane & 15) == 0) out[l] = p + bm2[0];
}

extern "C" void kernel_launch(void* const* d_in, const int* in_sizes, int n_in,
                              void* d_out, int out_size, void* d_ws, size_t ws_size,
                              hipStream_t stream) {
  const float* x     = (const float*)d_in[0];
  const int*   ei    = (const int*)d_in[1];
  const int*   eli   = (const int*)d_in[2];
  const float* W1l   = (const float*)d_in[3];
  const float* b1l   = (const float*)d_in[4];
  const float* W1r   = (const float*)d_in[5];
  const float* b1r   = (const float*)d_in[6];
  const float* att1  = (const float*)d_in[7];
  const float* bias1 = (const float*)d_in[8];
  const float* W2l   = (const float*)d_in[9];
  const float* b2l   = (const float*)d_in[10];
  const float* W2r   = (const float*)d_in[11];
  const float* b2r   = (const float*)d_in[12];
  const float* att2  = (const float*)d_in[13];
  const float* bias2 = (const float*)d_in[14];
  const float* Wm1   = (const float*)d_in[15];
  const float* bm1   = (const float*)d_in[16];
  const float* Wm2   = (const float*)d_in[17];
  const float* bm2   = (const float*)d_in[18];

  int N = in_sizes[0] / IN_DIM;   // 50000
  int E = in_sizes[1] / 2;        // 800000
  int EL = in_sizes[2] / 2;       // 200000
  int Etot = E + N;

  // ---- workspace layout (bytes) ----
  // [0, 25.6M)        xl1h (bf16)   (layer2: xl2 f32 @0, xr2/z2 @12.8M)
  // [51.2M, 102.4M)   xr1 -> z      (decoder: u @51.2M, v @64M)
  // [102.4M, ...)     row_start, cursor, csr_src
  char* ws = (char*)d_ws;
  unsigned short* xl1h = (unsigned short*)(ws);
  float* bufB      = (float*)(ws + 51200000);
  int*   row_start = (int*)(ws + 102400000);
  int*   cursor    = (int*)(ws + 102700000);
  int*   csr_src   = (int*)(ws + 103000000);
  float* xl2       = (float*)(ws);
  float* xr2       = (float*)(ws + 12800000);
  float* u_buf     = (float*)(ws + 51200000);
  float* v_buf     = (float*)(ws + 64000000);

  // ---- CSR build (reused by both layers) ----
  hipMemsetAsync(cursor, 0, (size_t)N * 4, stream);
  k_gemm1<<<(N + 31) / 32, 256, 0, stream>>>(x, W1l, b1l, W1r, b1r, xl1h, bufB, N);
  k_hist<<<(Etot + 255) / 256, 256, 0, stream>>>(ei, E, N, cursor);
  k_scan<<<1, 1024, 0, stream>>>(cursor, row_start, cursor, N, Etot);
  k_scatter<<<(Etot + 255) / 256, 256, 0, stream>>>(ei, E, N, cursor, csr_src);

  // ---- layer 1 (fused) ----
  k_fused1<<<(N + 3) / 4, 256, 0, stream>>>(xl1h, bufB, row_start, csr_src,
                                            att1, bias1, bufB, N);
  // ---- layer 2 ----
  k_gemm2<<<(N + 31) / 32, 256, 0, stream>>>(bufB, W2l, b2l, W2r, b2r, xl2, xr2, N);
  k_fused2<<<(N + 3) / 4, 256, 0, stream>>>(xl2, xr2, row_start, csr_src,
                                            att2, bias2, xr2, N);
  // ---- decoder ----
  k_gemm_uv<<<(N + 31) / 32, 256, 0, stream>>>(xr2, Wm1, u_buf, v_buf, N);
  k_link<<<(EL + 15) / 16, 256, 0, stream>>>(u_buf, v_buf, eli, EL,
                                             bm1, Wm2, bm2, (float*)d_out);
}

// Round 7
// 441.035 us; speedup vs baseline: 4.2666x; 1.2415x over previous
//
#include <hip/hip_runtime.h>
#include <hip/hip_bf16.h>

#define IN_DIM 128
#define HID    64
#define NH     4
#define F1     256   // NH*HID
#define OUTD   64
#define NEG    0.2f

__device__ __forceinline__ float bf2f(unsigned short h) {
  return __uint_as_float((unsigned)h << 16);
}
__device__ __forceinline__ unsigned short f2bf(float f) {
  unsigned u = __float_as_uint(f);
  u += 0x7fffu + ((u >> 16) & 1u);   // RTNE
  return (unsigned short)(u >> 16);
}

// ---------------- layer-1 GEMM: xl(bf16) = x@W1l+b1l, xr(f32) = x@W1r+b1r ---
__global__ __launch_bounds__(256) void k_gemm1(
    const float* __restrict__ x,
    const float* __restrict__ Wl, const float* __restrict__ bl,
    const float* __restrict__ Wr, const float* __restrict__ br,
    unsigned short* __restrict__ xlh, float* __restrict__ xr, int n_nodes) {
  __shared__ __align__(16) float xs[IN_DIM][36];
  int tid = threadIdx.x;
  int node0 = blockIdx.x * 32;
  for (int i = tid; i < 32 * IN_DIM; i += 256) {
    int n = i >> 7, k = i & 127;
    int node = node0 + n;
    xs[k][n] = (node < n_nodes) ? x[(size_t)node * IN_DIM + k] : 0.f;
  }
  __syncthreads();
  int j = tid;
  float accl[32], accr[32];
#pragma unroll
  for (int n = 0; n < 32; n++) { accl[n] = 0.f; accr[n] = 0.f; }
#pragma unroll 2
  for (int k = 0; k < IN_DIM; k++) {
    float wl = Wl[k * F1 + j];
    float wr = Wr[k * F1 + j];
#pragma unroll
    for (int g = 0; g < 8; g++) {
      float4 xv = *reinterpret_cast<const float4*>(&xs[k][g * 4]);
      accl[g * 4 + 0] = fmaf(xv.x, wl, accl[g * 4 + 0]);
      accl[g * 4 + 1] = fmaf(xv.y, wl, accl[g * 4 + 1]);
      accl[g * 4 + 2] = fmaf(xv.z, wl, accl[g * 4 + 2]);
      accl[g * 4 + 3] = fmaf(xv.w, wl, accl[g * 4 + 3]);
      accr[g * 4 + 0] = fmaf(xv.x, wr, accr[g * 4 + 0]);
      accr[g * 4 + 1] = fmaf(xv.y, wr, accr[g * 4 + 1]);
      accr[g * 4 + 2] = fmaf(xv.z, wr, accr[g * 4 + 2]);
      accr[g * 4 + 3] = fmaf(xv.w, wr, accr[g * 4 + 3]);
    }
  }
  float blj = bl[j], brj = br[j];
#pragma unroll
  for (int n = 0; n < 32; n++) {
    int node = node0 + n;
    if (node < n_nodes) {
      xlh[(size_t)node * F1 + j] = f2bf(accl[n] + blj);
      xr[(size_t)node * F1 + j] = accr[n] + brj;
    }
  }
}

// ---------------- CSR build: histogram -> 3-stage scan -> scatter ----------
__global__ __launch_bounds__(256) void k_hist(
    const int* __restrict__ ei, int E, int N, int* __restrict__ cnt) {
  int e = blockIdx.x * 256 + threadIdx.x;
  if (e >= E + N) return;
  int d = (e < E) ? ei[E + e] : (e - E);
  atomicAdd(&cnt[d], 1);
}

// stage 1: per-block (1024 elems) exclusive prefix, in place; block sums out.
__global__ __launch_bounds__(256) void k_scan1(
    int* __restrict__ cnt, int N, int* __restrict__ blk_sum) {
  int t = threadIdx.x, lane = t & 63, wid = t >> 6;
  int base = blockIdx.x * 1024 + t * 4;
  int4 v = {0, 0, 0, 0};
  if (base + 3 < N) {
    v = *(const int4*)(cnt + base);
  } else {
    if (base + 0 < N) v.x = cnt[base + 0];
    if (base + 1 < N) v.y = cnt[base + 1];
    if (base + 2 < N) v.z = cnt[base + 2];
    if (base + 3 < N) v.w = cnt[base + 3];
  }
  int s = v.x + v.y + v.z + v.w;
  int inc = s;
#pragma unroll
  for (int off = 1; off < 64; off <<= 1) {
    int u = __shfl_up(inc, off, 64);
    if (lane >= off) inc += u;
  }
  __shared__ int wsum[4];
  if (lane == 63) wsum[wid] = inc;
  __syncthreads();
  int wofs = 0;
#pragma unroll
  for (int q = 0; q < 4; q++) if (q < wid) wofs += wsum[q];
  int excl = wofs + inc - s;
  int4 o;
  o.x = excl; o.y = excl + v.x; o.z = o.y + v.y; o.w = o.z + v.z;
  if (base + 3 < N) {
    *(int4*)(cnt + base) = o;
  } else {
    if (base + 0 < N) cnt[base + 0] = o.x;
    if (base + 1 < N) cnt[base + 1] = o.y;
    if (base + 2 < N) cnt[base + 2] = o.z;
    if (base + 3 < N) cnt[base + 3] = o.w;
  }
  if (t == 255) blk_sum[blockIdx.x] = wofs + inc;
}

// stage 2: one wave scans block sums (nblk <= 64) -> exclusive offsets.
__global__ void k_scan2(int* __restrict__ blk, int nblk) {
  int lane = threadIdx.x;
  int v = (lane < nblk) ? blk[lane] : 0;
  int inc = v;
#pragma unroll
  for (int off = 1; off < 64; off <<= 1) {
    int u = __shfl_up(inc, off, 64);
    if (lane >= off) inc += u;
  }
  if (lane < nblk) blk[lane] = inc - v;
}

// stage 3: add block offset; emit row_start + cursor.
__global__ __launch_bounds__(256) void k_scan3(
    const int* __restrict__ local_ps, const int* __restrict__ blk_sum,
    int N, int Etot, int* __restrict__ row_start, int* __restrict__ cursor) {
  int i = blockIdx.x * 256 + threadIdx.x;
  if (i < N) {
    int p = local_ps[i] + blk_sum[i >> 10];
    row_start[i] = p;
    cursor[i] = p;
  }
  if (i == 0) row_start[N] = Etot;
}

__global__ __launch_bounds__(256) void k_scatter(
    const int* __restrict__ ei, int E, int N,
    int* __restrict__ cursor, int* __restrict__ csr_src) {
  int e = blockIdx.x * 256 + threadIdx.x;
  if (e >= E + N) return;
  int s, d;
  if (e < E) { s = ei[e]; d = ei[E + e]; } else { s = e - E; d = s; }
  int pos = atomicAdd(&cursor[d], 1);
  csr_src[pos] = s;
}

// ---------------- fused layer-1 (bf16 xl gathers) ---------------------------
#define LEAKY4(v, xs, xri)                                   \
  v.x = xs.x + xri.x; v.x = v.x > 0.f ? v.x : NEG * v.x;     \
  v.y = xs.y + xri.y; v.y = v.y > 0.f ? v.y : NEG * v.y;     \
  v.z = xs.z + xri.z; v.z = v.z > 0.f ? v.z : NEG * v.z;     \
  v.w = xs.w + xri.w; v.w = v.w > 0.f ? v.w : NEG * v.w;

#define RED16(p)                 \
  p += __shfl_xor(p, 1, 64);     \
  p += __shfl_xor(p, 2, 64);     \
  p += __shfl_xor(p, 4, 64);     \
  p += __shfl_xor(p, 8, 64);

#define BF4(dst, h)                                \
  dst.x = bf2f(h.x); dst.y = bf2f(h.y);            \
  dst.z = bf2f(h.z); dst.w = bf2f(h.w);

__global__ __launch_bounds__(256) void k_fused1(
    const unsigned short* __restrict__ xlh, const float* xr,
    const int* __restrict__ row_start, const int* __restrict__ csr_src,
    const float* __restrict__ att, const float* __restrict__ bias,
    float* out, int N) {
  int tid = threadIdx.x, lane = tid & 63, w = tid >> 6;
  int i = blockIdx.x * 4 + w;
  if (i >= N) return;
  float4 xri = *(const float4*)(xr + (size_t)i * F1 + lane * 4);
  float4 a4  = *(const float4*)(att + lane * 4);
  float m = -1e30f, den = 0.f;
  float4 acc = {0.f, 0.f, 0.f, 0.f};
  int b = row_start[i], e = row_start[i + 1];
  int k = b;
  for (; k + 3 < e; k += 4) {
    int s0 = csr_src[k], s1 = csr_src[k + 1];
    int s2 = csr_src[k + 2], s3 = csr_src[k + 3];
    ushort4 h0 = *(const ushort4*)(xlh + (size_t)s0 * F1 + lane * 4);
    ushort4 h1 = *(const ushort4*)(xlh + (size_t)s1 * F1 + lane * 4);
    ushort4 h2 = *(const ushort4*)(xlh + (size_t)s2 * F1 + lane * 4);
    ushort4 h3 = *(const ushort4*)(xlh + (size_t)s3 * F1 + lane * 4);
    float4 x0, x1, x2, x3;
    BF4(x0, h0); BF4(x1, h1); BF4(x2, h2); BF4(x3, h3);
    float4 v0, v1, v2, v3;
    LEAKY4(v0, x0, xri); LEAKY4(v1, x1, xri);
    LEAKY4(v2, x2, xri); LEAKY4(v3, x3, xri);
    float p0 = v0.x * a4.x + v0.y * a4.y + v0.z * a4.z + v0.w * a4.w;
    float p1 = v1.x * a4.x + v1.y * a4.y + v1.z * a4.z + v1.w * a4.w;
    float p2 = v2.x * a4.x + v2.y * a4.y + v2.z * a4.z + v2.w * a4.w;
    float p3 = v3.x * a4.x + v3.y * a4.y + v3.z * a4.z + v3.w * a4.w;
    RED16(p0); RED16(p1); RED16(p2); RED16(p3);
    float mn = fmaxf(fmaxf(m, p0), fmaxf(fmaxf(p1, p2), p3));
    float cs = __expf(m - mn);
    float w0 = __expf(p0 - mn), w1 = __expf(p1 - mn);
    float w2 = __expf(p2 - mn), w3 = __expf(p3 - mn);
    den = den * cs + (w0 + w1) + (w2 + w3);
    acc.x = acc.x * cs + w0 * x0.x + w1 * x1.x + w2 * x2.x + w3 * x3.x;
    acc.y = acc.y * cs + w0 * x0.y + w1 * x1.y + w2 * x2.y + w3 * x3.y;
    acc.z = acc.z * cs + w0 * x0.z + w1 * x1.z + w2 * x2.z + w3 * x3.z;
    acc.w = acc.w * cs + w0 * x0.w + w1 * x1.w + w2 * x2.w + w3 * x3.w;
    m = mn;
  }
  for (; k < e; k++) {
    int s = csr_src[k];
    ushort4 hh = *(const ushort4*)(xlh + (size_t)s * F1 + lane * 4);
    float4 xs;
    BF4(xs, hh);
    float4 v;
    LEAKY4(v, xs, xri);
    float p = v.x * a4.x + v.y * a4.y + v.z * a4.z + v.w * a4.w;
    RED16(p);
    float mn = fmaxf(m, p);
    float cs = __expf(m - mn);
    float wt = __expf(p - mn);
    den = den * cs + wt;
    acc.x = acc.x * cs + wt * xs.x;
    acc.y = acc.y * cs + wt * xs.y;
    acc.z = acc.z * cs + wt * xs.z;
    acc.w = acc.w * cs + wt * xs.w;
    m = mn;
  }
  float inv = 1.f / den;
  float4 bz = *(const float4*)(bias + lane * 4);
  float4 o;
  o.x = fmaxf(acc.x * inv + bz.x, 0.f);
  o.y = fmaxf(acc.y * inv + bz.y, 0.f);
  o.z = fmaxf(acc.z * inv + bz.z, 0.f);
  o.w = fmaxf(acc.w * inv + bz.w, 0.f);
  *(float4*)(out + (size_t)i * F1 + lane * 4) = o;
}

// ---------------- layer-2 GEMM: xl2 -> bf16, xr2 -> f32 ---------------------
__global__ __launch_bounds__(256) void k_gemm2(
    const float* __restrict__ z,
    const float* __restrict__ Wl, const float* __restrict__ bl,
    const float* __restrict__ Wr, const float* __restrict__ br,
    unsigned short* __restrict__ xl2h, float* __restrict__ xr2, int n_nodes) {
  __shared__ __align__(16) float zs[F1][36];
  int tid = threadIdx.x;
  int node0 = blockIdx.x * 32;
  for (int i = tid; i < 32 * F1; i += 256) {
    int n = i >> 8, k = i & 255;
    int node = node0 + n;
    zs[k][n] = (node < n_nodes) ? z[(size_t)node * F1 + k] : 0.f;
  }
  __syncthreads();
  int col = tid & 63;
  int half = (tid >> 6) & 1;
  int grp = tid >> 7;
  const float* W = half ? Wr : Wl;
  float acc[16];
#pragma unroll
  for (int q = 0; q < 16; q++) acc[q] = 0.f;
#pragma unroll 4
  for (int k = 0; k < F1; k++) {
    float w = W[k * 64 + col];
#pragma unroll
    for (int g = 0; g < 4; g++) {
      float4 zv = *reinterpret_cast<const float4*>(&zs[k][grp * 16 + g * 4]);
      acc[g * 4 + 0] = fmaf(zv.x, w, acc[g * 4 + 0]);
      acc[g * 4 + 1] = fmaf(zv.y, w, acc[g * 4 + 1]);
      acc[g * 4 + 2] = fmaf(zv.z, w, acc[g * 4 + 2]);
      acc[g * 4 + 3] = fmaf(zv.w, w, acc[g * 4 + 3]);
    }
  }
  float b = (half ? br : bl)[col];
#pragma unroll
  for (int q = 0; q < 16; q++) {
    int node = node0 + grp * 16 + q;
    if (node < n_nodes) {
      if (half) xr2[(size_t)node * OUTD + col] = acc[q] + b;
      else      xl2h[(size_t)node * OUTD + col] = f2bf(acc[q] + b);
    }
  }
}

// ---------------- fused layer-2 (H=1, bf16 xl gathers) + bias2 --------------
#define RED64(p)                 \
  p += __shfl_xor(p, 1, 64);     \
  p += __shfl_xor(p, 2, 64);     \
  p += __shfl_xor(p, 4, 64);     \
  p += __shfl_xor(p, 8, 64);     \
  p += __shfl_xor(p, 16, 64);    \
  p += __shfl_xor(p, 32, 64);

__global__ __launch_bounds__(256) void k_fused2(
    const unsigned short* __restrict__ xlh, const float* xr,
    const int* __restrict__ row_start, const int* __restrict__ csr_src,
    const float* __restrict__ att, const float* __restrict__ bias,
    float* out, int N) {
  int tid = threadIdx.x, lane = tid & 63, w = tid >> 6;
  int i = blockIdx.x * 4 + w;
  if (i >= N) return;
  float xri = xr[(size_t)i * OUTD + lane];
  float a = att[lane];
  float m = -1e30f, den = 0.f, acc = 0.f;
  int b = row_start[i], e = row_start[i + 1];
  int k = b;
  for (; k + 3 < e; k += 4) {
    int s0 = csr_src[k], s1 = csr_src[k + 1];
    int s2 = csr_src[k + 2], s3 = csr_src[k + 3];
    float x0 = bf2f(xlh[(size_t)s0 * OUTD + lane]);
    float x1 = bf2f(xlh[(size_t)s1 * OUTD + lane]);
    float x2 = bf2f(xlh[(size_t)s2 * OUTD + lane]);
    float x3 = bf2f(xlh[(size_t)s3 * OUTD + lane]);
    float v0 = x0 + xri; v0 = v0 > 0.f ? v0 : NEG * v0;
    float v1 = x1 + xri; v1 = v1 > 0.f ? v1 : NEG * v1;
    float v2 = x2 + xri; v2 = v2 > 0.f ? v2 : NEG * v2;
    float v3 = x3 + xri; v3 = v3 > 0.f ? v3 : NEG * v3;
    float p0 = v0 * a, p1 = v1 * a, p2 = v2 * a, p3 = v3 * a;
    RED64(p0); RED64(p1); RED64(p2); RED64(p3);
    float mn = fmaxf(fmaxf(m, p0), fmaxf(fmaxf(p1, p2), p3));
    float cs = __expf(m - mn);
    float w0 = __expf(p0 - mn), w1 = __expf(p1 - mn);
    float w2 = __expf(p2 - mn), w3 = __expf(p3 - mn);
    den = den * cs + (w0 + w1) + (w2 + w3);
    acc = acc * cs + w0 * x0 + w1 * x1 + w2 * x2 + w3 * x3;
    m = mn;
  }
  for (; k < e; k++) {
    int s = csr_src[k];
    float xs = bf2f(xlh[(size_t)s * OUTD + lane]);
    float v = xs + xri;
    v = v > 0.f ? v : NEG * v;
    float p = v * a;
    RED64(p);
    float mn = fmaxf(m, p);
    float cs = __expf(m - mn);
    float wt = __expf(p - mn);
    den = den * cs + wt;
    acc = acc * cs + wt * xs;
    m = mn;
  }
  out[(size_t)i * OUTD + lane] = acc / den + bias[lane];
}

// ---------------- decoder stage A ------------------------------------------
__global__ __launch_bounds__(256) void k_gemm_uv(
    const float* __restrict__ z2, const float* __restrict__ Wm1,
    float* __restrict__ u, float* __restrict__ v, int N) {
  __shared__ __align__(16) float zs[OUTD][36];
  int tid = threadIdx.x;
  int node0 = blockIdx.x * 32;
  for (int i = tid; i < 32 * OUTD; i += 256) {
    int n = i >> 6, k = i & 63;
    int node = node0 + n;
    zs[k][n] = (node < N) ? z2[(size_t)node * OUTD + k] : 0.f;
  }
  __syncthreads();
  int col = tid & 63;
  int half = (tid >> 6) & 1;
  int grp = tid >> 7;
  const float* W = Wm1 + (size_t)half * 64 * OUTD;
  float acc[16];
#pragma unroll
  for (int q = 0; q < 16; q++) acc[q] = 0.f;
#pragma unroll 4
  for (int k = 0; k < OUTD; k++) {
    float w = W[k * OUTD + col];
#pragma unroll
    for (int g = 0; g < 4; g++) {
      float4 zv = *reinterpret_cast<const float4*>(&zs[k][grp * 16 + g * 4]);
      acc[g * 4 + 0] = fmaf(zv.x, w, acc[g * 4 + 0]);
      acc[g * 4 + 1] = fmaf(zv.y, w, acc[g * 4 + 1]);
      acc[g * 4 + 2] = fmaf(zv.z, w, acc[g * 4 + 2]);
      acc[g * 4 + 3] = fmaf(zv.w, w, acc[g * 4 + 3]);
    }
  }
  float* dst = half ? v : u;
#pragma unroll
  for (int q = 0; q < 16; q++) {
    int node = node0 + grp * 16 + q;
    if (node < N) dst[(size_t)node * OUTD + col] = acc[q];
  }
}

// ---------------- decoder stage B ------------------------------------------
__global__ __launch_bounds__(256) void k_link(
    const float* __restrict__ u, const float* __restrict__ v,
    const int* __restrict__ eli, int EL,
    const float* __restrict__ bm1, const float* __restrict__ Wm2,
    const float* __restrict__ bm2, float* __restrict__ out) {
  int tid = threadIdx.x, lane = tid & 63, w = tid >> 6;
  int li = lane >> 4, c4 = (lane & 15) * 4;
  int l = (blockIdx.x * 4 + w) * 4 + li;
  if (l >= EL) return;
  int a = eli[l], b = eli[EL + l];
  float4 uu = *(const float4*)(u + (size_t)a * OUTD + c4);
  float4 vv = *(const float4*)(v + (size_t)b * OUTD + c4);
  float4 bb = *(const float4*)(bm1 + c4);
  float4 ww = *(const float4*)(Wm2 + c4);
  float p = fmaxf(uu.x + vv.x + bb.x, 0.f) * ww.x
          + fmaxf(uu.y + vv.y + bb.y, 0.f) * ww.y
          + fmaxf(uu.z + vv.z + bb.z, 0.f) * ww.z
          + fmaxf(uu.w + vv.w + bb.w, 0.f) * ww.w;
  p += __shfl_xor(p, 1, 64);
  p += __shfl_xor(p, 2, 64);
  p += __shfl_xor(p, 4, 64);
  p += __shfl_xor(p, 8, 64);
  if ((lane & 15) == 0) out[l] = p + bm2[0];
}

extern "C" void kernel_launch(void* const* d_in, const int* in_sizes, int n_in,
                              void* d_out, int out_size, void* d_ws, size_t ws_size,
                              hipStream_t stream) {
  const float* x     = (const float*)d_in[0];
  const int*   ei    = (const int*)d_in[1];
  const int*   eli   = (const int*)d_in[2];
  const float* W1l   = (const float*)d_in[3];
  const float* b1l   = (const float*)d_in[4];
  const float* W1r   = (const float*)d_in[5];
  const float* b1r   = (const float*)d_in[6];
  const float* att1  = (const float*)d_in[7];
  const float* bias1 = (const float*)d_in[8];
  const float* W2l   = (const float*)d_in[9];
  const float* b2l   = (const float*)d_in[10];
  const float* W2r   = (const float*)d_in[11];
  const float* b2r   = (const float*)d_in[12];
  const float* att2  = (const float*)d_in[13];
  const float* bias2 = (const float*)d_in[14];
  const float* Wm1   = (const float*)d_in[15];
  const float* bm1   = (const float*)d_in[16];
  const float* Wm2   = (const float*)d_in[17];
  const float* bm2   = (const float*)d_in[18];

  int N = in_sizes[0] / IN_DIM;   // 50000
  int E = in_sizes[1] / 2;        // 800000
  int EL = in_sizes[2] / 2;       // 200000
  int Etot = E + N;

  // ---- workspace layout (bytes) ----
  // [0, 25.6M)        xl1h (bf16)   (layer2: xl2h bf16 @0, xr2/z2 f32 @12.8M)
  // [51.2M, 102.4M)   xr1 -> z      (decoder: u @51.2M, v @64M)
  // [102.4M ...)      row_start, cursor(=cnt=local_ps), csr_src, blk_sum
  char* ws = (char*)d_ws;
  unsigned short* xl1h = (unsigned short*)(ws);
  float* bufB      = (float*)(ws + 51200000);
  int*   row_start = (int*)(ws + 102400000);
  int*   cursor    = (int*)(ws + 102700000);
  int*   csr_src   = (int*)(ws + 103000000);
  int*   blk_sum   = (int*)(ws + 103000000 + (size_t)Etot * 4 + 256);
  unsigned short* xl2h = (unsigned short*)(ws);
  float* xr2       = (float*)(ws + 12800000);
  float* u_buf     = (float*)(ws + 51200000);
  float* v_buf     = (float*)(ws + 64000000);

  int nblk = (N + 1023) / 1024;   // 49 (<=64 required by k_scan2)

  // ---- CSR build (reused by both layers) ----
  hipMemsetAsync(cursor, 0, (size_t)N * 4, stream);
  k_gemm1<<<(N + 31) / 32, 256, 0, stream>>>(x, W1l, b1l, W1r, b1r, xl1h, bufB, N);
  k_hist<<<(Etot + 255) / 256, 256, 0, stream>>>(ei, E, N, cursor);
  k_scan1<<<nblk, 256, 0, stream>>>(cursor, N, blk_sum);
  k_scan2<<<1, 64, 0, stream>>>(blk_sum, nblk);
  k_scan3<<<(N + 255) / 256, 256, 0, stream>>>(cursor, blk_sum, N, Etot,
                                               row_start, cursor);
  k_scatter<<<(Etot + 255) / 256, 256, 0, stream>>>(ei, E, N, cursor, csr_src);

  // ---- layer 1 (fused) ----
  k_fused1<<<(N + 3) / 4, 256, 0, stream>>>(xl1h, bufB, row_start, csr_src,
                                            att1, bias1, bufB, N);
  // ---- layer 2 ----
  k_gemm2<<<(N + 31) / 32, 256, 0, stream>>>(bufB, W2l, b2l, W2r, b2r, xl2h, xr2, N);
  k_fused2<<<(N + 3) / 4, 256, 0, stream>>>(xl2h, xr2, row_start, csr_src,
                                            att2, bias2, xr2, N);
  // ---- decoder ----
  k_gemm_uv<<<(N + 31) / 32, 256, 0, stream>>>(xr2, Wm1, u_buf, v_buf, N);
  k_link<<<(EL + 15) / 16, 256, 0, stream>>>(u_buf, v_buf, eli, EL,
                                             bm1, Wm2, bm2, (float*)d_out);
}

// Round 8
// 427.999 us; speedup vs baseline: 4.3965x; 1.0305x over previous
//
#include <hip/hip_runtime.h>
#include <hip/hip_bf16.h>

#define IN_DIM 128
#define HID    64
#define NH     4
#define F1     256   // NH*HID
#define OUTD   64
#define NEG    0.2f

typedef __attribute__((ext_vector_type(8))) short bf16x8;
typedef __attribute__((ext_vector_type(4))) float f32x4;

__device__ __forceinline__ float bf2f(unsigned short h) {
  return __uint_as_float((unsigned)h << 16);
}
__device__ __forceinline__ unsigned short f2bf(float f) {
  unsigned u = __float_as_uint(f);
  u += 0x7fffu + ((u >> 16) & 1u);   // RTNE
  return (unsigned short)(u >> 16);
}

// ---------------- conversions for MFMA GEMM1 --------------------------------
__global__ __launch_bounds__(256) void k_cvt_x(
    const float* __restrict__ x, unsigned short* __restrict__ xb, int total4) {
  int idx = blockIdx.x * 256 + threadIdx.x;
  if (idx >= total4) return;
  float4 v = *(const float4*)(x + (size_t)idx * 4);
  ushort4 o;
  o.x = f2bf(v.x); o.y = f2bf(v.y); o.z = f2bf(v.z); o.w = f2bf(v.w);
  *(ushort4*)(xb + (size_t)idx * 4) = o;
}

// Wt[c][k] (bf16, c in [0,512)) = c<256 ? W1l[k][c] : W1r[k][c-256]
__global__ __launch_bounds__(256) void k_cvt_w(
    const float* __restrict__ Wl, const float* __restrict__ Wr,
    unsigned short* __restrict__ Wt) {
  int idx = blockIdx.x * 256 + threadIdx.x;   // 512*128 total
  if (idx >= 512 * IN_DIM) return;
  int c = idx >> 7, k = idx & 127;
  float v = (c < F1) ? Wl[k * F1 + c] : Wr[k * F1 + (c - F1)];
  Wt[idx] = f2bf(v);
}

// ---------------- layer-1 GEMM via MFMA: [N,128]x[128,512] bf16 -------------
// Block: 64 nodes x 64 cols, 4 waves; wave w owns nodes [node0+w*16, +16).
// A-frag: row=lane&15, k=(lane>>4)*8+i (16B contiguous from xb row).
// B-frag: col=lane&15, k=(lane>>4)*8+i (16B contiguous from Wt row).
// C/D:    col=lane&15, row=(lane>>4)*4+reg.
__global__ __launch_bounds__(256) void k_gemm1_mfma(
    const unsigned short* __restrict__ xb, const unsigned short* __restrict__ Wt,
    const float* __restrict__ bl, const float* __restrict__ br,
    unsigned short* __restrict__ xlh, float* __restrict__ xr, int N) {
  int tid = threadIdx.x, lane = tid & 63, w = tid >> 6;
  int node0 = blockIdx.x * 64 + w * 16;
  int colbase = blockIdx.y * 64;
  int arow = node0 + (lane & 15); if (arow >= N) arow = N - 1;
  int koff = (lane >> 4) * 8;
  const unsigned short* ap = xb + (size_t)arow * IN_DIM + koff;
  bf16x8 a0 = *(const bf16x8*)(ap);
  bf16x8 a1 = *(const bf16x8*)(ap + 32);
  bf16x8 a2 = *(const bf16x8*)(ap + 64);
  bf16x8 a3 = *(const bf16x8*)(ap + 96);
#pragma unroll
  for (int ct = 0; ct < 4; ct++) {
    int col = colbase + ct * 16 + (lane & 15);
    const unsigned short* bp = Wt + (size_t)col * IN_DIM + koff;
    f32x4 acc = {0.f, 0.f, 0.f, 0.f};
    acc = __builtin_amdgcn_mfma_f32_16x16x32_bf16(a0, *(const bf16x8*)(bp), acc, 0, 0, 0);
    acc = __builtin_amdgcn_mfma_f32_16x16x32_bf16(a1, *(const bf16x8*)(bp + 32), acc, 0, 0, 0);
    acc = __builtin_amdgcn_mfma_f32_16x16x32_bf16(a2, *(const bf16x8*)(bp + 64), acc, 0, 0, 0);
    acc = __builtin_amdgcn_mfma_f32_16x16x32_bf16(a3, *(const bf16x8*)(bp + 96), acc, 0, 0, 0);
    if (col < F1) {            // wave-uniform branch (16-col tiles)
      float bias = bl[col];
#pragma unroll
      for (int i = 0; i < 4; i++) {
        int node = node0 + ((lane >> 4) << 2) + i;
        if (node < N) xlh[(size_t)node * F1 + col] = f2bf(acc[i] + bias);
      }
    } else {
      float bias = br[col - F1];
#pragma unroll
      for (int i = 0; i < 4; i++) {
        int node = node0 + ((lane >> 4) << 2) + i;
        if (node < N) xr[(size_t)node * F1 + (col - F1)] = acc[i] + bias;
      }
    }
  }
}

// ---------------- CSR build: histogram -> 3-stage scan -> scatter ----------
__global__ __launch_bounds__(256) void k_hist(
    const int* __restrict__ ei, int E, int N, int* __restrict__ cnt) {
  int e = blockIdx.x * 256 + threadIdx.x;
  if (e >= E + N) return;
  int d = (e < E) ? ei[E + e] : (e - E);
  atomicAdd(&cnt[d], 1);
}

__global__ __launch_bounds__(256) void k_scan1(
    int* __restrict__ cnt, int N, int* __restrict__ blk_sum) {
  int t = threadIdx.x, lane = t & 63, wid = t >> 6;
  int base = blockIdx.x * 1024 + t * 4;
  int4 v = {0, 0, 0, 0};
  if (base + 3 < N) {
    v = *(const int4*)(cnt + base);
  } else {
    if (base + 0 < N) v.x = cnt[base + 0];
    if (base + 1 < N) v.y = cnt[base + 1];
    if (base + 2 < N) v.z = cnt[base + 2];
    if (base + 3 < N) v.w = cnt[base + 3];
  }
  int s = v.x + v.y + v.z + v.w;
  int inc = s;
#pragma unroll
  for (int off = 1; off < 64; off <<= 1) {
    int u = __shfl_up(inc, off, 64);
    if (lane >= off) inc += u;
  }
  __shared__ int wsum[4];
  if (lane == 63) wsum[wid] = inc;
  __syncthreads();
  int wofs = 0;
#pragma unroll
  for (int q = 0; q < 4; q++) if (q < wid) wofs += wsum[q];
  int excl = wofs + inc - s;
  int4 o;
  o.x = excl; o.y = excl + v.x; o.z = o.y + v.y; o.w = o.z + v.z;
  if (base + 3 < N) {
    *(int4*)(cnt + base) = o;
  } else {
    if (base + 0 < N) cnt[base + 0] = o.x;
    if (base + 1 < N) cnt[base + 1] = o.y;
    if (base + 2 < N) cnt[base + 2] = o.z;
    if (base + 3 < N) cnt[base + 3] = o.w;
  }
  if (t == 255) blk_sum[blockIdx.x] = wofs + inc;
}

__global__ void k_scan2(int* __restrict__ blk, int nblk) {
  int lane = threadIdx.x;
  int v = (lane < nblk) ? blk[lane] : 0;
  int inc = v;
#pragma unroll
  for (int off = 1; off < 64; off <<= 1) {
    int u = __shfl_up(inc, off, 64);
    if (lane >= off) inc += u;
  }
  if (lane < nblk) blk[lane] = inc - v;
}

__global__ __launch_bounds__(256) void k_scan3(
    const int* __restrict__ local_ps, const int* __restrict__ blk_sum,
    int N, int Etot, int* __restrict__ row_start, int* __restrict__ cursor) {
  int i = blockIdx.x * 256 + threadIdx.x;
  if (i < N) {
    int p = local_ps[i] + blk_sum[i >> 10];
    row_start[i] = p;
    cursor[i] = p;
  }
  if (i == 0) row_start[N] = Etot;
}

__global__ __launch_bounds__(256) void k_scatter(
    const int* __restrict__ ei, int E, int N,
    int* __restrict__ cursor, int* __restrict__ csr_src) {
  int e = blockIdx.x * 256 + threadIdx.x;
  if (e >= E + N) return;
  int s, d;
  if (e < E) { s = ei[e]; d = ei[E + e]; } else { s = e - E; d = s; }
  int pos = atomicAdd(&cursor[d], 1);
  csr_src[pos] = s;
}

// ---------------- fused layer-1 (bf16 xl gathers) ---------------------------
#define LEAKY4(v, xs, xri)                                   \
  v.x = xs.x + xri.x; v.x = v.x > 0.f ? v.x : NEG * v.x;     \
  v.y = xs.y + xri.y; v.y = v.y > 0.f ? v.y : NEG * v.y;     \
  v.z = xs.z + xri.z; v.z = v.z > 0.f ? v.z : NEG * v.z;     \
  v.w = xs.w + xri.w; v.w = v.w > 0.f ? v.w : NEG * v.w;

#define RED16(p)                 \
  p += __shfl_xor(p, 1, 64);     \
  p += __shfl_xor(p, 2, 64);     \
  p += __shfl_xor(p, 4, 64);     \
  p += __shfl_xor(p, 8, 64);

#define BF4(dst, h)                                \
  dst.x = bf2f(h.x); dst.y = bf2f(h.y);            \
  dst.z = bf2f(h.z); dst.w = bf2f(h.w);

__global__ __launch_bounds__(256) void k_fused1(
    const unsigned short* __restrict__ xlh, const float* xr,
    const int* __restrict__ row_start, const int* __restrict__ csr_src,
    const float* __restrict__ att, const float* __restrict__ bias,
    float* out, int N) {
  int tid = threadIdx.x, lane = tid & 63, w = tid >> 6;
  int i = blockIdx.x * 4 + w;
  if (i >= N) return;
  float4 xri = *(const float4*)(xr + (size_t)i * F1 + lane * 4);
  float4 a4  = *(const float4*)(att + lane * 4);
  float m = -1e30f, den = 0.f;
  float4 acc = {0.f, 0.f, 0.f, 0.f};
  int b = row_start[i], e = row_start[i + 1];
  int k = b;
  for (; k + 3 < e; k += 4) {
    int s0 = csr_src[k], s1 = csr_src[k + 1];
    int s2 = csr_src[k + 2], s3 = csr_src[k + 3];
    ushort4 h0 = *(const ushort4*)(xlh + (size_t)s0 * F1 + lane * 4);
    ushort4 h1 = *(const ushort4*)(xlh + (size_t)s1 * F1 + lane * 4);
    ushort4 h2 = *(const ushort4*)(xlh + (size_t)s2 * F1 + lane * 4);
    ushort4 h3 = *(const ushort4*)(xlh + (size_t)s3 * F1 + lane * 4);
    float4 x0, x1, x2, x3;
    BF4(x0, h0); BF4(x1, h1); BF4(x2, h2); BF4(x3, h3);
    float4 v0, v1, v2, v3;
    LEAKY4(v0, x0, xri); LEAKY4(v1, x1, xri);
    LEAKY4(v2, x2, xri); LEAKY4(v3, x3, xri);
    float p0 = v0.x * a4.x + v0.y * a4.y + v0.z * a4.z + v0.w * a4.w;
    float p1 = v1.x * a4.x + v1.y * a4.y + v1.z * a4.z + v1.w * a4.w;
    float p2 = v2.x * a4.x + v2.y * a4.y + v2.z * a4.z + v2.w * a4.w;
    float p3 = v3.x * a4.x + v3.y * a4.y + v3.z * a4.z + v3.w * a4.w;
    RED16(p0); RED16(p1); RED16(p2); RED16(p3);
    float mn = fmaxf(fmaxf(m, p0), fmaxf(fmaxf(p1, p2), p3));
    float cs = __expf(m - mn);
    float w0 = __expf(p0 - mn), w1 = __expf(p1 - mn);
    float w2 = __expf(p2 - mn), w3 = __expf(p3 - mn);
    den = den * cs + (w0 + w1) + (w2 + w3);
    acc.x = acc.x * cs + w0 * x0.x + w1 * x1.x + w2 * x2.x + w3 * x3.x;
    acc.y = acc.y * cs + w0 * x0.y + w1 * x1.y + w2 * x2.y + w3 * x3.y;
    acc.z = acc.z * cs + w0 * x0.z + w1 * x1.z + w2 * x2.z + w3 * x3.z;
    acc.w = acc.w * cs + w0 * x0.w + w1 * x1.w + w2 * x2.w + w3 * x3.w;
    m = mn;
  }
  for (; k < e; k++) {
    int s = csr_src[k];
    ushort4 hh = *(const ushort4*)(xlh + (size_t)s * F1 + lane * 4);
    float4 xs;
    BF4(xs, hh);
    float4 v;
    LEAKY4(v, xs, xri);
    float p = v.x * a4.x + v.y * a4.y + v.z * a4.z + v.w * a4.w;
    RED16(p);
    float mn = fmaxf(m, p);
    float cs = __expf(m - mn);
    float wt = __expf(p - mn);
    den = den * cs + wt;
    acc.x = acc.x * cs + wt * xs.x;
    acc.y = acc.y * cs + wt * xs.y;
    acc.z = acc.z * cs + wt * xs.z;
    acc.w = acc.w * cs + wt * xs.w;
    m = mn;
  }
  float inv = 1.f / den;
  float4 bz = *(const float4*)(bias + lane * 4);
  float4 o;
  o.x = fmaxf(acc.x * inv + bz.x, 0.f);
  o.y = fmaxf(acc.y * inv + bz.y, 0.f);
  o.z = fmaxf(acc.z * inv + bz.z, 0.f);
  o.w = fmaxf(acc.w * inv + bz.w, 0.f);
  *(float4*)(out + (size_t)i * F1 + lane * 4) = o;
}

// ---------------- layer-2 GEMM: xl2 -> bf16, xr2 -> f32 ---------------------
__global__ __launch_bounds__(256) void k_gemm2(
    const float* __restrict__ z,
    const float* __restrict__ Wl, const float* __restrict__ bl,
    const float* __restrict__ Wr, const float* __restrict__ br,
    unsigned short* __restrict__ xl2h, float* __restrict__ xr2, int n_nodes) {
  __shared__ __align__(16) float zs[F1][36];
  int tid = threadIdx.x;
  int node0 = blockIdx.x * 32;
  for (int i = tid; i < 32 * F1; i += 256) {
    int n = i >> 8, k = i & 255;
    int node = node0 + n;
    zs[k][n] = (node < n_nodes) ? z[(size_t)node * F1 + k] : 0.f;
  }
  __syncthreads();
  int col = tid & 63;
  int half = (tid >> 6) & 1;
  int grp = tid >> 7;
  const float* W = half ? Wr : Wl;
  float acc[16];
#pragma unroll
  for (int q = 0; q < 16; q++) acc[q] = 0.f;
#pragma unroll 4
  for (int k = 0; k < F1; k++) {
    float w = W[k * 64 + col];
#pragma unroll
    for (int g = 0; g < 4; g++) {
      float4 zv = *reinterpret_cast<const float4*>(&zs[k][grp * 16 + g * 4]);
      acc[g * 4 + 0] = fmaf(zv.x, w, acc[g * 4 + 0]);
      acc[g * 4 + 1] = fmaf(zv.y, w, acc[g * 4 + 1]);
      acc[g * 4 + 2] = fmaf(zv.z, w, acc[g * 4 + 2]);
      acc[g * 4 + 3] = fmaf(zv.w, w, acc[g * 4 + 3]);
    }
  }
  float b = (half ? br : bl)[col];
#pragma unroll
  for (int q = 0; q < 16; q++) {
    int node = node0 + grp * 16 + q;
    if (node < n_nodes) {
      if (half) xr2[(size_t)node * OUTD + col] = acc[q] + b;
      else      xl2h[(size_t)node * OUTD + col] = f2bf(acc[q] + b);
    }
  }
}

// ---------------- fused layer-2 (H=1, bf16 xl gathers) + bias2 --------------
#define RED64(p)                 \
  p += __shfl_xor(p, 1, 64);     \
  p += __shfl_xor(p, 2, 64);     \
  p += __shfl_xor(p, 4, 64);     \
  p += __shfl_xor(p, 8, 64);     \
  p += __shfl_xor(p, 16, 64);    \
  p += __shfl_xor(p, 32, 64);

__global__ __launch_bounds__(256) void k_fused2(
    const unsigned short* __restrict__ xlh, const float* xr,
    const int* __restrict__ row_start, const int* __restrict__ csr_src,
    const float* __restrict__ att, const float* __restrict__ bias,
    float* out, int N) {
  int tid = threadIdx.x, lane = tid & 63, w = tid >> 6;
  int i = blockIdx.x * 4 + w;
  if (i >= N) return;
  float xri = xr[(size_t)i * OUTD + lane];
  float a = att[lane];
  float m = -1e30f, den = 0.f, acc = 0.f;
  int b = row_start[i], e = row_start[i + 1];
  int k = b;
  for (; k + 3 < e; k += 4) {
    int s0 = csr_src[k], s1 = csr_src[k + 1];
    int s2 = csr_src[k + 2], s3 = csr_src[k + 3];
    float x0 = bf2f(xlh[(size_t)s0 * OUTD + lane]);
    float x1 = bf2f(xlh[(size_t)s1 * OUTD + lane]);
    float x2 = bf2f(xlh[(size_t)s2 * OUTD + lane]);
    float x3 = bf2f(xlh[(size_t)s3 * OUTD + lane]);
    float v0 = x0 + xri; v0 = v0 > 0.f ? v0 : NEG * v0;
    float v1 = x1 + xri; v1 = v1 > 0.f ? v1 : NEG * v1;
    float v2 = x2 + xri; v2 = v2 > 0.f ? v2 : NEG * v2;
    float v3 = x3 + xri; v3 = v3 > 0.f ? v3 : NEG * v3;
    float p0 = v0 * a, p1 = v1 * a, p2 = v2 * a, p3 = v3 * a;
    RED64(p0); RED64(p1); RED64(p2); RED64(p3);
    float mn = fmaxf(fmaxf(m, p0), fmaxf(fmaxf(p1, p2), p3));
    float cs = __expf(m - mn);
    float w0 = __expf(p0 - mn), w1 = __expf(p1 - mn);
    float w2 = __expf(p2 - mn), w3 = __expf(p3 - mn);
    den = den * cs + (w0 + w1) + (w2 + w3);
    acc = acc * cs + w0 * x0 + w1 * x1 + w2 * x2 + w3 * x3;
    m = mn;
  }
  for (; k < e; k++) {
    int s = csr_src[k];
    float xs = bf2f(xlh[(size_t)s * OUTD + lane]);
    float v = xs + xri;
    v = v > 0.f ? v : NEG * v;
    float p = v * a;
    RED64(p);
    float mn = fmaxf(m, p);
    float cs = __expf(m - mn);
    float wt = __expf(p - mn);
    den = den * cs + wt;
    acc = acc * cs + wt * xs;
    m = mn;
  }
  out[(size_t)i * OUTD + lane] = acc / den + bias[lane];
}

// ---------------- decoder stage A ------------------------------------------
__global__ __launch_bounds__(256) void k_gemm_uv(
    const float* __restrict__ z2, const float* __restrict__ Wm1,
    float* __restrict__ u, float* __restrict__ v, int N) {
  __shared__ __align__(16) float zs[OUTD][36];
  int tid = threadIdx.x;
  int node0 = blockIdx.x * 32;
  for (int i = tid; i < 32 * OUTD; i += 256) {
    int n = i >> 6, k = i & 63;
    int node = node0 + n;
    zs[k][n] = (node < N) ? z2[(size_t)node * OUTD + k] : 0.f;
  }
  __syncthreads();
  int col = tid & 63;
  int half = (tid >> 6) & 1;
  int grp = tid >> 7;
  const float* W = Wm1 + (size_t)half * 64 * OUTD;
  float acc[16];
#pragma unroll
  for (int q = 0; q < 16; q++) acc[q] = 0.f;
#pragma unroll 4
  for (int k = 0; k < OUTD; k++) {
    float w = W[k * OUTD + col];
#pragma unroll
    for (int g = 0; g < 4; g++) {
      float4 zv = *reinterpret_cast<const float4*>(&zs[k][grp * 16 + g * 4]);
      acc[g * 4 + 0] = fmaf(zv.x, w, acc[g * 4 + 0]);
      acc[g * 4 + 1] = fmaf(zv.y, w, acc[g * 4 + 1]);
      acc[g * 4 + 2] = fmaf(zv.z, w, acc[g * 4 + 2]);
      acc[g * 4 + 3] = fmaf(zv.w, w, acc[g * 4 + 3]);
    }
  }
  float* dst = half ? v : u;
#pragma unroll
  for (int q = 0; q < 16; q++) {
    int node = node0 + grp * 16 + q;
    if (node < N) dst[(size_t)node * OUTD + col] = acc[q];
  }
}

// ---------------- decoder stage B ------------------------------------------
__global__ __launch_bounds__(256) void k_link(
    const float* __restrict__ u, const float* __restrict__ v,
    const int* __restrict__ eli, int EL,
    const float* __restrict__ bm1, const float* __restrict__ Wm2,
    const float* __restrict__ bm2, float* __restrict__ out) {
  int tid = threadIdx.x, lane = tid & 63, w = tid >> 6;
  int li = lane >> 4, c4 = (lane & 15) * 4;
  int l = (blockIdx.x * 4 + w) * 4 + li;
  if (l >= EL) return;
  int a = eli[l], b = eli[EL + l];
  float4 uu = *(const float4*)(u + (size_t)a * OUTD + c4);
  float4 vv = *(const float4*)(v + (size_t)b * OUTD + c4);
  float4 bb = *(const float4*)(bm1 + c4);
  float4 ww = *(const float4*)(Wm2 + c4);
  float p = fmaxf(uu.x + vv.x + bb.x, 0.f) * ww.x
          + fmaxf(uu.y + vv.y + bb.y, 0.f) * ww.y
          + fmaxf(uu.z + vv.z + bb.z, 0.f) * ww.z
          + fmaxf(uu.w + vv.w + bb.w, 0.f) * ww.w;
  p += __shfl_xor(p, 1, 64);
  p += __shfl_xor(p, 2, 64);
  p += __shfl_xor(p, 4, 64);
  p += __shfl_xor(p, 8, 64);
  if ((lane & 15) == 0) out[l] = p + bm2[0];
}

extern "C" void kernel_launch(void* const* d_in, const int* in_sizes, int n_in,
                              void* d_out, int out_size, void* d_ws, size_t ws_size,
                              hipStream_t stream) {
  const float* x     = (const float*)d_in[0];
  const int*   ei    = (const int*)d_in[1];
  const int*   eli   = (const int*)d_in[2];
  const float* W1l   = (const float*)d_in[3];
  const float* b1l   = (const float*)d_in[4];
  const float* W1r   = (const float*)d_in[5];
  const float* b1r   = (const float*)d_in[6];
  const float* att1  = (const float*)d_in[7];
  const float* bias1 = (const float*)d_in[8];
  const float* W2l   = (const float*)d_in[9];
  const float* b2l   = (const float*)d_in[10];
  const float* W2r   = (const float*)d_in[11];
  const float* b2r   = (const float*)d_in[12];
  const float* att2  = (const float*)d_in[13];
  const float* bias2 = (const float*)d_in[14];
  const float* Wm1   = (const float*)d_in[15];
  const float* bm1   = (const float*)d_in[16];
  const float* Wm2   = (const float*)d_in[17];
  const float* bm2   = (const float*)d_in[18];

  int N = in_sizes[0] / IN_DIM;   // 50000
  int E = in_sizes[1] / 2;        // 800000
  int EL = in_sizes[2] / 2;       // 200000
  int Etot = E + N;

  // ---- workspace layout (bytes) ----
  // [0, 25.6M)        xl1h (bf16)   (layer2: xl2h bf16 @0, xr2/z2 f32 @12.8M)
  // [25.6M, 38.4M)    xb (bf16 x)   (only live before/during gemm1)
  // [38.4M, 38.6M)    Wt (bf16 weights, transposed)
  // [51.2M, 102.4M)   xr1 -> z      (decoder: u @51.2M, v @64M)
  // [102.4M ...)      row_start, cursor(=cnt=local_ps), csr_src, blk_sum
  char* ws = (char*)d_ws;
  unsigned short* xl1h = (unsigned short*)(ws);
  unsigned short* xb   = (unsigned short*)(ws + 25600000);
  unsigned short* Wt   = (unsigned short*)(ws + 38400000);
  float* bufB      = (float*)(ws + 51200000);
  int*   row_start = (int*)(ws + 102400000);
  int*   cursor    = (int*)(ws + 102700000);
  int*   csr_src   = (int*)(ws + 103000000);
  int*   blk_sum   = (int*)(ws + 103000000 + (size_t)Etot * 4 + 256);
  unsigned short* xl2h = (unsigned short*)(ws);
  float* xr2       = (float*)(ws + 12800000);
  float* u_buf     = (float*)(ws + 51200000);
  float* v_buf     = (float*)(ws + 64000000);

  int nblk = (N + 1023) / 1024;   // 49 (<=64 required by k_scan2)

  // ---- conversions + CSR build ----
  hipMemsetAsync(cursor, 0, (size_t)N * 4, stream);
  k_cvt_x<<<(N * IN_DIM / 4 + 255) / 256, 256, 0, stream>>>(x, xb, N * IN_DIM / 4);
  k_cvt_w<<<(512 * IN_DIM + 255) / 256, 256, 0, stream>>>(W1l, W1r, Wt);
  {
    dim3 g1((N + 63) / 64, 8);
    k_gemm1_mfma<<<g1, 256, 0, stream>>>(xb, Wt, b1l, b1r, xl1h, bufB, N);
  }
  k_hist<<<(Etot + 255) / 256, 256, 0, stream>>>(ei, E, N, cursor);
  k_scan1<<<nblk, 256, 0, stream>>>(cursor, N, blk_sum);
  k_scan2<<<1, 64, 0, stream>>>(blk_sum, nblk);
  k_scan3<<<(N + 255) / 256, 256, 0, stream>>>(cursor, blk_sum, N, Etot,
                                               row_start, cursor);
  k_scatter<<<(Etot + 255) / 256, 256, 0, stream>>>(ei, E, N, cursor, csr_src);

  // ---- layer 1 (fused) ----
  k_fused1<<<(N + 3) / 4, 256, 0, stream>>>(xl1h, bufB, row_start, csr_src,
                                            att1, bias1, bufB, N);
  // ---- layer 2 ----
  k_gemm2<<<(N + 31) / 32, 256, 0, stream>>>(bufB, W2l, b2l, W2r, b2r, xl2h, xr2, N);
  k_fused2<<<(N + 3) / 4, 256, 0, stream>>>(xl2h, xr2, row_start, csr_src,
                                            att2, bias2, xr2, N);
  // ---- decoder ----
  k_gemm_uv<<<(N + 31) / 32, 256, 0, stream>>>(xr2, Wm1, u_buf, v_buf, N);
  k_link<<<(EL + 15) / 16, 256, 0, stream>>>(u_buf, v_buf, eli, EL,
                                             bm1, Wm2, bm2, (float*)d_out);
}

// Round 9
// 389.144 us; speedup vs baseline: 4.8355x; 1.0998x over previous
//
#include <hip/hip_runtime.h>
#include <hip/hip_bf16.h>

#define IN_DIM 128
#define HID    64
#define NH     4
#define F1     256   // NH*HID
#define OUTD   64
#define NEG    0.2f

typedef __attribute__((ext_vector_type(8))) short bf16x8;
typedef __attribute__((ext_vector_type(4))) float f32x4;

__device__ __forceinline__ float bf2f(unsigned short h) {
  return __uint_as_float((unsigned)h << 16);
}
__device__ __forceinline__ unsigned short f2bf(float f) {
  unsigned u = __float_as_uint(f);
  u += 0x7fffu + ((u >> 16) & 1u);   // RTNE
  return (unsigned short)(u >> 16);
}
__device__ __forceinline__ bf16x8 f2bf8(const float* p) {
  float4 lo = *(const float4*)p;
  float4 hi = *(const float4*)(p + 4);
  bf16x8 r;
  r[0] = (short)f2bf(lo.x); r[1] = (short)f2bf(lo.y);
  r[2] = (short)f2bf(lo.z); r[3] = (short)f2bf(lo.w);
  r[4] = (short)f2bf(hi.x); r[5] = (short)f2bf(hi.y);
  r[6] = (short)f2bf(hi.z); r[7] = (short)f2bf(hi.w);
  return r;
}

// ---------------- conversions for MFMA GEMMs --------------------------------
__global__ __launch_bounds__(256) void k_cvt_x(
    const float* __restrict__ x, unsigned short* __restrict__ xb, int total4) {
  int idx = blockIdx.x * 256 + threadIdx.x;
  if (idx >= total4) return;
  float4 v = *(const float4*)(x + (size_t)idx * 4);
  ushort4 o;
  o.x = f2bf(v.x); o.y = f2bf(v.y); o.z = f2bf(v.z); o.w = f2bf(v.w);
  *(ushort4*)(xb + (size_t)idx * 4) = o;
}

// Wt[c][k] (bf16, c in [0,512)) = c<256 ? W1l[k][c] : W1r[k][c-256]
__global__ __launch_bounds__(256) void k_cvt_w(
    const float* __restrict__ Wl, const float* __restrict__ Wr,
    unsigned short* __restrict__ Wt) {
  int idx = blockIdx.x * 256 + threadIdx.x;   // 512*128 total
  if (idx >= 512 * IN_DIM) return;
  int c = idx >> 7, k = idx & 127;
  float v = (c < F1) ? Wl[k * F1 + c] : Wr[k * F1 + (c - F1)];
  Wt[idx] = f2bf(v);
}

// Wt2[c][k] (c in [0,128), k in [0,256)) = c<64 ? W2l[k][c] : W2r[k][c-64]
__global__ __launch_bounds__(256) void k_cvt_w2(
    const float* __restrict__ Wl, const float* __restrict__ Wr,
    unsigned short* __restrict__ Wt2) {
  int idx = blockIdx.x * 256 + threadIdx.x;   // 128*256 total
  if (idx >= 128 * F1) return;
  int c = idx >> 8, k = idx & 255;
  float v = (c < OUTD) ? Wl[k * OUTD + c] : Wr[k * OUTD + (c - OUTD)];
  Wt2[idx] = f2bf(v);
}

// Wuv[c][k] (c in [0,128), k in [0,64)): c<64 -> Wm1[k][c], else Wm1[64+k][c-64]
__global__ __launch_bounds__(256) void k_cvt_wuv(
    const float* __restrict__ Wm1, unsigned short* __restrict__ Wuv) {
  int idx = blockIdx.x * 256 + threadIdx.x;   // 128*64 total
  if (idx >= 128 * OUTD) return;
  int c = idx >> 6, k = idx & 63;
  float v = (c < OUTD) ? Wm1[k * OUTD + c] : Wm1[(64 + k) * OUTD + (c - OUTD)];
  Wuv[idx] = f2bf(v);
}

// ---------------- layer-1 GEMM via MFMA: [N,128]x[128,512] bf16 -------------
__global__ __launch_bounds__(256) void k_gemm1_mfma(
    const unsigned short* __restrict__ xb, const unsigned short* __restrict__ Wt,
    const float* __restrict__ bl, const float* __restrict__ br,
    unsigned short* __restrict__ xlh, float* __restrict__ xr, int N) {
  int tid = threadIdx.x, lane = tid & 63, w = tid >> 6;
  int node0 = blockIdx.x * 64 + w * 16;
  int colbase = blockIdx.y * 64;
  int arow = node0 + (lane & 15); if (arow >= N) arow = N - 1;
  int koff = (lane >> 4) * 8;
  const unsigned short* ap = xb + (size_t)arow * IN_DIM + koff;
  bf16x8 a0 = *(const bf16x8*)(ap);
  bf16x8 a1 = *(const bf16x8*)(ap + 32);
  bf16x8 a2 = *(const bf16x8*)(ap + 64);
  bf16x8 a3 = *(const bf16x8*)(ap + 96);
#pragma unroll
  for (int ct = 0; ct < 4; ct++) {
    int col = colbase + ct * 16 + (lane & 15);
    const unsigned short* bp = Wt + (size_t)col * IN_DIM + koff;
    f32x4 acc = {0.f, 0.f, 0.f, 0.f};
    acc = __builtin_amdgcn_mfma_f32_16x16x32_bf16(a0, *(const bf16x8*)(bp), acc, 0, 0, 0);
    acc = __builtin_amdgcn_mfma_f32_16x16x32_bf16(a1, *(const bf16x8*)(bp + 32), acc, 0, 0, 0);
    acc = __builtin_amdgcn_mfma_f32_16x16x32_bf16(a2, *(const bf16x8*)(bp + 64), acc, 0, 0, 0);
    acc = __builtin_amdgcn_mfma_f32_16x16x32_bf16(a3, *(const bf16x8*)(bp + 96), acc, 0, 0, 0);
    if (col < F1) {
      float bias = bl[col];
#pragma unroll
      for (int i = 0; i < 4; i++) {
        int node = node0 + ((lane >> 4) << 2) + i;
        if (node < N) xlh[(size_t)node * F1 + col] = f2bf(acc[i] + bias);
      }
    } else {
      float bias = br[col - F1];
#pragma unroll
      for (int i = 0; i < 4; i++) {
        int node = node0 + ((lane >> 4) << 2) + i;
        if (node < N) xr[(size_t)node * F1 + (col - F1)] = acc[i] + bias;
      }
    }
  }
}

// ---------------- layer-2 GEMM via MFMA: [N,256]x[256,128] ------------------
// grid ((N+63)/64, 2): y=0 -> xl2h (bf16, cols=W2l), y=1 -> xr2 (f32, W2r).
// z is f32; lanes convert their 8-float k-slices to bf16 fragments in regs.
__global__ __launch_bounds__(256) void k_gemm2_mfma(
    const float* __restrict__ z, const unsigned short* __restrict__ Wt2,
    const float* __restrict__ bl, const float* __restrict__ br,
    unsigned short* __restrict__ xl2h, float* __restrict__ xr2, int N) {
  int tid = threadIdx.x, lane = tid & 63, w = tid >> 6;
  int node0 = blockIdx.x * 64 + w * 16;
  int half = blockIdx.y;
  int arow = node0 + (lane & 15); if (arow >= N) arow = N - 1;
  int koff = (lane >> 4) * 8;
  const float* zp = z + (size_t)arow * F1 + koff;
  bf16x8 a[8];
#pragma unroll
  for (int t = 0; t < 8; t++) a[t] = f2bf8(zp + 32 * t);
  const unsigned short* Wbase = Wt2 + (size_t)half * OUTD * F1;
#pragma unroll
  for (int ct = 0; ct < 4; ct++) {
    int col = ct * 16 + (lane & 15);
    const unsigned short* bp = Wbase + (size_t)col * F1 + koff;
    f32x4 acc = {0.f, 0.f, 0.f, 0.f};
#pragma unroll
    for (int t = 0; t < 8; t++)
      acc = __builtin_amdgcn_mfma_f32_16x16x32_bf16(
          a[t], *(const bf16x8*)(bp + 32 * t), acc, 0, 0, 0);
    if (half == 0) {
      float bias = bl[col];
#pragma unroll
      for (int i = 0; i < 4; i++) {
        int node = node0 + ((lane >> 4) << 2) + i;
        if (node < N) xl2h[(size_t)node * OUTD + col] = f2bf(acc[i] + bias);
      }
    } else {
      float bias = br[col];
#pragma unroll
      for (int i = 0; i < 4; i++) {
        int node = node0 + ((lane >> 4) << 2) + i;
        if (node < N) xr2[(size_t)node * OUTD + col] = acc[i] + bias;
      }
    }
  }
}

// ---------------- decoder uv GEMM via MFMA: [N,64]x[64,128] -----------------
// grid ((N+63)/64, 2): y=0 -> u, y=1 -> v. No bias (bm1 added in k_link).
__global__ __launch_bounds__(256) void k_uv_mfma(
    const float* __restrict__ z2, const unsigned short* __restrict__ Wuv,
    float* __restrict__ u, float* __restrict__ v, int N) {
  int tid = threadIdx.x, lane = tid & 63, w = tid >> 6;
  int node0 = blockIdx.x * 64 + w * 16;
  int half = blockIdx.y;
  int arow = node0 + (lane & 15); if (arow >= N) arow = N - 1;
  int koff = (lane >> 4) * 8;
  const float* zp = z2 + (size_t)arow * OUTD + koff;
  bf16x8 a0 = f2bf8(zp);
  bf16x8 a1 = f2bf8(zp + 32);
  const unsigned short* Wbase = Wuv + (size_t)half * OUTD * OUTD;
  float* dst = half ? v : u;
#pragma unroll
  for (int ct = 0; ct < 4; ct++) {
    int col = ct * 16 + (lane & 15);
    const unsigned short* bp = Wbase + (size_t)col * OUTD + koff;
    f32x4 acc = {0.f, 0.f, 0.f, 0.f};
    acc = __builtin_amdgcn_mfma_f32_16x16x32_bf16(a0, *(const bf16x8*)(bp), acc, 0, 0, 0);
    acc = __builtin_amdgcn_mfma_f32_16x16x32_bf16(a1, *(const bf16x8*)(bp + 32), acc, 0, 0, 0);
#pragma unroll
    for (int i = 0; i < 4; i++) {
      int node = node0 + ((lane >> 4) << 2) + i;
      if (node < N) dst[(size_t)node * OUTD + col] = acc[i];
    }
  }
}

// ---------------- CSR build: histogram -> 3-stage scan -> scatter ----------
__global__ __launch_bounds__(256) void k_hist(
    const int* __restrict__ ei, int E, int N, int* __restrict__ cnt) {
  int e = blockIdx.x * 256 + threadIdx.x;
  if (e >= E + N) return;
  int d = (e < E) ? ei[E + e] : (e - E);
  atomicAdd(&cnt[d], 1);
}

__global__ __launch_bounds__(256) void k_scan1(
    int* __restrict__ cnt, int N, int* __restrict__ blk_sum) {
  int t = threadIdx.x, lane = t & 63, wid = t >> 6;
  int base = blockIdx.x * 1024 + t * 4;
  int4 v = {0, 0, 0, 0};
  if (base + 3 < N) {
    v = *(const int4*)(cnt + base);
  } else {
    if (base + 0 < N) v.x = cnt[base + 0];
    if (base + 1 < N) v.y = cnt[base + 1];
    if (base + 2 < N) v.z = cnt[base + 2];
    if (base + 3 < N) v.w = cnt[base + 3];
  }
  int s = v.x + v.y + v.z + v.w;
  int inc = s;
#pragma unroll
  for (int off = 1; off < 64; off <<= 1) {
    int u = __shfl_up(inc, off, 64);
    if (lane >= off) inc += u;
  }
  __shared__ int wsum[4];
  if (lane == 63) wsum[wid] = inc;
  __syncthreads();
  int wofs = 0;
#pragma unroll
  for (int q = 0; q < 4; q++) if (q < wid) wofs += wsum[q];
  int excl = wofs + inc - s;
  int4 o;
  o.x = excl; o.y = excl + v.x; o.z = o.y + v.y; o.w = o.z + v.z;
  if (base + 3 < N) {
    *(int4*)(cnt + base) = o;
  } else {
    if (base + 0 < N) cnt[base + 0] = o.x;
    if (base + 1 < N) cnt[base + 1] = o.y;
    if (base + 2 < N) cnt[base + 2] = o.z;
    if (base + 3 < N) cnt[base + 3] = o.w;
  }
  if (t == 255) blk_sum[blockIdx.x] = wofs + inc;
}

__global__ void k_scan2(int* __restrict__ blk, int nblk) {
  int lane = threadIdx.x;
  int v = (lane < nblk) ? blk[lane] : 0;
  int inc = v;
#pragma unroll
  for (int off = 1; off < 64; off <<= 1) {
    int u = __shfl_up(inc, off, 64);
    if (lane >= off) inc += u;
  }
  if (lane < nblk) blk[lane] = inc - v;
}

__global__ __launch_bounds__(256) void k_scan3(
    const int* __restrict__ local_ps, const int* __restrict__ blk_sum,
    int N, int Etot, int* __restrict__ row_start, int* __restrict__ cursor) {
  int i = blockIdx.x * 256 + threadIdx.x;
  if (i < N) {
    int p = local_ps[i] + blk_sum[i >> 10];
    row_start[i] = p;
    cursor[i] = p;
  }
  if (i == 0) row_start[N] = Etot;
}

__global__ __launch_bounds__(256) void k_scatter(
    const int* __restrict__ ei, int E, int N,
    int* __restrict__ cursor, int* __restrict__ csr_src) {
  int e = blockIdx.x * 256 + threadIdx.x;
  if (e >= E + N) return;
  int s, d;
  if (e < E) { s = ei[e]; d = ei[E + e]; } else { s = e - E; d = s; }
  int pos = atomicAdd(&cursor[d], 1);
  csr_src[pos] = s;
}

// ---------------- fused layer-1 (bf16 xl gathers) ---------------------------
#define LEAKY4(v, xs, xri)                                   \
  v.x = xs.x + xri.x; v.x = v.x > 0.f ? v.x : NEG * v.x;     \
  v.y = xs.y + xri.y; v.y = v.y > 0.f ? v.y : NEG * v.y;     \
  v.z = xs.z + xri.z; v.z = v.z > 0.f ? v.z : NEG * v.z;     \
  v.w = xs.w + xri.w; v.w = v.w > 0.f ? v.w : NEG * v.w;

#define RED16(p)                 \
  p += __shfl_xor(p, 1, 64);     \
  p += __shfl_xor(p, 2, 64);     \
  p += __shfl_xor(p, 4, 64);     \
  p += __shfl_xor(p, 8, 64);

#define BF4(dst, h)                                \
  dst.x = bf2f(h.x); dst.y = bf2f(h.y);            \
  dst.z = bf2f(h.z); dst.w = bf2f(h.w);

__global__ __launch_bounds__(256) void k_fused1(
    const unsigned short* __restrict__ xlh, const float* xr,
    const int* __restrict__ row_start, const int* __restrict__ csr_src,
    const float* __restrict__ att, const float* __restrict__ bias,
    float* out, int N) {
  int tid = threadIdx.x, lane = tid & 63, w = tid >> 6;
  int i = blockIdx.x * 4 + w;
  if (i >= N) return;
  float4 xri = *(const float4*)(xr + (size_t)i * F1 + lane * 4);
  float4 a4  = *(const float4*)(att + lane * 4);
  float m = -1e30f, den = 0.f;
  float4 acc = {0.f, 0.f, 0.f, 0.f};
  int b = row_start[i], e = row_start[i + 1];
  int k = b;
  for (; k + 3 < e; k += 4) {
    int s0 = csr_src[k], s1 = csr_src[k + 1];
    int s2 = csr_src[k + 2], s3 = csr_src[k + 3];
    ushort4 h0 = *(const ushort4*)(xlh + (size_t)s0 * F1 + lane * 4);
    ushort4 h1 = *(const ushort4*)(xlh + (size_t)s1 * F1 + lane * 4);
    ushort4 h2 = *(const ushort4*)(xlh + (size_t)s2 * F1 + lane * 4);
    ushort4 h3 = *(const ushort4*)(xlh + (size_t)s3 * F1 + lane * 4);
    float4 x0, x1, x2, x3;
    BF4(x0, h0); BF4(x1, h1); BF4(x2, h2); BF4(x3, h3);
    float4 v0, v1, v2, v3;
    LEAKY4(v0, x0, xri); LEAKY4(v1, x1, xri);
    LEAKY4(v2, x2, xri); LEAKY4(v3, x3, xri);
    float p0 = v0.x * a4.x + v0.y * a4.y + v0.z * a4.z + v0.w * a4.w;
    float p1 = v1.x * a4.x + v1.y * a4.y + v1.z * a4.z + v1.w * a4.w;
    float p2 = v2.x * a4.x + v2.y * a4.y + v2.z * a4.z + v2.w * a4.w;
    float p3 = v3.x * a4.x + v3.y * a4.y + v3.z * a4.z + v3.w * a4.w;
    RED16(p0); RED16(p1); RED16(p2); RED16(p3);
    float mn = fmaxf(fmaxf(m, p0), fmaxf(fmaxf(p1, p2), p3));
    float cs = __expf(m - mn);
    float w0 = __expf(p0 - mn), w1 = __expf(p1 - mn);
    float w2 = __expf(p2 - mn), w3 = __expf(p3 - mn);
    den = den * cs + (w0 + w1) + (w2 + w3);
    acc.x = acc.x * cs + w0 * x0.x + w1 * x1.x + w2 * x2.x + w3 * x3.x;
    acc.y = acc.y * cs + w0 * x0.y + w1 * x1.y + w2 * x2.y + w3 * x3.y;
    acc.z = acc.z * cs + w0 * x0.z + w1 * x1.z + w2 * x2.z + w3 * x3.z;
    acc.w = acc.w * cs + w0 * x0.w + w1 * x1.w + w2 * x2.w + w3 * x3.w;
    m = mn;
  }
  for (; k < e; k++) {
    int s = csr_src[k];
    ushort4 hh = *(const ushort4*)(xlh + (size_t)s * F1 + lane * 4);
    float4 xs;
    BF4(xs, hh);
    float4 v;
    LEAKY4(v, xs, xri);
    float p = v.x * a4.x + v.y * a4.y + v.z * a4.z + v.w * a4.w;
    RED16(p);
    float mn = fmaxf(m, p);
    float cs = __expf(m - mn);
    float wt = __expf(p - mn);
    den = den * cs + wt;
    acc.x = acc.x * cs + wt * xs.x;
    acc.y = acc.y * cs + wt * xs.y;
    acc.z = acc.z * cs + wt * xs.z;
    acc.w = acc.w * cs + wt * xs.w;
    m = mn;
  }
  float inv = 1.f / den;
  float4 bz = *(const float4*)(bias + lane * 4);
  float4 o;
  o.x = fmaxf(acc.x * inv + bz.x, 0.f);
  o.y = fmaxf(acc.y * inv + bz.y, 0.f);
  o.z = fmaxf(acc.z * inv + bz.z, 0.f);
  o.w = fmaxf(acc.w * inv + bz.w, 0.f);
  *(float4*)(out + (size_t)i * F1 + lane * 4) = o;
}

// ---------------- fused layer-2 (H=1, bf16 xl gathers) + bias2 --------------
#define RED64(p)                 \
  p += __shfl_xor(p, 1, 64);     \
  p += __shfl_xor(p, 2, 64);     \
  p += __shfl_xor(p, 4, 64);     \
  p += __shfl_xor(p, 8, 64);     \
  p += __shfl_xor(p, 16, 64);    \
  p += __shfl_xor(p, 32, 64);

__global__ __launch_bounds__(256) void k_fused2(
    const unsigned short* __restrict__ xlh, const float* xr,
    const int* __restrict__ row_start, const int* __restrict__ csr_src,
    const float* __restrict__ att, const float* __restrict__ bias,
    float* out, int N) {
  int tid = threadIdx.x, lane = tid & 63, w = tid >> 6;
  int i = blockIdx.x * 4 + w;
  if (i >= N) return;
  float xri = xr[(size_t)i * OUTD + lane];
  float a = att[lane];
  float m = -1e30f, den = 0.f, acc = 0.f;
  int b = row_start[i], e = row_start[i + 1];
  int k = b;
  for (; k + 3 < e; k += 4) {
    int s0 = csr_src[k], s1 = csr_src[k + 1];
    int s2 = csr_src[k + 2], s3 = csr_src[k + 3];
    float x0 = bf2f(xlh[(size_t)s0 * OUTD + lane]);
    float x1 = bf2f(xlh[(size_t)s1 * OUTD + lane]);
    float x2 = bf2f(xlh[(size_t)s2 * OUTD + lane]);
    float x3 = bf2f(xlh[(size_t)s3 * OUTD + lane]);
    float v0 = x0 + xri; v0 = v0 > 0.f ? v0 : NEG * v0;
    float v1 = x1 + xri; v1 = v1 > 0.f ? v1 : NEG * v1;
    float v2 = x2 + xri; v2 = v2 > 0.f ? v2 : NEG * v2;
    float v3 = x3 + xri; v3 = v3 > 0.f ? v3 : NEG * v3;
    float p0 = v0 * a, p1 = v1 * a, p2 = v2 * a, p3 = v3 * a;
    RED64(p0); RED64(p1); RED64(p2); RED64(p3);
    float mn = fmaxf(fmaxf(m, p0), fmaxf(fmaxf(p1, p2), p3));
    float cs = __expf(m - mn);
    float w0 = __expf(p0 - mn), w1 = __expf(p1 - mn);
    float w2 = __expf(p2 - mn), w3 = __expf(p3 - mn);
    den = den * cs + (w0 + w1) + (w2 + w3);
    acc = acc * cs + w0 * x0 + w1 * x1 + w2 * x2 + w3 * x3;
    m = mn;
  }
  for (; k < e; k++) {
    int s = csr_src[k];
    float xs = bf2f(xlh[(size_t)s * OUTD + lane]);
    float v = xs + xri;
    v = v > 0.f ? v : NEG * v;
    float p = v * a;
    RED64(p);
    float mn = fmaxf(m, p);
    float cs = __expf(m - mn);
    float wt = __expf(p - mn);
    den = den * cs + wt;
    acc = acc * cs + wt * xs;
    m = mn;
  }
  out[(size_t)i * OUTD + lane] = acc / den + bias[lane];
}

// ---------------- decoder stage B ------------------------------------------
__global__ __launch_bounds__(256) void k_link(
    const float* __restrict__ u, const float* __restrict__ v,
    const int* __restrict__ eli, int EL,
    const float* __restrict__ bm1, const float* __restrict__ Wm2,
    const float* __restrict__ bm2, float* __restrict__ out) {
  int tid = threadIdx.x, lane = tid & 63, w = tid >> 6;
  int li = lane >> 4, c4 = (lane & 15) * 4;
  int l = (blockIdx.x * 4 + w) * 4 + li;
  if (l >= EL) return;
  int a = eli[l], b = eli[EL + l];
  float4 uu = *(const float4*)(u + (size_t)a * OUTD + c4);
  float4 vv = *(const float4*)(v + (size_t)b * OUTD + c4);
  float4 bb = *(const float4*)(bm1 + c4);
  float4 ww = *(const float4*)(Wm2 + c4);
  float p = fmaxf(uu.x + vv.x + bb.x, 0.f) * ww.x
          + fmaxf(uu.y + vv.y + bb.y, 0.f) * ww.y
          + fmaxf(uu.z + vv.z + bb.z, 0.f) * ww.z
          + fmaxf(uu.w + vv.w + bb.w, 0.f) * ww.w;
  p += __shfl_xor(p, 1, 64);
  p += __shfl_xor(p, 2, 64);
  p += __shfl_xor(p, 4, 64);
  p += __shfl_xor(p, 8, 64);
  if ((lane & 15) == 0) out[l] = p + bm2[0];
}

extern "C" void kernel_launch(void* const* d_in, const int* in_sizes, int n_in,
                              void* d_out, int out_size, void* d_ws, size_t ws_size,
                              hipStream_t stream) {
  const float* x     = (const float*)d_in[0];
  const int*   ei    = (const int*)d_in[1];
  const int*   eli   = (const int*)d_in[2];
  const float* W1l   = (const float*)d_in[3];
  const float* b1l   = (const float*)d_in[4];
  const float* W1r   = (const float*)d_in[5];
  const float* b1r   = (const float*)d_in[6];
  const float* att1  = (const float*)d_in[7];
  const float* bias1 = (const float*)d_in[8];
  const float* W2l   = (const float*)d_in[9];
  const float* b2l   = (const float*)d_in[10];
  const float* W2r   = (const float*)d_in[11];
  const float* b2r   = (const float*)d_in[12];
  const float* att2  = (const float*)d_in[13];
  const float* bias2 = (const float*)d_in[14];
  const float* Wm1   = (const float*)d_in[15];
  const float* bm1   = (const float*)d_in[16];
  const float* Wm2   = (const float*)d_in[17];
  const float* bm2   = (const float*)d_in[18];

  int N = in_sizes[0] / IN_DIM;   // 50000
  int E = in_sizes[1] / 2;        // 800000
  int EL = in_sizes[2] / 2;       // 200000
  int Etot = E + N;

  // ---- workspace layout (bytes) ----
  // [0, 25.6M)        xl1h (bf16)   (layer2: xl2h bf16 @0, xr2/z2 f32 @12.8M)
  // [25.6M, 38.4M)    xb (bf16 x)   (dead after gemm1)
  // [38.4M, 38.7M)    Wt (bf16)     [39.0M, 39.2M) Wt2   [39.2M, 39.3M) Wuv
  // [51.2M, 102.4M)   xr1 -> z      (decoder: u @51.2M, v @64M)
  // [102.4M ...)      row_start, cursor(=cnt=local_ps), csr_src, blk_sum
  char* ws = (char*)d_ws;
  unsigned short* xl1h = (unsigned short*)(ws);
  unsigned short* xb   = (unsigned short*)(ws + 25600000);
  unsigned short* Wt   = (unsigned short*)(ws + 38400000);
  unsigned short* Wt2  = (unsigned short*)(ws + 39000000);
  unsigned short* Wuv  = (unsigned short*)(ws + 39200000);
  float* bufB      = (float*)(ws + 51200000);
  int*   row_start = (int*)(ws + 102400000);
  int*   cursor    = (int*)(ws + 102700000);
  int*   csr_src   = (int*)(ws + 103000000);
  int*   blk_sum   = (int*)(ws + 103000000 + (size_t)Etot * 4 + 256);
  unsigned short* xl2h = (unsigned short*)(ws);
  float* xr2       = (float*)(ws + 12800000);
  float* u_buf     = (float*)(ws + 51200000);
  float* v_buf     = (float*)(ws + 64000000);

  int nblk = (N + 1023) / 1024;   // 49 (<=64 required by k_scan2)

  // ---- conversions + CSR build ----
  hipMemsetAsync(cursor, 0, (size_t)N * 4, stream);
  k_cvt_x<<<(N * IN_DIM / 4 + 255) / 256, 256, 0, stream>>>(x, xb, N * IN_DIM / 4);
  k_cvt_w<<<(512 * IN_DIM + 255) / 256, 256, 0, stream>>>(W1l, W1r, Wt);
  k_cvt_w2<<<(128 * F1 + 255) / 256, 256, 0, stream>>>(W2l, W2r, Wt2);
  k_cvt_wuv<<<(128 * OUTD + 255) / 256, 256, 0, stream>>>(Wm1, Wuv);
  {
    dim3 g1((N + 63) / 64, 8);
    k_gemm1_mfma<<<g1, 256, 0, stream>>>(xb, Wt, b1l, b1r, xl1h, bufB, N);
  }
  k_hist<<<(Etot + 255) / 256, 256, 0, stream>>>(ei, E, N, cursor);
  k_scan1<<<nblk, 256, 0, stream>>>(cursor, N, blk_sum);
  k_scan2<<<1, 64, 0, stream>>>(blk_sum, nblk);
  k_scan3<<<(N + 255) / 256, 256, 0, stream>>>(cursor, blk_sum, N, Etot,
                                               row_start, cursor);
  k_scatter<<<(Etot + 255) / 256, 256, 0, stream>>>(ei, E, N, cursor, csr_src);

  // ---- layer 1 (fused) ----
  k_fused1<<<(N + 3) / 4, 256, 0, stream>>>(xl1h, bufB, row_start, csr_src,
                                            att1, bias1, bufB, N);
  // ---- layer 2 ----
  {
    dim3 g2((N + 63) / 64, 2);
    k_gemm2_mfma<<<g2, 256, 0, stream>>>(bufB, Wt2, b2l, b2r, xl2h, xr2, N);
  }
  k_fused2<<<(N + 3) / 4, 256, 0, stream>>>(xl2h, xr2, row_start, csr_src,
                                            att2, bias2, xr2, N);
  // ---- decoder ----
  {
    dim3 g3((N + 63) / 64, 2);
    k_uv_mfma<<<g3, 256, 0, stream>>>(xr2, Wuv, u_buf, v_buf, N);
  }
  k_link<<<(EL + 15) / 16, 256, 0, stream>>>(u_buf, v_buf, eli, EL,
                                             bm1, Wm2, bm2, (float*)d_out);
}

// Round 10
// 360.183 us; speedup vs baseline: 5.2243x; 1.0804x over previous
//
#include <hip/hip_runtime.h>
#include <hip/hip_bf16.h>

#define IN_DIM 128
#define HID    64
#define NH     4
#define F1     256   // NH*HID
#define OUTD   64
#define NEG    0.2f

typedef __attribute__((ext_vector_type(8))) short bf16x8;
typedef __attribute__((ext_vector_type(4))) float f32x4;

__device__ __forceinline__ float bf2f(unsigned short h) {
  return __uint_as_float((unsigned)h << 16);
}
__device__ __forceinline__ unsigned short f2bf(float f) {
  unsigned u = __float_as_uint(f);
  u += 0x7fffu + ((u >> 16) & 1u);   // RTNE
  return (unsigned short)(u >> 16);
}
__device__ __forceinline__ bf16x8 f2bf8(const float* p) {
  float4 lo = *(const float4*)p;
  float4 hi = *(const float4*)(p + 4);
  bf16x8 r;
  r[0] = (short)f2bf(lo.x); r[1] = (short)f2bf(lo.y);
  r[2] = (short)f2bf(lo.z); r[3] = (short)f2bf(lo.w);
  r[4] = (short)f2bf(hi.x); r[5] = (short)f2bf(hi.y);
  r[6] = (short)f2bf(hi.z); r[7] = (short)f2bf(hi.w);
  return r;
}

// ---------------- weight conversions for MFMA GEMMs -------------------------
// Wt[c][k] (bf16, c in [0,512)) = c<256 ? W1l[k][c] : W1r[k][c-256]
__global__ __launch_bounds__(256) void k_cvt_w(
    const float* __restrict__ Wl, const float* __restrict__ Wr,
    unsigned short* __restrict__ Wt) {
  int idx = blockIdx.x * 256 + threadIdx.x;   // 512*128 total
  if (idx >= 512 * IN_DIM) return;
  int c = idx >> 7, k = idx & 127;
  float v = (c < F1) ? Wl[k * F1 + c] : Wr[k * F1 + (c - F1)];
  Wt[idx] = f2bf(v);
}

// Wt2[c][k] (c in [0,128), k in [0,256)) = c<64 ? W2l[k][c] : W2r[k][c-64]
__global__ __launch_bounds__(256) void k_cvt_w2(
    const float* __restrict__ Wl, const float* __restrict__ Wr,
    unsigned short* __restrict__ Wt2) {
  int idx = blockIdx.x * 256 + threadIdx.x;   // 128*256 total
  if (idx >= 128 * F1) return;
  int c = idx >> 8, k = idx & 255;
  float v = (c < OUTD) ? Wl[k * OUTD + c] : Wr[k * OUTD + (c - OUTD)];
  Wt2[idx] = f2bf(v);
}

// Wuv[c][k] (c in [0,128), k in [0,64)): c<64 -> Wm1[k][c], else Wm1[64+k][c-64]
__global__ __launch_bounds__(256) void k_cvt_wuv(
    const float* __restrict__ Wm1, unsigned short* __restrict__ Wuv) {
  int idx = blockIdx.x * 256 + threadIdx.x;   // 128*64 total
  if (idx >= 128 * OUTD) return;
  int c = idx >> 6, k = idx & 63;
  float v = (c < OUTD) ? Wm1[k * OUTD + c] : Wm1[(64 + k) * OUTD + (c - OUTD)];
  Wuv[idx] = f2bf(v);
}

// ---------------- layer-1 GEMM via MFMA: [N,128]x[128,512] ------------------
// Block = 256 nodes (4 waves x 64 nodes = 4 row-tiles of 16); internal loop
// over 32 col-tiles. x read f32, converted to bf16 fragments in regs.
__global__ __launch_bounds__(256) void k_gemm1_mfma(
    const float* __restrict__ x, const unsigned short* __restrict__ Wt,
    const float* __restrict__ bl, const float* __restrict__ br,
    unsigned short* __restrict__ xlh, float* __restrict__ xr, int N) {
  int tid = threadIdx.x, lane = tid & 63, w = tid >> 6;
  int node0 = blockIdx.x * 256 + w * 64;
  int l16 = lane & 15, khi = lane >> 4;
  int koff = khi * 8;
  bf16x8 afr[4][4];
#pragma unroll
  for (int r = 0; r < 4; r++) {
    int arow = node0 + r * 16 + l16; if (arow >= N) arow = N - 1;
    const float* ap_ = x + (size_t)arow * IN_DIM + koff;
    afr[r][0] = f2bf8(ap_);
    afr[r][1] = f2bf8(ap_ + 32);
    afr[r][2] = f2bf8(ap_ + 64);
    afr[r][3] = f2bf8(ap_ + 96);
  }
#pragma unroll 4
  for (int ct = 0; ct < 32; ct++) {
    int col = ct * 16 + l16;
    const unsigned short* bp = Wt + (size_t)col * IN_DIM + koff;
    bf16x8 b0 = *(const bf16x8*)(bp);
    bf16x8 b1 = *(const bf16x8*)(bp + 32);
    bf16x8 b2 = *(const bf16x8*)(bp + 64);
    bf16x8 b3 = *(const bf16x8*)(bp + 96);
    bool isL = (ct < 16);
    float bias = isL ? bl[col] : br[col - F1];
#pragma unroll
    for (int r = 0; r < 4; r++) {
      f32x4 acc = {0.f, 0.f, 0.f, 0.f};
      acc = __builtin_amdgcn_mfma_f32_16x16x32_bf16(afr[r][0], b0, acc, 0, 0, 0);
      acc = __builtin_amdgcn_mfma_f32_16x16x32_bf16(afr[r][1], b1, acc, 0, 0, 0);
      acc = __builtin_amdgcn_mfma_f32_16x16x32_bf16(afr[r][2], b2, acc, 0, 0, 0);
      acc = __builtin_amdgcn_mfma_f32_16x16x32_bf16(afr[r][3], b3, acc, 0, 0, 0);
      int nbase = node0 + r * 16 + khi * 4;
      if (isL) {
#pragma unroll
        for (int i = 0; i < 4; i++) {
          int node = nbase + i;
          if (node < N) xlh[(size_t)node * F1 + col] = f2bf(acc[i] + bias);
        }
      } else {
#pragma unroll
        for (int i = 0; i < 4; i++) {
          int node = nbase + i;
          if (node < N) xr[(size_t)node * F1 + (col - F1)] = acc[i] + bias;
        }
      }
    }
  }
}

// ---------------- layer-2 GEMM via MFMA: [N,256]x[256,128], halves merged ---
__global__ __launch_bounds__(256) void k_gemm2_mfma(
    const float* __restrict__ z, const unsigned short* __restrict__ Wt2,
    const float* __restrict__ bl, const float* __restrict__ br,
    unsigned short* __restrict__ xl2h, float* __restrict__ xr2, int N) {
  int tid = threadIdx.x, lane = tid & 63, w = tid >> 6;
  int node0 = blockIdx.x * 64 + w * 16;
  int l16 = lane & 15, khi = lane >> 4;
  int koff = khi * 8;
  int arow = node0 + l16; if (arow >= N) arow = N - 1;
  const float* zp = z + (size_t)arow * F1 + koff;
  bf16x8 a[8];
#pragma unroll
  for (int t = 0; t < 8; t++) a[t] = f2bf8(zp + 32 * t);
#pragma unroll
  for (int half = 0; half < 2; half++) {
    const unsigned short* Wbase = Wt2 + (size_t)half * OUTD * F1;
#pragma unroll
    for (int ct = 0; ct < 4; ct++) {
      int col = ct * 16 + l16;
      const unsigned short* bp = Wbase + (size_t)col * F1 + koff;
      f32x4 acc = {0.f, 0.f, 0.f, 0.f};
#pragma unroll
      for (int t = 0; t < 8; t++)
        acc = __builtin_amdgcn_mfma_f32_16x16x32_bf16(
            a[t], *(const bf16x8*)(bp + 32 * t), acc, 0, 0, 0);
      int nbase = node0 + khi * 4;
      if (half == 0) {
        float bias = bl[col];
#pragma unroll
        for (int i = 0; i < 4; i++) {
          int node = nbase + i;
          if (node < N) xl2h[(size_t)node * OUTD + col] = f2bf(acc[i] + bias);
        }
      } else {
        float bias = br[col];
#pragma unroll
        for (int i = 0; i < 4; i++) {
          int node = nbase + i;
          if (node < N) xr2[(size_t)node * OUTD + col] = acc[i] + bias;
        }
      }
    }
  }
}

// ---------------- decoder uv GEMM via MFMA: [N,64]x[64,128] -----------------
__global__ __launch_bounds__(256) void k_uv_mfma(
    const float* __restrict__ z2, const unsigned short* __restrict__ Wuv,
    float* __restrict__ u, float* __restrict__ v, int N) {
  int tid = threadIdx.x, lane = tid & 63, w = tid >> 6;
  int node0 = blockIdx.x * 64 + w * 16;
  int half = blockIdx.y;
  int arow = node0 + (lane & 15); if (arow >= N) arow = N - 1;
  int koff = (lane >> 4) * 8;
  const float* zp = z2 + (size_t)arow * OUTD + koff;
  bf16x8 a0 = f2bf8(zp);
  bf16x8 a1 = f2bf8(zp + 32);
  const unsigned short* Wbase = Wuv + (size_t)half * OUTD * OUTD;
  float* dst = half ? v : u;
#pragma unroll
  for (int ct = 0; ct < 4; ct++) {
    int col = ct * 16 + (lane & 15);
    const unsigned short* bp = Wbase + (size_t)col * OUTD + koff;
    f32x4 acc = {0.f, 0.f, 0.f, 0.f};
    acc = __builtin_amdgcn_mfma_f32_16x16x32_bf16(a0, *(const bf16x8*)(bp), acc, 0, 0, 0);
    acc = __builtin_amdgcn_mfma_f32_16x16x32_bf16(a1, *(const bf16x8*)(bp + 32), acc, 0, 0, 0);
#pragma unroll
    for (int i = 0; i < 4; i++) {
      int node = node0 + ((lane >> 4) << 2) + i;
      if (node < N) dst[(size_t)node * OUTD + col] = acc[i];
    }
  }
}

// ---------------- CSR build: histogram -> 3-stage scan -> scatter ----------
__global__ __launch_bounds__(256) void k_hist(
    const int* __restrict__ ei, int E, int N, int* __restrict__ cnt) {
  int e = blockIdx.x * 256 + threadIdx.x;
  if (e >= E + N) return;
  int d = (e < E) ? ei[E + e] : (e - E);
  atomicAdd(&cnt[d], 1);
}

__global__ __launch_bounds__(256) void k_scan1(
    int* __restrict__ cnt, int N, int* __restrict__ blk_sum) {
  int t = threadIdx.x, lane = t & 63, wid = t >> 6;
  int base = blockIdx.x * 1024 + t * 4;
  int4 v = {0, 0, 0, 0};
  if (base + 3 < N) {
    v = *(const int4*)(cnt + base);
  } else {
    if (base + 0 < N) v.x = cnt[base + 0];
    if (base + 1 < N) v.y = cnt[base + 1];
    if (base + 2 < N) v.z = cnt[base + 2];
    if (base + 3 < N) v.w = cnt[base + 3];
  }
  int s = v.x + v.y + v.z + v.w;
  int inc = s;
#pragma unroll
  for (int off = 1; off < 64; off <<= 1) {
    int u = __shfl_up(inc, off, 64);
    if (lane >= off) inc += u;
  }
  __shared__ int wsum[4];
  if (lane == 63) wsum[wid] = inc;
  __syncthreads();
  int wofs = 0;
#pragma unroll
  for (int q = 0; q < 4; q++) if (q < wid) wofs += wsum[q];
  int excl = wofs + inc - s;
  int4 o;
  o.x = excl; o.y = excl + v.x; o.z = o.y + v.y; o.w = o.z + v.z;
  if (base + 3 < N) {
    *(int4*)(cnt + base) = o;
  } else {
    if (base + 0 < N) cnt[base + 0] = o.x;
    if (base + 1 < N) cnt[base + 1] = o.y;
    if (base + 2 < N) cnt[base + 2] = o.z;
    if (base + 3 < N) cnt[base + 3] = o.w;
  }
  if (t == 255) blk_sum[blockIdx.x] = wofs + inc;
}

__global__ void k_scan2(int* __restrict__ blk, int nblk) {
  int lane = threadIdx.x;
  int v = (lane < nblk) ? blk[lane] : 0;
  int inc = v;
#pragma unroll
  for (int off = 1; off < 64; off <<= 1) {
    int u = __shfl_up(inc, off, 64);
    if (lane >= off) inc += u;
  }
  if (lane < nblk) blk[lane] = inc - v;
}

__global__ __launch_bounds__(256) void k_scan3(
    const int* __restrict__ local_ps, const int* __restrict__ blk_sum,
    int N, int Etot, int* __restrict__ row_start, int* __restrict__ cursor) {
  int i = blockIdx.x * 256 + threadIdx.x;
  if (i < N) {
    int p = local_ps[i] + blk_sum[i >> 10];
    row_start[i] = p;
    cursor[i] = p;
  }
  if (i == 0) row_start[N] = Etot;
}

__global__ __launch_bounds__(256) void k_scatter(
    const int* __restrict__ ei, int E, int N,
    int* __restrict__ cursor, int* __restrict__ csr_src) {
  int e = blockIdx.x * 256 + threadIdx.x;
  if (e >= E + N) return;
  int s, d;
  if (e < E) { s = ei[e]; d = ei[E + e]; } else { s = e - E; d = s; }
  int pos = atomicAdd(&cursor[d], 1);
  csr_src[pos] = s;
}

// ---------------- fused layer-1 (bf16 xl gathers, att-select dot) -----------
#define RED16(p)                 \
  p += __shfl_xor(p, 1, 64);     \
  p += __shfl_xor(p, 2, 64);     \
  p += __shfl_xor(p, 4, 64);     \
  p += __shfl_xor(p, 8, 64);

#define BF4(dst, h)                                \
  dst.x = bf2f(h.x); dst.y = bf2f(h.y);            \
  dst.z = bf2f(h.z); dst.w = bf2f(h.w);

// p += sum_c t_c * (t_c>0 ? att_c : 0.2*att_c), t = xv + xri
#define DOTSEL(p, xv)                                              \
  { float t;                                                       \
    t = xv.x + xri.x; p = fmaf(t, t > 0.f ? a4.x : an4.x, p);      \
    t = xv.y + xri.y; p = fmaf(t, t > 0.f ? a4.y : an4.y, p);      \
    t = xv.z + xri.z; p = fmaf(t, t > 0.f ? a4.z : an4.z, p);      \
    t = xv.w + xri.w; p = fmaf(t, t > 0.f ? a4.w : an4.w, p); }

__global__ __launch_bounds__(256) void k_fused1(
    const unsigned short* __restrict__ xlh, const float* xr,
    const int* __restrict__ row_start, const int* __restrict__ csr_src,
    const float* __restrict__ att, const float* __restrict__ bias,
    float* out, int N) {
  int tid = threadIdx.x, lane = tid & 63, w = tid >> 6;
  int i = blockIdx.x * 4 + w;
  if (i >= N) return;
  float4 xri = *(const float4*)(xr + (size_t)i * F1 + lane * 4);
  float4 a4  = *(const float4*)(att + lane * 4);
  float4 an4;
  an4.x = NEG * a4.x; an4.y = NEG * a4.y; an4.z = NEG * a4.z; an4.w = NEG * a4.w;
  float m = -1e30f, den = 0.f;
  float4 acc = {0.f, 0.f, 0.f, 0.f};
  int b = row_start[i], e = row_start[i + 1];
  int k = b;
  for (; k + 3 < e; k += 4) {
    int s0 = csr_src[k], s1 = csr_src[k + 1];
    int s2 = csr_src[k + 2], s3 = csr_src[k + 3];
    ushort4 h0 = *(const ushort4*)(xlh + (size_t)s0 * F1 + lane * 4);
    ushort4 h1 = *(const ushort4*)(xlh + (size_t)s1 * F1 + lane * 4);
    ushort4 h2 = *(const ushort4*)(xlh + (size_t)s2 * F1 + lane * 4);
    ushort4 h3 = *(const ushort4*)(xlh + (size_t)s3 * F1 + lane * 4);
    float4 x0, x1, x2, x3;
    BF4(x0, h0); BF4(x1, h1); BF4(x2, h2); BF4(x3, h3);
    float p0 = 0.f, p1 = 0.f, p2 = 0.f, p3 = 0.f;
    DOTSEL(p0, x0); DOTSEL(p1, x1); DOTSEL(p2, x2); DOTSEL(p3, x3);
    RED16(p0); RED16(p1); RED16(p2); RED16(p3);
    float mn = fmaxf(fmaxf(m, p0), fmaxf(fmaxf(p1, p2), p3));
    float cs = __expf(m - mn);
    float w0 = __expf(p0 - mn), w1 = __expf(p1 - mn);
    float w2 = __expf(p2 - mn), w3 = __expf(p3 - mn);
    den = den * cs + (w0 + w1) + (w2 + w3);
    acc.x = acc.x * cs + w0 * x0.x + w1 * x1.x + w2 * x2.x + w3 * x3.x;
    acc.y = acc.y * cs + w0 * x0.y + w1 * x1.y + w2 * x2.y + w3 * x3.y;
    acc.z = acc.z * cs + w0 * x0.z + w1 * x1.z + w2 * x2.z + w3 * x3.z;
    acc.w = acc.w * cs + w0 * x0.w + w1 * x1.w + w2 * x2.w + w3 * x3.w;
    m = mn;
  }
  for (; k < e; k++) {
    int s = csr_src[k];
    ushort4 hh = *(const ushort4*)(xlh + (size_t)s * F1 + lane * 4);
    float4 xs;
    BF4(xs, hh);
    float p = 0.f;
    DOTSEL(p, xs);
    RED16(p);
    float mn = fmaxf(m, p);
    float cs = __expf(m - mn);
    float wt = __expf(p - mn);
    den = den * cs + wt;
    acc.x = acc.x * cs + wt * xs.x;
    acc.y = acc.y * cs + wt * xs.y;
    acc.z = acc.z * cs + wt * xs.z;
    acc.w = acc.w * cs + wt * xs.w;
    m = mn;
  }
  float inv = 1.f / den;
  float4 bz = *(const float4*)(bias + lane * 4);
  float4 o;
  o.x = fmaxf(acc.x * inv + bz.x, 0.f);
  o.y = fmaxf(acc.y * inv + bz.y, 0.f);
  o.z = fmaxf(acc.z * inv + bz.z, 0.f);
  o.w = fmaxf(acc.w * inv + bz.w, 0.f);
  *(float4*)(out + (size_t)i * F1 + lane * 4) = o;
}

// ---------------- fused layer-2: 4x16-lane groups, 8 edges in flight --------
// One wave per dst node. Group g (lanes 16g..16g+15) processes edges k+g and
// k+4+g; lane l16 owns channels [4*l16, 4*l16+4). Per-group online softmax;
// cross-group merge at the end via shfl_xor 16/32.
__global__ __launch_bounds__(256) void k_fused2(
    const unsigned short* __restrict__ xlh, const float* xr,
    const int* __restrict__ row_start, const int* __restrict__ csr_src,
    const float* __restrict__ att, const float* __restrict__ bias,
    float* out, int N) {
  int tid = threadIdx.x, lane = tid & 63, w = tid >> 6;
  int i = blockIdx.x * 4 + w;
  if (i >= N) return;
  int g = lane >> 4, l16 = lane & 15;
  float4 xri = *(const float4*)(xr + (size_t)i * OUTD + l16 * 4);
  float4 a4  = *(const float4*)(att + l16 * 4);
  float4 an4;
  an4.x = NEG * a4.x; an4.y = NEG * a4.y; an4.z = NEG * a4.z; an4.w = NEG * a4.w;
  float m = -1e30f, den = 0.f;
  float4 acc = {0.f, 0.f, 0.f, 0.f};
  int b = row_start[i], e = row_start[i + 1];
  for (int k = b; k < e; k += 8) {
    int ea = k + g, eb = k + 4 + g;
    int sa = csr_src[ea < e ? ea : (e - 1)];
    int sb = csr_src[eb < e ? eb : (e - 1)];
    ushort4 ha = *(const ushort4*)(xlh + (size_t)sa * OUTD + l16 * 4);
    ushort4 hb = *(const ushort4*)(xlh + (size_t)sb * OUTD + l16 * 4);
    float4 xa, xb;
    BF4(xa, ha); BF4(xb, hb);
    float pa = 0.f, pb = 0.f;
    DOTSEL(pa, xa); DOTSEL(pb, xb);
    RED16(pa); RED16(pb);
    if (ea >= e) pa = -1e30f;
    if (eb >= e) pb = -1e30f;
    float mn = fmaxf(m, fmaxf(pa, pb));
    float cs = __expf(m - mn);
    float wa = __expf(pa - mn), wb = __expf(pb - mn);
    den = den * cs + wa + wb;
    acc.x = acc.x * cs + wa * xa.x + wb * xb.x;
    acc.y = acc.y * cs + wa * xa.y + wb * xb.y;
    acc.z = acc.z * cs + wa * xa.z + wb * xb.z;
    acc.w = acc.w * cs + wa * xa.w + wb * xb.w;
    m = mn;
  }
  // merge the 4 groups' partial (m, den, acc)
#pragma unroll
  for (int off = 16; off <= 32; off <<= 1) {
    float om   = __shfl_xor(m, off, 64);
    float oden = __shfl_xor(den, off, 64);
    float4 oa;
    oa.x = __shfl_xor(acc.x, off, 64);
    oa.y = __shfl_xor(acc.y, off, 64);
    oa.z = __shfl_xor(acc.z, off, 64);
    oa.w = __shfl_xor(acc.w, off, 64);
    float mn = fmaxf(m, om);
    float cs = __expf(m - mn), co = __expf(om - mn);
    den = den * cs + oden * co;
    acc.x = acc.x * cs + oa.x * co;
    acc.y = acc.y * cs + oa.y * co;
    acc.z = acc.z * cs + oa.z * co;
    acc.w = acc.w * cs + oa.w * co;
    m = mn;
  }
  if (g == 0) {
    float inv = 1.f / den;
    float4 bz = *(const float4*)(bias + l16 * 4);
    float4 o;
    o.x = acc.x * inv + bz.x;
    o.y = acc.y * inv + bz.y;
    o.z = acc.z * inv + bz.z;
    o.w = acc.w * inv + bz.w;
    *(float4*)(out + (size_t)i * OUTD + l16 * 4) = o;
  }
}

// ---------------- decoder stage B ------------------------------------------
__global__ __launch_bounds__(256) void k_link(
    const float* __restrict__ u, const float* __restrict__ v,
    const int* __restrict__ eli, int EL,
    const float* __restrict__ bm1, const float* __restrict__ Wm2,
    const float* __restrict__ bm2, float* __restrict__ out) {
  int tid = threadIdx.x, lane = tid & 63, w = tid >> 6;
  int li = lane >> 4, c4 = (lane & 15) * 4;
  int l = (blockIdx.x * 4 + w) * 4 + li;
  if (l >= EL) return;
  int a = eli[l], b = eli[EL + l];
  float4 uu = *(const float4*)(u + (size_t)a * OUTD + c4);
  float4 vv = *(const float4*)(v + (size_t)b * OUTD + c4);
  float4 bb = *(const float4*)(bm1 + c4);
  float4 ww = *(const float4*)(Wm2 + c4);
  float p = fmaxf(uu.x + vv.x + bb.x, 0.f) * ww.x
          + fmaxf(uu.y + vv.y + bb.y, 0.f) * ww.y
          + fmaxf(uu.z + vv.z + bb.z, 0.f) * ww.z
          + fmaxf(uu.w + vv.w + bb.w, 0.f) * ww.w;
  p += __shfl_xor(p, 1, 64);
  p += __shfl_xor(p, 2, 64);
  p += __shfl_xor(p, 4, 64);
  p += __shfl_xor(p, 8, 64);
  if ((lane & 15) == 0) out[l] = p + bm2[0];
}

extern "C" void kernel_launch(void* const* d_in, const int* in_sizes, int n_in,
                              void* d_out, int out_size, void* d_ws, size_t ws_size,
                              hipStream_t stream) {
  const float* x     = (const float*)d_in[0];
  const int*   ei    = (const int*)d_in[1];
  const int*   eli   = (const int*)d_in[2];
  const float* W1l   = (const float*)d_in[3];
  const float* b1l   = (const float*)d_in[4];
  const float* W1r   = (const float*)d_in[5];
  const float* b1r   = (const float*)d_in[6];
  const float* att1  = (const float*)d_in[7];
  const float* bias1 = (const float*)d_in[8];
  const float* W2l   = (const float*)d_in[9];
  const float* b2l   = (const float*)d_in[10];
  const float* W2r   = (const float*)d_in[11];
  const float* b2r   = (const float*)d_in[12];
  const float* att2  = (const float*)d_in[13];
  const float* bias2 = (const float*)d_in[14];
  const float* Wm1   = (const float*)d_in[15];
  const float* bm1   = (const float*)d_in[16];
  const float* Wm2   = (const float*)d_in[17];
  const float* bm2   = (const float*)d_in[18];

  int N = in_sizes[0] / IN_DIM;   // 50000
  int E = in_sizes[1] / 2;        // 800000
  int EL = in_sizes[2] / 2;       // 200000
  int Etot = E + N;

  // ---- workspace layout (bytes) ----
  // [0, 25.6M)        xl1h (bf16)   (layer2: xl2h bf16 @0, xr2/z2 f32 @12.8M)
  // [38.4M, 38.7M)    Wt (bf16)     [39.0M, 39.2M) Wt2   [39.2M, 39.3M) Wuv
  // [51.2M, 102.4M)   xr1 -> z      (decoder: u @51.2M, v @64M)
  // [102.4M ...)      row_start, cursor(=cnt=local_ps), csr_src, blk_sum
  char* ws = (char*)d_ws;
  unsigned short* xl1h = (unsigned short*)(ws);
  unsigned short* Wt   = (unsigned short*)(ws + 38400000);
  unsigned short* Wt2  = (unsigned short*)(ws + 39000000);
  unsigned short* Wuv  = (unsigned short*)(ws + 39200000);
  float* bufB      = (float*)(ws + 51200000);
  int*   row_start = (int*)(ws + 102400000);
  int*   cursor    = (int*)(ws + 102700000);
  int*   csr_src   = (int*)(ws + 103000000);
  int*   blk_sum   = (int*)(ws + 103000000 + (size_t)Etot * 4 + 256);
  unsigned short* xl2h = (unsigned short*)(ws);
  float* xr2       = (float*)(ws + 12800000);
  float* u_buf     = (float*)(ws + 51200000);
  float* v_buf     = (float*)(ws + 64000000);

  int nblk = (N + 1023) / 1024;   // 49 (<=64 required by k_scan2)

  // ---- weight conversions + CSR build ----
  hipMemsetAsync(cursor, 0, (size_t)N * 4, stream);
  k_cvt_w<<<(512 * IN_DIM + 255) / 256, 256, 0, stream>>>(W1l, W1r, Wt);
  k_cvt_w2<<<(128 * F1 + 255) / 256, 256, 0, stream>>>(W2l, W2r, Wt2);
  k_cvt_wuv<<<(128 * OUTD + 255) / 256, 256, 0, stream>>>(Wm1, Wuv);
  k_gemm1_mfma<<<(N + 255) / 256, 256, 0, stream>>>(x, Wt, b1l, b1r, xl1h, bufB, N);
  k_hist<<<(Etot + 255) / 256, 256, 0, stream>>>(ei, E, N, cursor);
  k_scan1<<<nblk, 256, 0, stream>>>(cursor, N, blk_sum);
  k_scan2<<<1, 64, 0, stream>>>(blk_sum, nblk);
  k_scan3<<<(N + 255) / 256, 256, 0, stream>>>(cursor, blk_sum, N, Etot,
                                               row_start, cursor);
  k_scatter<<<(Etot + 255) / 256, 256, 0, stream>>>(ei, E, N, cursor, csr_src);

  // ---- layer 1 (fused) ----
  k_fused1<<<(N + 3) / 4, 256, 0, stream>>>(xl1h, bufB, row_start, csr_src,
                                            att1, bias1, bufB, N);
  // ---- layer 2 ----
  k_gemm2_mfma<<<(N + 63) / 64, 256, 0, stream>>>(bufB, Wt2, b2l, b2r, xl2h, xr2, N);
  k_fused2<<<(N + 3) / 4, 256, 0, stream>>>(xl2h, xr2, row_start, csr_src,
                                            att2, bias2, xr2, N);
  // ---- decoder ----
  {
    dim3 g3((N + 63) / 64, 2);
    k_uv_mfma<<<g3, 256, 0, stream>>>(xr2, Wuv, u_buf, v_buf, N);
  }
  k_link<<<(EL + 15) / 16, 256, 0, stream>>>(u_buf, v_buf, eli, EL,
                                             bm1, Wm2, bm2, (float*)d_out);
}

// Round 11
// 354.616 us; speedup vs baseline: 5.3063x; 1.0157x over previous
//
#include <hip/hip_runtime.h>
#include <hip/hip_bf16.h>

#define IN_DIM 128
#define HID    64
#define NH     4
#define F1     256   // NH*HID
#define OUTD   64
#define NEG    0.2f

typedef __attribute__((ext_vector_type(8))) short bf16x8;
typedef __attribute__((ext_vector_type(4))) float f32x4;

__device__ __forceinline__ float bf2f(unsigned short h) {
  return __uint_as_float((unsigned)h << 16);
}
__device__ __forceinline__ unsigned short f2bf(float f) {
  unsigned u = __float_as_uint(f);
  u += 0x7fffu + ((u >> 16) & 1u);   // RTNE
  return (unsigned short)(u >> 16);
}
__device__ __forceinline__ bf16x8 f2bf8(const float* p) {
  float4 lo = *(const float4*)p;
  float4 hi = *(const float4*)(p + 4);
  bf16x8 r;
  r[0] = (short)f2bf(lo.x); r[1] = (short)f2bf(lo.y);
  r[2] = (short)f2bf(lo.z); r[3] = (short)f2bf(lo.w);
  r[4] = (short)f2bf(hi.x); r[5] = (short)f2bf(hi.y);
  r[6] = (short)f2bf(hi.z); r[7] = (short)f2bf(hi.w);
  return r;
}

// ---------------- weight conversions for MFMA GEMMs -------------------------
// Wt[c][k] (bf16, c in [0,512)) = c<256 ? W1l[k][c] : W1r[k][c-256]
__global__ __launch_bounds__(256) void k_cvt_w(
    const float* __restrict__ Wl, const float* __restrict__ Wr,
    unsigned short* __restrict__ Wt) {
  int idx = blockIdx.x * 256 + threadIdx.x;   // 512*128 total
  if (idx >= 512 * IN_DIM) return;
  int c = idx >> 7, k = idx & 127;
  float v = (c < F1) ? Wl[k * F1 + c] : Wr[k * F1 + (c - F1)];
  Wt[idx] = f2bf(v);
}

// Wt2[c][k] (c in [0,128), k in [0,256)) = c<64 ? W2l[k][c] : W2r[k][c-64]
__global__ __launch_bounds__(256) void k_cvt_w2(
    const float* __restrict__ Wl, const float* __restrict__ Wr,
    unsigned short* __restrict__ Wt2) {
  int idx = blockIdx.x * 256 + threadIdx.x;   // 128*256 total
  if (idx >= 128 * F1) return;
  int c = idx >> 8, k = idx & 255;
  float v = (c < OUTD) ? Wl[k * OUTD + c] : Wr[k * OUTD + (c - OUTD)];
  Wt2[idx] = f2bf(v);
}

// Wuv[c][k] (c in [0,128), k in [0,64)): c<64 -> Wm1[k][c], else Wm1[64+k][c-64]
__global__ __launch_bounds__(256) void k_cvt_wuv(
    const float* __restrict__ Wm1, unsigned short* __restrict__ Wuv) {
  int idx = blockIdx.x * 256 + threadIdx.x;   // 128*64 total
  if (idx >= 128 * OUTD) return;
  int c = idx >> 6, k = idx & 63;
  float v = (c < OUTD) ? Wm1[k * OUTD + c] : Wm1[(64 + k) * OUTD + (c - OUTD)];
  Wuv[idx] = f2bf(v);
}

// ---------------- layer-1 GEMM via MFMA: [N,128]x[128,512] ------------------
// Block = 64 nodes (4 waves x 16), blockIdx.y in [0,4) = 128-col group.
// 3128 blocks -> ~12 waves/SIMD. x read f32, converted to bf16 frags in regs.
__global__ __launch_bounds__(256) void k_gemm1_mfma(
    const float* __restrict__ x, const unsigned short* __restrict__ Wt,
    const float* __restrict__ bl, const float* __restrict__ br,
    unsigned short* __restrict__ xlh, float* __restrict__ xr, int N) {
  int tid = threadIdx.x, lane = tid & 63, w = tid >> 6;
  int node0 = blockIdx.x * 64 + w * 16;
  int colbase = blockIdx.y * 128;
  int l16 = lane & 15, khi = lane >> 4;
  int koff = khi * 8;
  int arow = node0 + l16; if (arow >= N) arow = N - 1;
  const float* ap = x + (size_t)arow * IN_DIM + koff;
  bf16x8 a0 = f2bf8(ap);
  bf16x8 a1 = f2bf8(ap + 32);
  bf16x8 a2 = f2bf8(ap + 64);
  bf16x8 a3 = f2bf8(ap + 96);
#pragma unroll
  for (int ct = 0; ct < 8; ct++) {
    int col = colbase + ct * 16 + l16;
    const unsigned short* bp = Wt + (size_t)col * IN_DIM + koff;
    f32x4 acc = {0.f, 0.f, 0.f, 0.f};
    acc = __builtin_amdgcn_mfma_f32_16x16x32_bf16(a0, *(const bf16x8*)(bp), acc, 0, 0, 0);
    acc = __builtin_amdgcn_mfma_f32_16x16x32_bf16(a1, *(const bf16x8*)(bp + 32), acc, 0, 0, 0);
    acc = __builtin_amdgcn_mfma_f32_16x16x32_bf16(a2, *(const bf16x8*)(bp + 64), acc, 0, 0, 0);
    acc = __builtin_amdgcn_mfma_f32_16x16x32_bf16(a3, *(const bf16x8*)(bp + 96), acc, 0, 0, 0);
    int nbase = node0 + khi * 4;
    if (col < F1) {            // wave-uniform (16-col tiles)
      float bias = bl[col];
#pragma unroll
      for (int i = 0; i < 4; i++) {
        int node = nbase + i;
        if (node < N) xlh[(size_t)node * F1 + col] = f2bf(acc[i] + bias);
      }
    } else {
      float bias = br[col - F1];
#pragma unroll
      for (int i = 0; i < 4; i++) {
        int node = nbase + i;
        if (node < N) xr[(size_t)node * F1 + (col - F1)] = acc[i] + bias;
      }
    }
  }
}

// ---------------- layer-2 GEMM via MFMA: [N,256]x[256,128], halves merged ---
__global__ __launch_bounds__(256) void k_gemm2_mfma(
    const float* __restrict__ z, const unsigned short* __restrict__ Wt2,
    const float* __restrict__ bl, const float* __restrict__ br,
    unsigned short* __restrict__ xl2h, float* __restrict__ xr2, int N) {
  int tid = threadIdx.x, lane = tid & 63, w = tid >> 6;
  int node0 = blockIdx.x * 64 + w * 16;
  int l16 = lane & 15, khi = lane >> 4;
  int koff = khi * 8;
  int arow = node0 + l16; if (arow >= N) arow = N - 1;
  const float* zp = z + (size_t)arow * F1 + koff;
  bf16x8 a[8];
#pragma unroll
  for (int t = 0; t < 8; t++) a[t] = f2bf8(zp + 32 * t);
#pragma unroll
  for (int half = 0; half < 2; half++) {
    const unsigned short* Wbase = Wt2 + (size_t)half * OUTD * F1;
#pragma unroll
    for (int ct = 0; ct < 4; ct++) {
      int col = ct * 16 + l16;
      const unsigned short* bp = Wbase + (size_t)col * F1 + koff;
      f32x4 acc = {0.f, 0.f, 0.f, 0.f};
#pragma unroll
      for (int t = 0; t < 8; t++)
        acc = __builtin_amdgcn_mfma_f32_16x16x32_bf16(
            a[t], *(const bf16x8*)(bp + 32 * t), acc, 0, 0, 0);
      int nbase = node0 + khi * 4;
      if (half == 0) {
        float bias = bl[col];
#pragma unroll
        for (int i = 0; i < 4; i++) {
          int node = nbase + i;
          if (node < N) xl2h[(size_t)node * OUTD + col] = f2bf(acc[i] + bias);
        }
      } else {
        float bias = br[col];
#pragma unroll
        for (int i = 0; i < 4; i++) {
          int node = nbase + i;
          if (node < N) xr2[(size_t)node * OUTD + col] = acc[i] + bias;
        }
      }
    }
  }
}

// ---------------- decoder uv GEMM via MFMA: [N,64]x[64,128] -----------------
__global__ __launch_bounds__(256) void k_uv_mfma(
    const float* __restrict__ z2, const unsigned short* __restrict__ Wuv,
    float* __restrict__ u, float* __restrict__ v, int N) {
  int tid = threadIdx.x, lane = tid & 63, w = tid >> 6;
  int node0 = blockIdx.x * 64 + w * 16;
  int half = blockIdx.y;
  int arow = node0 + (lane & 15); if (arow >= N) arow = N - 1;
  int koff = (lane >> 4) * 8;
  const float* zp = z2 + (size_t)arow * OUTD + koff;
  bf16x8 a0 = f2bf8(zp);
  bf16x8 a1 = f2bf8(zp + 32);
  const unsigned short* Wbase = Wuv + (size_t)half * OUTD * OUTD;
  float* dst = half ? v : u;
#pragma unroll
  for (int ct = 0; ct < 4; ct++) {
    int col = ct * 16 + (lane & 15);
    const unsigned short* bp = Wbase + (size_t)col * OUTD + koff;
    f32x4 acc = {0.f, 0.f, 0.f, 0.f};
    acc = __builtin_amdgcn_mfma_f32_16x16x32_bf16(a0, *(const bf16x8*)(bp), acc, 0, 0, 0);
    acc = __builtin_amdgcn_mfma_f32_16x16x32_bf16(a1, *(const bf16x8*)(bp + 32), acc, 0, 0, 0);
#pragma unroll
    for (int i = 0; i < 4; i++) {
      int node = node0 + ((lane >> 4) << 2) + i;
      if (node < N) dst[(size_t)node * OUTD + col] = acc[i];
    }
  }
}

// ---------------- CSR build: histogram -> 3-stage scan -> scatter ----------
__global__ __launch_bounds__(256) void k_hist(
    const int* __restrict__ ei, int E, int N, int* __restrict__ cnt) {
  int e = blockIdx.x * 256 + threadIdx.x;
  if (e >= E + N) return;
  int d = (e < E) ? ei[E + e] : (e - E);
  atomicAdd(&cnt[d], 1);
}

__global__ __launch_bounds__(256) void k_scan1(
    int* __restrict__ cnt, int N, int* __restrict__ blk_sum) {
  int t = threadIdx.x, lane = t & 63, wid = t >> 6;
  int base = blockIdx.x * 1024 + t * 4;
  int4 v = {0, 0, 0, 0};
  if (base + 3 < N) {
    v = *(const int4*)(cnt + base);
  } else {
    if (base + 0 < N) v.x = cnt[base + 0];
    if (base + 1 < N) v.y = cnt[base + 1];
    if (base + 2 < N) v.z = cnt[base + 2];
    if (base + 3 < N) v.w = cnt[base + 3];
  }
  int s = v.x + v.y + v.z + v.w;
  int inc = s;
#pragma unroll
  for (int off = 1; off < 64; off <<= 1) {
    int u = __shfl_up(inc, off, 64);
    if (lane >= off) inc += u;
  }
  __shared__ int wsum[4];
  if (lane == 63) wsum[wid] = inc;
  __syncthreads();
  int wofs = 0;
#pragma unroll
  for (int q = 0; q < 4; q++) if (q < wid) wofs += wsum[q];
  int excl = wofs + inc - s;
  int4 o;
  o.x = excl; o.y = excl + v.x; o.z = o.y + v.y; o.w = o.z + v.z;
  if (base + 3 < N) {
    *(int4*)(cnt + base) = o;
  } else {
    if (base + 0 < N) cnt[base + 0] = o.x;
    if (base + 1 < N) cnt[base + 1] = o.y;
    if (base + 2 < N) cnt[base + 2] = o.z;
    if (base + 3 < N) cnt[base + 3] = o.w;
  }
  if (t == 255) blk_sum[blockIdx.x] = wofs + inc;
}

__global__ void k_scan2(int* __restrict__ blk, int nblk) {
  int lane = threadIdx.x;
  int v = (lane < nblk) ? blk[lane] : 0;
  int inc = v;
#pragma unroll
  for (int off = 1; off < 64; off <<= 1) {
    int u = __shfl_up(inc, off, 64);
    if (lane >= off) inc += u;
  }
  if (lane < nblk) blk[lane] = inc - v;
}

__global__ __launch_bounds__(256) void k_scan3(
    const int* __restrict__ local_ps, const int* __restrict__ blk_sum,
    int N, int Etot, int* __restrict__ row_start, int* __restrict__ cursor) {
  int i = blockIdx.x * 256 + threadIdx.x;
  if (i < N) {
    int p = local_ps[i] + blk_sum[i >> 10];
    row_start[i] = p;
    cursor[i] = p;
  }
  if (i == 0) row_start[N] = Etot;
}

__global__ __launch_bounds__(256) void k_scatter(
    const int* __restrict__ ei, int E, int N,
    int* __restrict__ cursor, int* __restrict__ csr_src) {
  int e = blockIdx.x * 256 + threadIdx.x;
  if (e >= E + N) return;
  int s, d;
  if (e < E) { s = ei[e]; d = ei[E + e]; } else { s = e - E; d = s; }
  int pos = atomicAdd(&cursor[d], 1);
  csr_src[pos] = s;
}

// ---------------- fused layer-1 (bf16 xl gathers, att-select dot) -----------
#define RED16(p)                 \
  p += __shfl_xor(p, 1, 64);     \
  p += __shfl_xor(p, 2, 64);     \
  p += __shfl_xor(p, 4, 64);     \
  p += __shfl_xor(p, 8, 64);

#define BF4(dst, h)                                \
  dst.x = bf2f(h.x); dst.y = bf2f(h.y);            \
  dst.z = bf2f(h.z); dst.w = bf2f(h.w);

// p += sum_c t_c * (t_c>0 ? att_c : 0.2*att_c), t = xv + xri
#define DOTSEL(p, xv)                                              \
  { float t;                                                       \
    t = xv.x + xri.x; p = fmaf(t, t > 0.f ? a4.x : an4.x, p);      \
    t = xv.y + xri.y; p = fmaf(t, t > 0.f ? a4.y : an4.y, p);      \
    t = xv.z + xri.z; p = fmaf(t, t > 0.f ? a4.z : an4.z, p);      \
    t = xv.w + xri.w; p = fmaf(t, t > 0.f ? a4.w : an4.w, p); }

__global__ __launch_bounds__(256) void k_fused1(
    const unsigned short* __restrict__ xlh, const float* xr,
    const int* __restrict__ row_start, const int* __restrict__ csr_src,
    const float* __restrict__ att, const float* __restrict__ bias,
    float* out, int N) {
  int tid = threadIdx.x, lane = tid & 63, w = tid >> 6;
  int i = blockIdx.x * 4 + w;
  if (i >= N) return;
  float4 xri = *(const float4*)(xr + (size_t)i * F1 + lane * 4);
  float4 a4  = *(const float4*)(att + lane * 4);
  float4 an4;
  an4.x = NEG * a4.x; an4.y = NEG * a4.y; an4.z = NEG * a4.z; an4.w = NEG * a4.w;
  float m = -1e30f, den = 0.f;
  float4 acc = {0.f, 0.f, 0.f, 0.f};
  int b = row_start[i], e = row_start[i + 1];
  int k = b;
  for (; k + 3 < e; k += 4) {
    int s0 = csr_src[k], s1 = csr_src[k + 1];
    int s2 = csr_src[k + 2], s3 = csr_src[k + 3];
    ushort4 h0 = *(const ushort4*)(xlh + (size_t)s0 * F1 + lane * 4);
    ushort4 h1 = *(const ushort4*)(xlh + (size_t)s1 * F1 + lane * 4);
    ushort4 h2 = *(const ushort4*)(xlh + (size_t)s2 * F1 + lane * 4);
    ushort4 h3 = *(const ushort4*)(xlh + (size_t)s3 * F1 + lane * 4);
    float4 x0, x1, x2, x3;
    BF4(x0, h0); BF4(x1, h1); BF4(x2, h2); BF4(x3, h3);
    float p0 = 0.f, p1 = 0.f, p2 = 0.f, p3 = 0.f;
    DOTSEL(p0, x0); DOTSEL(p1, x1); DOTSEL(p2, x2); DOTSEL(p3, x3);
    RED16(p0); RED16(p1); RED16(p2); RED16(p3);
    float mn = fmaxf(fmaxf(m, p0), fmaxf(fmaxf(p1, p2), p3));
    float cs = __expf(m - mn);
    float w0 = __expf(p0 - mn), w1 = __expf(p1 - mn);
    float w2 = __expf(p2 - mn), w3 = __expf(p3 - mn);
    den = den * cs + (w0 + w1) + (w2 + w3);
    acc.x = acc.x * cs + w0 * x0.x + w1 * x1.x + w2 * x2.x + w3 * x3.x;
    acc.y = acc.y * cs + w0 * x0.y + w1 * x1.y + w2 * x2.y + w3 * x3.y;
    acc.z = acc.z * cs + w0 * x0.z + w1 * x1.z + w2 * x2.z + w3 * x3.z;
    acc.w = acc.w * cs + w0 * x0.w + w1 * x1.w + w2 * x2.w + w3 * x3.w;
    m = mn;
  }
  for (; k < e; k++) {
    int s = csr_src[k];
    ushort4 hh = *(const ushort4*)(xlh + (size_t)s * F1 + lane * 4);
    float4 xs;
    BF4(xs, hh);
    float p = 0.f;
    DOTSEL(p, xs);
    RED16(p);
    float mn = fmaxf(m, p);
    float cs = __expf(m - mn);
    float wt = __expf(p - mn);
    den = den * cs + wt;
    acc.x = acc.x * cs + wt * xs.x;
    acc.y = acc.y * cs + wt * xs.y;
    acc.z = acc.z * cs + wt * xs.z;
    acc.w = acc.w * cs + wt * xs.w;
    m = mn;
  }
  float inv = 1.f / den;
  float4 bz = *(const float4*)(bias + lane * 4);
  float4 o;
  o.x = fmaxf(acc.x * inv + bz.x, 0.f);
  o.y = fmaxf(acc.y * inv + bz.y, 0.f);
  o.z = fmaxf(acc.z * inv + bz.z, 0.f);
  o.w = fmaxf(acc.w * inv + bz.w, 0.f);
  *(float4*)(out + (size_t)i * F1 + lane * 4) = o;
}

// ---------------- fused layer-2: 4x16-lane groups, 8 edges in flight --------
__global__ __launch_bounds__(256) void k_fused2(
    const unsigned short* __restrict__ xlh, const float* xr,
    const int* __restrict__ row_start, const int* __restrict__ csr_src,
    const float* __restrict__ att, const float* __restrict__ bias,
    float* out, int N) {
  int tid = threadIdx.x, lane = tid & 63, w = tid >> 6;
  int i = blockIdx.x * 4 + w;
  if (i >= N) return;
  int g = lane >> 4, l16 = lane & 15;
  float4 xri = *(const float4*)(xr + (size_t)i * OUTD + l16 * 4);
  float4 a4  = *(const float4*)(att + l16 * 4);
  float4 an4;
  an4.x = NEG * a4.x; an4.y = NEG * a4.y; an4.z = NEG * a4.z; an4.w = NEG * a4.w;
  float m = -1e30f, den = 0.f;
  float4 acc = {0.f, 0.f, 0.f, 0.f};
  int b = row_start[i], e = row_start[i + 1];
  for (int k = b; k < e; k += 8) {
    int ea = k + g, eb = k + 4 + g;
    int sa = csr_src[ea < e ? ea : (e - 1)];
    int sb = csr_src[eb < e ? eb : (e - 1)];
    ushort4 ha = *(const ushort4*)(xlh + (size_t)sa * OUTD + l16 * 4);
    ushort4 hb = *(const ushort4*)(xlh + (size_t)sb * OUTD + l16 * 4);
    float4 xa, xb;
    BF4(xa, ha); BF4(xb, hb);
    float pa = 0.f, pb = 0.f;
    DOTSEL(pa, xa); DOTSEL(pb, xb);
    RED16(pa); RED16(pb);
    if (ea >= e) pa = -1e30f;
    if (eb >= e) pb = -1e30f;
    float mn = fmaxf(m, fmaxf(pa, pb));
    float cs = __expf(m - mn);
    float wa = __expf(pa - mn), wb = __expf(pb - mn);
    den = den * cs + wa + wb;
    acc.x = acc.x * cs + wa * xa.x + wb * xb.x;
    acc.y = acc.y * cs + wa * xa.y + wb * xb.y;
    acc.z = acc.z * cs + wa * xa.z + wb * xb.z;
    acc.w = acc.w * cs + wa * xa.w + wb * xb.w;
    m = mn;
  }
  // merge the 4 groups' partial (m, den, acc)
#pragma unroll
  for (int off = 16; off <= 32; off <<= 1) {
    float om   = __shfl_xor(m, off, 64);
    float oden = __shfl_xor(den, off, 64);
    float4 oa;
    oa.x = __shfl_xor(acc.x, off, 64);
    oa.y = __shfl_xor(acc.y, off, 64);
    oa.z = __shfl_xor(acc.z, off, 64);
    oa.w = __shfl_xor(acc.w, off, 64);
    float mn = fmaxf(m, om);
    float cs = __expf(m - mn), co = __expf(om - mn);
    den = den * cs + oden * co;
    acc.x = acc.x * cs + oa.x * co;
    acc.y = acc.y * cs + oa.y * co;
    acc.z = acc.z * cs + oa.z * co;
    acc.w = acc.w * cs + oa.w * co;
    m = mn;
  }
  if (g == 0) {
    float inv = 1.f / den;
    float4 bz = *(const float4*)(bias + l16 * 4);
    float4 o;
    o.x = acc.x * inv + bz.x;
    o.y = acc.y * inv + bz.y;
    o.z = acc.z * inv + bz.z;
    o.w = acc.w * inv + bz.w;
    *(float4*)(out + (size_t)i * OUTD + l16 * 4) = o;
  }
}

// ---------------- decoder stage B ------------------------------------------
__global__ __launch_bounds__(256) void k_link(
    const float* __restrict__ u, const float* __restrict__ v,
    const int* __restrict__ eli, int EL,
    const float* __restrict__ bm1, const float* __restrict__ Wm2,
    const float* __restrict__ bm2, float* __restrict__ out) {
  int tid = threadIdx.x, lane = tid & 63, w = tid >> 6;
  int li = lane >> 4, c4 = (lane & 15) * 4;
  int l = (blockIdx.x * 4 + w) * 4 + li;
  if (l >= EL) return;
  int a = eli[l], b = eli[EL + l];
  float4 uu = *(const float4*)(u + (size_t)a * OUTD + c4);
  float4 vv = *(const float4*)(v + (size_t)b * OUTD + c4);
  float4 bb = *(const float4*)(bm1 + c4);
  float4 ww = *(const float4*)(Wm2 + c4);
  float p = fmaxf(uu.x + vv.x + bb.x, 0.f) * ww.x
          + fmaxf(uu.y + vv.y + bb.y, 0.f) * ww.y
          + fmaxf(uu.z + vv.z + bb.z, 0.f) * ww.z
          + fmaxf(uu.w + vv.w + bb.w, 0.f) * ww.w;
  p += __shfl_xor(p, 1, 64);
  p += __shfl_xor(p, 2, 64);
  p += __shfl_xor(p, 4, 64);
  p += __shfl_xor(p, 8, 64);
  if ((lane & 15) == 0) out[l] = p + bm2[0];
}

extern "C" void kernel_launch(void* const* d_in, const int* in_sizes, int n_in,
                              void* d_out, int out_size, void* d_ws, size_t ws_size,
                              hipStream_t stream) {
  const float* x     = (const float*)d_in[0];
  const int*   ei    = (const int*)d_in[1];
  const int*   eli   = (const int*)d_in[2];
  const float* W1l   = (const float*)d_in[3];
  const float* b1l   = (const float*)d_in[4];
  const float* W1r   = (const float*)d_in[5];
  const float* b1r   = (const float*)d_in[6];
  const float* att1  = (const float*)d_in[7];
  const float* bias1 = (const float*)d_in[8];
  const float* W2l   = (const float*)d_in[9];
  const float* b2l   = (const float*)d_in[10];
  const float* W2r   = (const float*)d_in[11];
  const float* b2r   = (const float*)d_in[12];
  const float* att2  = (const float*)d_in[13];
  const float* bias2 = (const float*)d_in[14];
  const float* Wm1   = (const float*)d_in[15];
  const float* bm1   = (const float*)d_in[16];
  const float* Wm2   = (const float*)d_in[17];
  const float* bm2   = (const float*)d_in[18];

  int N = in_sizes[0] / IN_DIM;   // 50000
  int E = in_sizes[1] / 2;        // 800000
  int EL = in_sizes[2] / 2;       // 200000
  int Etot = E + N;

  // ---- workspace layout (bytes) ----
  // [0, 25.6M)        xl1h (bf16)   (layer2: xl2h bf16 @0, xr2/z2 f32 @12.8M)
  // [38.4M, 38.7M)    Wt (bf16)     [39.0M, 39.2M) Wt2   [39.2M, 39.3M) Wuv
  // [51.2M, 102.4M)   xr1 -> z      (decoder: u @51.2M, v @64M)
  // [102.4M ...)      row_start, cursor(=cnt=local_ps), csr_src, blk_sum
  char* ws = (char*)d_ws;
  unsigned short* xl1h = (unsigned short*)(ws);
  unsigned short* Wt   = (unsigned short*)(ws + 38400000);
  unsigned short* Wt2  = (unsigned short*)(ws + 39000000);
  unsigned short* Wuv  = (unsigned short*)(ws + 39200000);
  float* bufB      = (float*)(ws + 51200000);
  int*   row_start = (int*)(ws + 102400000);
  int*   cursor    = (int*)(ws + 102700000);
  int*   csr_src   = (int*)(ws + 103000000);
  int*   blk_sum   = (int*)(ws + 103000000 + (size_t)Etot * 4 + 256);
  unsigned short* xl2h = (unsigned short*)(ws);
  float* xr2       = (float*)(ws + 12800000);
  float* u_buf     = (float*)(ws + 51200000);
  float* v_buf     = (float*)(ws + 64000000);

  int nblk = (N + 1023) / 1024;   // 49 (<=64 required by k_scan2)

  // ---- weight conversions + CSR build ----
  hipMemsetAsync(cursor, 0, (size_t)N * 4, stream);
  k_cvt_w<<<(512 * IN_DIM + 255) / 256, 256, 0, stream>>>(W1l, W1r, Wt);
  k_cvt_w2<<<(128 * F1 + 255) / 256, 256, 0, stream>>>(W2l, W2r, Wt2);
  k_cvt_wuv<<<(128 * OUTD + 255) / 256, 256, 0, stream>>>(Wm1, Wuv);
  {
    dim3 g1((N + 63) / 64, 4);
    k_gemm1_mfma<<<g1, 256, 0, stream>>>(x, Wt, b1l, b1r, xl1h, bufB, N);
  }
  k_hist<<<(Etot + 255) / 256, 256, 0, stream>>>(ei, E, N, cursor);
  k_scan1<<<nblk, 256, 0, stream>>>(cursor, N, blk_sum);
  k_scan2<<<1, 64, 0, stream>>>(blk_sum, nblk);
  k_scan3<<<(N + 255) / 256, 256, 0, stream>>>(cursor, blk_sum, N, Etot,
                                               row_start, cursor);
  k_scatter<<<(Etot + 255) / 256, 256, 0, stream>>>(ei, E, N, cursor, csr_src);

  // ---- layer 1 (fused) ----
  k_fused1<<<(N + 3) / 4, 256, 0, stream>>>(xl1h, bufB, row_start, csr_src,
                                            att1, bias1, bufB, N);
  // ---- layer 2 ----
  k_gemm2_mfma<<<(N + 63) / 64, 256, 0, stream>>>(bufB, Wt2, b2l, b2r, xl2h, xr2, N);
  k_fused2<<<(N + 3) / 4, 256, 0, stream>>>(xl2h, xr2, row_start, csr_src,
                                            att2, bias2, xr2, N);
  // ---- decoder ----
  {
    dim3 g3((N + 63) / 64, 2);
    k_uv_mfma<<<g3, 256, 0, stream>>>(xr2, Wuv, u_buf, v_buf, N);
  }
  k_link<<<(EL + 15) / 16, 256, 0, stream>>>(u_buf, v_buf, eli, EL,
                                             bm1, Wm2, bm2, (float*)d_out);
}

// Round 12
// 347.482 us; speedup vs baseline: 5.4153x; 1.0205x over previous
//
#include <hip/hip_runtime.h>
#include <hip/hip_bf16.h>

#define IN_DIM 128
#define HID    64
#define NH     4
#define F1     256   // NH*HID
#define OUTD   64
#define NEG    0.2f

typedef __attribute__((ext_vector_type(8))) short bf16x8;
typedef __attribute__((ext_vector_type(4))) float f32x4;

__device__ __forceinline__ float bf2f(unsigned short h) {
  return __uint_as_float((unsigned)h << 16);
}
__device__ __forceinline__ unsigned short f2bf(float f) {
  unsigned u = __float_as_uint(f);
  u += 0x7fffu + ((u >> 16) & 1u);   // RTNE
  return (unsigned short)(u >> 16);
}
__device__ __forceinline__ bf16x8 f2bf8(const float* p) {
  float4 lo = *(const float4*)p;
  float4 hi = *(const float4*)(p + 4);
  bf16x8 r;
  r[0] = (short)f2bf(lo.x); r[1] = (short)f2bf(lo.y);
  r[2] = (short)f2bf(lo.z); r[3] = (short)f2bf(lo.w);
  r[4] = (short)f2bf(hi.x); r[5] = (short)f2bf(hi.y);
  r[6] = (short)f2bf(hi.z); r[7] = (short)f2bf(hi.w);
  return r;
}

// ---------------- weight conversions for MFMA GEMMs -------------------------
// Wt[c][k] (bf16, c in [0,512)) = c<256 ? W1l[k][c] : W1r[k][c-256]
__global__ __launch_bounds__(256) void k_cvt_w(
    const float* __restrict__ Wl, const float* __restrict__ Wr,
    unsigned short* __restrict__ Wt) {
  int idx = blockIdx.x * 256 + threadIdx.x;   // 512*128 total
  if (idx >= 512 * IN_DIM) return;
  int c = idx >> 7, k = idx & 127;
  float v = (c < F1) ? Wl[k * F1 + c] : Wr[k * F1 + (c - F1)];
  Wt[idx] = f2bf(v);
}

// Wt2[c][k] (c in [0,128), k in [0,256)) = c<64 ? W2l[k][c] : W2r[k][c-64]
__global__ __launch_bounds__(256) void k_cvt_w2(
    const float* __restrict__ Wl, const float* __restrict__ Wr,
    unsigned short* __restrict__ Wt2) {
  int idx = blockIdx.x * 256 + threadIdx.x;   // 128*256 total
  if (idx >= 128 * F1) return;
  int c = idx >> 8, k = idx & 255;
  float v = (c < OUTD) ? Wl[k * OUTD + c] : Wr[k * OUTD + (c - OUTD)];
  Wt2[idx] = f2bf(v);
}

// Wuv[c][k] (c in [0,128), k in [0,64)): c<64 -> Wm1[k][c], else Wm1[64+k][c-64]
__global__ __launch_bounds__(256) void k_cvt_wuv(
    const float* __restrict__ Wm1, unsigned short* __restrict__ Wuv) {
  int idx = blockIdx.x * 256 + threadIdx.x;   // 128*64 total
  if (idx >= 128 * OUTD) return;
  int c = idx >> 6, k = idx & 63;
  float v = (c < OUTD) ? Wm1[k * OUTD + c] : Wm1[(64 + k) * OUTD + (c - OUTD)];
  Wuv[idx] = f2bf(v);
}

// ---------------- layer-1 GEMM via MFMA (swapped operands) ------------------
// A = W fragment (rows = output cols), B = x fragment (cols = nodes).
// D[wcol][node]: lane (l16,khi) holds 4 CONSECUTIVE cols khi*4+[0,4) of node
// l16 -> single ushort4/float4 store per tile.
__global__ __launch_bounds__(256) void k_gemm1_mfma(
    const float* __restrict__ x, const unsigned short* __restrict__ Wt,
    const float* __restrict__ bl, const float* __restrict__ br,
    unsigned short* __restrict__ xlh, float* __restrict__ xr, int N) {
  int tid = threadIdx.x, lane = tid & 63, w = tid >> 6;
  int node0 = blockIdx.x * 64 + w * 16;
  int colbase = blockIdx.y * 128;
  int l16 = lane & 15, khi = lane >> 4;
  int koff = khi * 8;
  int arow = node0 + l16; if (arow >= N) arow = N - 1;
  const float* ap = x + (size_t)arow * IN_DIM + koff;
  bf16x8 b0 = f2bf8(ap);
  bf16x8 b1 = f2bf8(ap + 32);
  bf16x8 b2 = f2bf8(ap + 64);
  bf16x8 b3 = f2bf8(ap + 96);
  int node = node0 + l16;
  bool nok = node < N;
#pragma unroll
  for (int ct = 0; ct < 8; ct++) {
    int wrow = colbase + ct * 16 + l16;       // A-fragment row (output col)
    const unsigned short* wp = Wt + (size_t)wrow * IN_DIM + koff;
    f32x4 acc = {0.f, 0.f, 0.f, 0.f};
    acc = __builtin_amdgcn_mfma_f32_16x16x32_bf16(*(const bf16x8*)(wp), b0, acc, 0, 0, 0);
    acc = __builtin_amdgcn_mfma_f32_16x16x32_bf16(*(const bf16x8*)(wp + 32), b1, acc, 0, 0, 0);
    acc = __builtin_amdgcn_mfma_f32_16x16x32_bf16(*(const bf16x8*)(wp + 64), b2, acc, 0, 0, 0);
    acc = __builtin_amdgcn_mfma_f32_16x16x32_bf16(*(const bf16x8*)(wp + 96), b3, acc, 0, 0, 0);
    int cbase = colbase + ct * 16 + khi * 4;  // this lane's 4 output cols
    if (cbase < F1) {                         // uniform per block (colbase<256)
      float4 bb = *(const float4*)(bl + cbase);
      if (nok) {
        ushort4 o;
        o.x = f2bf(acc[0] + bb.x); o.y = f2bf(acc[1] + bb.y);
        o.z = f2bf(acc[2] + bb.z); o.w = f2bf(acc[3] + bb.w);
        *(ushort4*)(xlh + (size_t)node * F1 + cbase) = o;
      }
    } else {
      float4 bb = *(const float4*)(br + cbase - F1);
      if (nok) {
        float4 o;
        o.x = acc[0] + bb.x; o.y = acc[1] + bb.y;
        o.z = acc[2] + bb.z; o.w = acc[3] + bb.w;
        *(float4*)(xr + (size_t)node * F1 + (cbase - F1)) = o;
      }
    }
  }
}

// ---------------- layer-2 GEMM via MFMA (swapped), halves merged ------------
__global__ __launch_bounds__(256) void k_gemm2_mfma(
    const float* __restrict__ z, const unsigned short* __restrict__ Wt2,
    const float* __restrict__ bl, const float* __restrict__ br,
    unsigned short* __restrict__ xl2h, float* __restrict__ xr2, int N) {
  int tid = threadIdx.x, lane = tid & 63, w = tid >> 6;
  int node0 = blockIdx.x * 64 + w * 16;
  int l16 = lane & 15, khi = lane >> 4;
  int koff = khi * 8;
  int arow = node0 + l16; if (arow >= N) arow = N - 1;
  const float* zp = z + (size_t)arow * F1 + koff;
  bf16x8 bfr[8];
#pragma unroll
  for (int t = 0; t < 8; t++) bfr[t] = f2bf8(zp + 32 * t);
  int node = node0 + l16;
  bool nok = node < N;
#pragma unroll
  for (int half = 0; half < 2; half++) {
    const unsigned short* Wbase = Wt2 + (size_t)half * OUTD * F1;
#pragma unroll
    for (int ct = 0; ct < 4; ct++) {
      int wrow = ct * 16 + l16;
      const unsigned short* wp = Wbase + (size_t)wrow * F1 + koff;
      f32x4 acc = {0.f, 0.f, 0.f, 0.f};
#pragma unroll
      for (int t = 0; t < 8; t++)
        acc = __builtin_amdgcn_mfma_f32_16x16x32_bf16(
            *(const bf16x8*)(wp + 32 * t), bfr[t], acc, 0, 0, 0);
      int cbase = ct * 16 + khi * 4;
      if (half == 0) {
        float4 bb = *(const float4*)(bl + cbase);
        if (nok) {
          ushort4 o;
          o.x = f2bf(acc[0] + bb.x); o.y = f2bf(acc[1] + bb.y);
          o.z = f2bf(acc[2] + bb.z); o.w = f2bf(acc[3] + bb.w);
          *(ushort4*)(xl2h + (size_t)node * OUTD + cbase) = o;
        }
      } else {
        float4 bb = *(const float4*)(br + cbase);
        if (nok) {
          float4 o;
          o.x = acc[0] + bb.x; o.y = acc[1] + bb.y;
          o.z = acc[2] + bb.z; o.w = acc[3] + bb.w;
          *(float4*)(xr2 + (size_t)node * OUTD + cbase) = o;
        }
      }
    }
  }
}

// ---------------- decoder uv GEMM via MFMA (swapped) ------------------------
__global__ __launch_bounds__(256) void k_uv_mfma(
    const float* __restrict__ z2, const unsigned short* __restrict__ Wuv,
    float* __restrict__ u, float* __restrict__ v, int N) {
  int tid = threadIdx.x, lane = tid & 63, w = tid >> 6;
  int node0 = blockIdx.x * 64 + w * 16;
  int half = blockIdx.y;
  int l16 = lane & 15, khi = lane >> 4;
  int koff = khi * 8;
  int arow = node0 + l16; if (arow >= N) arow = N - 1;
  const float* zp = z2 + (size_t)arow * OUTD + koff;
  bf16x8 b0 = f2bf8(zp);
  bf16x8 b1 = f2bf8(zp + 32);
  const unsigned short* Wbase = Wuv + (size_t)half * OUTD * OUTD;
  float* dst = half ? v : u;
  int node = node0 + l16;
  bool nok = node < N;
#pragma unroll
  for (int ct = 0; ct < 4; ct++) {
    int wrow = ct * 16 + l16;
    const unsigned short* wp = Wbase + (size_t)wrow * OUTD + koff;
    f32x4 acc = {0.f, 0.f, 0.f, 0.f};
    acc = __builtin_amdgcn_mfma_f32_16x16x32_bf16(*(const bf16x8*)(wp), b0, acc, 0, 0, 0);
    acc = __builtin_amdgcn_mfma_f32_16x16x32_bf16(*(const bf16x8*)(wp + 32), b1, acc, 0, 0, 0);
    int cbase = ct * 16 + khi * 4;
    if (nok) {
      float4 o;
      o.x = acc[0]; o.y = acc[1]; o.z = acc[2]; o.w = acc[3];
      *(float4*)(dst + (size_t)node * OUTD + cbase) = o;
    }
  }
}

// ---------------- CSR build: histogram -> 3-stage scan -> scatter ----------
__global__ __launch_bounds__(256) void k_hist(
    const int* __restrict__ ei, int E, int N, int* __restrict__ cnt) {
  int e = blockIdx.x * 256 + threadIdx.x;
  if (e >= E + N) return;
  int d = (e < E) ? ei[E + e] : (e - E);
  atomicAdd(&cnt[d], 1);
}

__global__ __launch_bounds__(256) void k_scan1(
    int* __restrict__ cnt, int N, int* __restrict__ blk_sum) {
  int t = threadIdx.x, lane = t & 63, wid = t >> 6;
  int base = blockIdx.x * 1024 + t * 4;
  int4 v = {0, 0, 0, 0};
  if (base + 3 < N) {
    v = *(const int4*)(cnt + base);
  } else {
    if (base + 0 < N) v.x = cnt[base + 0];
    if (base + 1 < N) v.y = cnt[base + 1];
    if (base + 2 < N) v.z = cnt[base + 2];
    if (base + 3 < N) v.w = cnt[base + 3];
  }
  int s = v.x + v.y + v.z + v.w;
  int inc = s;
#pragma unroll
  for (int off = 1; off < 64; off <<= 1) {
    int u = __shfl_up(inc, off, 64);
    if (lane >= off) inc += u;
  }
  __shared__ int wsum[4];
  if (lane == 63) wsum[wid] = inc;
  __syncthreads();
  int wofs = 0;
#pragma unroll
  for (int q = 0; q < 4; q++) if (q < wid) wofs += wsum[q];
  int excl = wofs + inc - s;
  int4 o;
  o.x = excl; o.y = excl + v.x; o.z = o.y + v.y; o.w = o.z + v.z;
  if (base + 3 < N) {
    *(int4*)(cnt + base) = o;
  } else {
    if (base + 0 < N) cnt[base + 0] = o.x;
    if (base + 1 < N) cnt[base + 1] = o.y;
    if (base + 2 < N) cnt[base + 2] = o.z;
    if (base + 3 < N) cnt[base + 3] = o.w;
  }
  if (t == 255) blk_sum[blockIdx.x] = wofs + inc;
}

__global__ void k_scan2(int* __restrict__ blk, int nblk) {
  int lane = threadIdx.x;
  int v = (lane < nblk) ? blk[lane] : 0;
  int inc = v;
#pragma unroll
  for (int off = 1; off < 64; off <<= 1) {
    int u = __shfl_up(inc, off, 64);
    if (lane >= off) inc += u;
  }
  if (lane < nblk) blk[lane] = inc - v;
}

__global__ __launch_bounds__(256) void k_scan3(
    const int* __restrict__ local_ps, const int* __restrict__ blk_sum,
    int N, int Etot, int* __restrict__ row_start, int* __restrict__ cursor) {
  int i = blockIdx.x * 256 + threadIdx.x;
  if (i < N) {
    int p = local_ps[i] + blk_sum[i >> 10];
    row_start[i] = p;
    cursor[i] = p;
  }
  if (i == 0) row_start[N] = Etot;
}

__global__ __launch_bounds__(256) void k_scatter(
    const int* __restrict__ ei, int E, int N,
    int* __restrict__ cursor, int* __restrict__ csr_src) {
  int e = blockIdx.x * 256 + threadIdx.x;
  if (e >= E + N) return;
  int s, d;
  if (e < E) { s = ei[e]; d = ei[E + e]; } else { s = e - E; d = s; }
  int pos = atomicAdd(&cursor[d], 1);
  csr_src[pos] = s;
}

// ---------------- fused layer-1 (bf16 xl gathers, att-select dot) -----------
#define RED16(p)                 \
  p += __shfl_xor(p, 1, 64);     \
  p += __shfl_xor(p, 2, 64);     \
  p += __shfl_xor(p, 4, 64);     \
  p += __shfl_xor(p, 8, 64);

#define BF4(dst, h)                                \
  dst.x = bf2f(h.x); dst.y = bf2f(h.y);            \
  dst.z = bf2f(h.z); dst.w = bf2f(h.w);

// p += sum_c t_c * (t_c>0 ? att_c : 0.2*att_c), t = xv + xri
#define DOTSEL(p, xv)                                              \
  { float t;                                                       \
    t = xv.x + xri.x; p = fmaf(t, t > 0.f ? a4.x : an4.x, p);      \
    t = xv.y + xri.y; p = fmaf(t, t > 0.f ? a4.y : an4.y, p);      \
    t = xv.z + xri.z; p = fmaf(t, t > 0.f ? a4.z : an4.z, p);      \
    t = xv.w + xri.w; p = fmaf(t, t > 0.f ? a4.w : an4.w, p); }

__global__ __launch_bounds__(256) void k_fused1(
    const unsigned short* __restrict__ xlh, const float* xr,
    const int* __restrict__ row_start, const int* __restrict__ csr_src,
    const float* __restrict__ att, const float* __restrict__ bias,
    float* out, int N) {
  int tid = threadIdx.x, lane = tid & 63, w = tid >> 6;
  int i = blockIdx.x * 4 + w;
  if (i >= N) return;
  float4 xri = *(const float4*)(xr + (size_t)i * F1 + lane * 4);
  float4 a4  = *(const float4*)(att + lane * 4);
  float4 an4;
  an4.x = NEG * a4.x; an4.y = NEG * a4.y; an4.z = NEG * a4.z; an4.w = NEG * a4.w;
  float m = -1e30f, den = 0.f;
  float4 acc = {0.f, 0.f, 0.f, 0.f};
  int b = row_start[i], e = row_start[i + 1];
  int k = b;
  for (; k + 3 < e; k += 4) {
    int s0 = csr_src[k], s1 = csr_src[k + 1];
    int s2 = csr_src[k + 2], s3 = csr_src[k + 3];
    ushort4 h0 = *(const ushort4*)(xlh + (size_t)s0 * F1 + lane * 4);
    ushort4 h1 = *(const ushort4*)(xlh + (size_t)s1 * F1 + lane * 4);
    ushort4 h2 = *(const ushort4*)(xlh + (size_t)s2 * F1 + lane * 4);
    ushort4 h3 = *(const ushort4*)(xlh + (size_t)s3 * F1 + lane * 4);
    float4 x0, x1, x2, x3;
    BF4(x0, h0); BF4(x1, h1); BF4(x2, h2); BF4(x3, h3);
    float p0 = 0.f, p1 = 0.f, p2 = 0.f, p3 = 0.f;
    DOTSEL(p0, x0); DOTSEL(p1, x1); DOTSEL(p2, x2); DOTSEL(p3, x3);
    RED16(p0); RED16(p1); RED16(p2); RED16(p3);
    float mn = fmaxf(fmaxf(m, p0), fmaxf(fmaxf(p1, p2), p3));
    float cs = __expf(m - mn);
    float w0 = __expf(p0 - mn), w1 = __expf(p1 - mn);
    float w2 = __expf(p2 - mn), w3 = __expf(p3 - mn);
    den = den * cs + (w0 + w1) + (w2 + w3);
    acc.x = acc.x * cs + w0 * x0.x + w1 * x1.x + w2 * x2.x + w3 * x3.x;
    acc.y = acc.y * cs + w0 * x0.y + w1 * x1.y + w2 * x2.y + w3 * x3.y;
    acc.z = acc.z * cs + w0 * x0.z + w1 * x1.z + w2 * x2.z + w3 * x3.z;
    acc.w = acc.w * cs + w0 * x0.w + w1 * x1.w + w2 * x2.w + w3 * x3.w;
    m = mn;
  }
  for (; k < e; k++) {
    int s = csr_src[k];
    ushort4 hh = *(const ushort4*)(xlh + (size_t)s * F1 + lane * 4);
    float4 xs;
    BF4(xs, hh);
    float p = 0.f;
    DOTSEL(p, xs);
    RED16(p);
    float mn = fmaxf(m, p);
    float cs = __expf(m - mn);
    float wt = __expf(p - mn);
    den = den * cs + wt;
    acc.x = acc.x * cs + wt * xs.x;
    acc.y = acc.y * cs + wt * xs.y;
    acc.z = acc.z * cs + wt * xs.z;
    acc.w = acc.w * cs + wt * xs.w;
    m = mn;
  }
  float inv = 1.f / den;
  float4 bz = *(const float4*)(bias + lane * 4);
  float4 o;
  o.x = fmaxf(acc.x * inv + bz.x, 0.f);
  o.y = fmaxf(acc.y * inv + bz.y, 0.f);
  o.z = fmaxf(acc.z * inv + bz.z, 0.f);
  o.w = fmaxf(acc.w * inv + bz.w, 0.f);
  *(float4*)(out + (size_t)i * F1 + lane * 4) = o;
}

// ---------------- fused layer-2: 4x16-lane groups, 8 edges in flight --------
__global__ __launch_bounds__(256) void k_fused2(
    const unsigned short* __restrict__ xlh, const float* xr,
    const int* __restrict__ row_start, const int* __restrict__ csr_src,
    const float* __restrict__ att, const float* __restrict__ bias,
    float* out, int N) {
  int tid = threadIdx.x, lane = tid & 63, w = tid >> 6;
  int i = blockIdx.x * 4 + w;
  if (i >= N) return;
  int g = lane >> 4, l16 = lane & 15;
  float4 xri = *(const float4*)(xr + (size_t)i * OUTD + l16 * 4);
  float4 a4  = *(const float4*)(att + l16 * 4);
  float4 an4;
  an4.x = NEG * a4.x; an4.y = NEG * a4.y; an4.z = NEG * a4.z; an4.w = NEG * a4.w;
  float m = -1e30f, den = 0.f;
  float4 acc = {0.f, 0.f, 0.f, 0.f};
  int b = row_start[i], e = row_start[i + 1];
  for (int k = b; k < e; k += 8) {
    int ea = k + g, eb = k + 4 + g;
    int sa = csr_src[ea < e ? ea : (e - 1)];
    int sb = csr_src[eb < e ? eb : (e - 1)];
    ushort4 ha = *(const ushort4*)(xlh + (size_t)sa * OUTD + l16 * 4);
    ushort4 hb = *(const ushort4*)(xlh + (size_t)sb * OUTD + l16 * 4);
    float4 xa, xb;
    BF4(xa, ha); BF4(xb, hb);
    float pa = 0.f, pb = 0.f;
    DOTSEL(pa, xa); DOTSEL(pb, xb);
    RED16(pa); RED16(pb);
    if (ea >= e) pa = -1e30f;
    if (eb >= e) pb = -1e30f;
    float mn = fmaxf(m, fmaxf(pa, pb));
    float cs = __expf(m - mn);
    float wa = __expf(pa - mn), wb = __expf(pb - mn);
    den = den * cs + wa + wb;
    acc.x = acc.x * cs + wa * xa.x + wb * xb.x;
    acc.y = acc.y * cs + wa * xa.y + wb * xb.y;
    acc.z = acc.z * cs + wa * xa.z + wb * xb.z;
    acc.w = acc.w * cs + wa * xa.w + wb * xb.w;
    m = mn;
  }
  // merge the 4 groups' partial (m, den, acc)
#pragma unroll
  for (int off = 16; off <= 32; off <<= 1) {
    float om   = __shfl_xor(m, off, 64);
    float oden = __shfl_xor(den, off, 64);
    float4 oa;
    oa.x = __shfl_xor(acc.x, off, 64);
    oa.y = __shfl_xor(acc.y, off, 64);
    oa.z = __shfl_xor(acc.z, off, 64);
    oa.w = __shfl_xor(acc.w, off, 64);
    float mn = fmaxf(m, om);
    float cs = __expf(m - mn), co = __expf(om - mn);
    den = den * cs + oden * co;
    acc.x = acc.x * cs + oa.x * co;
    acc.y = acc.y * cs + oa.y * co;
    acc.z = acc.z * cs + oa.z * co;
    acc.w = acc.w * cs + oa.w * co;
    m = mn;
  }
  if (g == 0) {
    float inv = 1.f / den;
    float4 bz = *(const float4*)(bias + l16 * 4);
    float4 o;
    o.x = acc.x * inv + bz.x;
    o.y = acc.y * inv + bz.y;
    o.z = acc.z * inv + bz.z;
    o.w = acc.w * inv + bz.w;
    *(float4*)(out + (size_t)i * OUTD + l16 * 4) = o;
  }
}

// ---------------- decoder stage B ------------------------------------------
__global__ __launch_bounds__(256) void k_link(
    const float* __restrict__ u, const float* __restrict__ v,
    const int* __restrict__ eli, int EL,
    const float* __restrict__ bm1, const float* __restrict__ Wm2,
    const float* __restrict__ bm2, float* __restrict__ out) {
  int tid = threadIdx.x, lane = tid & 63, w = tid >> 6;
  int li = lane >> 4, c4 = (lane & 15) * 4;
  int l = (blockIdx.x * 4 + w) * 4 + li;
  if (l >= EL) return;
  int a = eli[l], b = eli[EL + l];
  float4 uu = *(const float4*)(u + (size_t)a * OUTD + c4);
  float4 vv = *(const float4*)(v + (size_t)b * OUTD + c4);
  float4 bb = *(const float4*)(bm1 + c4);
  float4 ww = *(const float4*)(Wm2 + c4);
  float p = fmaxf(uu.x + vv.x + bb.x, 0.f) * ww.x
          + fmaxf(uu.y + vv.y + bb.y, 0.f) * ww.y
          + fmaxf(uu.z + vv.z + bb.z, 0.f) * ww.z
          + fmaxf(uu.w + vv.w + bb.w, 0.f) * ww.w;
  p += __shfl_xor(p, 1, 64);
  p += __shfl_xor(p, 2, 64);
  p += __shfl_xor(p, 4, 64);
  p += __shfl_xor(p, 8, 64);
  if ((lane & 15) == 0) out[l] = p + bm2[0];
}

extern "C" void kernel_launch(void* const* d_in, const int* in_sizes, int n_in,
                              void* d_out, int out_size, void* d_ws, size_t ws_size,
                              hipStream_t stream) {
  const float* x     = (const float*)d_in[0];
  const int*   ei    = (const int*)d_in[1];
  const int*   eli   = (const int*)d_in[2];
  const float* W1l   = (const float*)d_in[3];
  const float* b1l   = (const float*)d_in[4];
  const float* W1r   = (const float*)d_in[5];
  const float* b1r   = (const float*)d_in[6];
  const float* att1  = (const float*)d_in[7];
  const float* bias1 = (const float*)d_in[8];
  const float* W2l   = (const float*)d_in[9];
  const float* b2l   = (const float*)d_in[10];
  const float* W2r   = (const float*)d_in[11];
  const float* b2r   = (const float*)d_in[12];
  const float* att2  = (const float*)d_in[13];
  const float* bias2 = (const float*)d_in[14];
  const float* Wm1   = (const float*)d_in[15];
  const float* bm1   = (const float*)d_in[16];
  const float* Wm2   = (const float*)d_in[17];
  const float* bm2   = (const float*)d_in[18];

  int N = in_sizes[0] / IN_DIM;   // 50000
  int E = in_sizes[1] / 2;        // 800000
  int EL = in_sizes[2] / 2;       // 200000
  int Etot = E + N;

  // ---- workspace layout (bytes) ----
  // [0, 25.6M)        xl1h (bf16)   (layer2: xl2h bf16 @0, xr2/z2 f32 @12.8M)
  // [38.4M, 38.7M)    Wt (bf16)     [39.0M, 39.2M) Wt2   [39.2M, 39.3M) Wuv
  // [51.2M, 102.4M)   xr1 -> z      (decoder: u @51.2M, v @64M)
  // [102.4M ...)      row_start, cursor(=cnt=local_ps), csr_src, blk_sum
  char* ws = (char*)d_ws;
  unsigned short* xl1h = (unsigned short*)(ws);
  unsigned short* Wt   = (unsigned short*)(ws + 38400000);
  unsigned short* Wt2  = (unsigned short*)(ws + 39000000);
  unsigned short* Wuv  = (unsigned short*)(ws + 39200000);
  float* bufB      = (float*)(ws + 51200000);
  int*   row_start = (int*)(ws + 102400000);
  int*   cursor    = (int*)(ws + 102700000);
  int*   csr_src   = (int*)(ws + 103000000);
  int*   blk_sum   = (int*)(ws + 103000000 + (size_t)Etot * 4 + 256);
  unsigned short* xl2h = (unsigned short*)(ws);
  float* xr2       = (float*)(ws + 12800000);
  float* u_buf     = (float*)(ws + 51200000);
  float* v_buf     = (float*)(ws + 64000000);

  int nblk = (N + 1023) / 1024;   // 49 (<=64 required by k_scan2)

  // ---- weight conversions + CSR build ----
  hipMemsetAsync(cursor, 0, (size_t)N * 4, stream);
  k_cvt_w<<<(512 * IN_DIM + 255) / 256, 256, 0, stream>>>(W1l, W1r, Wt);
  k_cvt_w2<<<(128 * F1 + 255) / 256, 256, 0, stream>>>(W2l, W2r, Wt2);
  k_cvt_wuv<<<(128 * OUTD + 255) / 256, 256, 0, stream>>>(Wm1, Wuv);
  {
    dim3 g1((N + 63) / 64, 4);
    k_gemm1_mfma<<<g1, 256, 0, stream>>>(x, Wt, b1l, b1r, xl1h, bufB, N);
  }
  k_hist<<<(Etot + 255) / 256, 256, 0, stream>>>(ei, E, N, cursor);
  k_scan1<<<nblk, 256, 0, stream>>>(cursor, N, blk_sum);
  k_scan2<<<1, 64, 0, stream>>>(blk_sum, nblk);
  k_scan3<<<(N + 255) / 256, 256, 0, stream>>>(cursor, blk_sum, N, Etot,
                                               row_start, cursor);
  k_scatter<<<(Etot + 255) / 256, 256, 0, stream>>>(ei, E, N, cursor, csr_src);

  // ---- layer 1 (fused) ----
  k_fused1<<<(N + 3) / 4, 256, 0, stream>>>(xl1h, bufB, row_start, csr_src,
                                            att1, bias1, bufB, N);
  // ---- layer 2 ----
  k_gemm2_mfma<<<(N + 63) / 64, 256, 0, stream>>>(bufB, Wt2, b2l, b2r, xl2h, xr2, N);
  k_fused2<<<(N + 3) / 4, 256, 0, stream>>>(xl2h, xr2, row_start, csr_src,
                                            att2, bias2, xr2, N);
  // ---- decoder ----
  {
    dim3 g3((N + 63) / 64, 2);
    k_uv_mfma<<<g3, 256, 0, stream>>>(xr2, Wuv, u_buf, v_buf, N);
  }
  k_link<<<(EL + 15) / 16, 256, 0, stream>>>(u_buf, v_buf, eli, EL,
                                             bm1, Wm2, bm2, (float*)d_out);
}

// Round 14
// 343.111 us; speedup vs baseline: 5.4843x; 1.0127x over previous
//
#include <hip/hip_runtime.h>
#include <hip/hip_bf16.h>

#define IN_DIM 128
#define HID    64
#define NH     4
#define F1     256   // NH*HID
#define OUTD   64
#define NEG    0.2f
#define LOG2E  1.44269504088896f

#define EXP2F(x) __builtin_amdgcn_exp2f(x)

typedef __attribute__((ext_vector_type(8))) short bf16x8;
typedef __attribute__((ext_vector_type(4))) float f32x4;

__device__ __forceinline__ float bf2f(unsigned short h) {
  return __uint_as_float((unsigned)h << 16);
}
__device__ __forceinline__ unsigned short f2bf(float f) {
  unsigned u = __float_as_uint(f);
  u += 0x7fffu + ((u >> 16) & 1u);   // RTNE
  return (unsigned short)(u >> 16);
}
__device__ __forceinline__ bf16x8 f2bf8(const float* p) {
  float4 lo = *(const float4*)p;
  float4 hi = *(const float4*)(p + 4);
  bf16x8 r;
  r[0] = (short)f2bf(lo.x); r[1] = (short)f2bf(lo.y);
  r[2] = (short)f2bf(lo.z); r[3] = (short)f2bf(lo.w);
  r[4] = (short)f2bf(hi.x); r[5] = (short)f2bf(hi.y);
  r[6] = (short)f2bf(hi.z); r[7] = (short)f2bf(hi.w);
  return r;
}

// ---------------- weight conversions for MFMA GEMMs -------------------------
__global__ __launch_bounds__(256) void k_cvt_w(
    const float* __restrict__ Wl, const float* __restrict__ Wr,
    unsigned short* __restrict__ Wt) {
  int idx = blockIdx.x * 256 + threadIdx.x;   // 512*128 total
  if (idx >= 512 * IN_DIM) return;
  int c = idx >> 7, k = idx & 127;
  float v = (c < F1) ? Wl[k * F1 + c] : Wr[k * F1 + (c - F1)];
  Wt[idx] = f2bf(v);
}

__global__ __launch_bounds__(256) void k_cvt_w2(
    const float* __restrict__ Wl, const float* __restrict__ Wr,
    unsigned short* __restrict__ Wt2) {
  int idx = blockIdx.x * 256 + threadIdx.x;   // 128*256 total
  if (idx >= 128 * F1) return;
  int c = idx >> 8, k = idx & 255;
  float v = (c < OUTD) ? Wl[k * OUTD + c] : Wr[k * OUTD + (c - OUTD)];
  Wt2[idx] = f2bf(v);
}

__global__ __launch_bounds__(256) void k_cvt_wuv(
    const float* __restrict__ Wm1, unsigned short* __restrict__ Wuv) {
  int idx = blockIdx.x * 256 + threadIdx.x;   // 128*64 total
  if (idx >= 128 * OUTD) return;
  int c = idx >> 6, k = idx & 63;
  float v = (c < OUTD) ? Wm1[k * OUTD + c] : Wm1[(64 + k) * OUTD + (c - OUTD)];
  Wuv[idx] = f2bf(v);
}

// ---------------- layer-1 GEMM via MFMA (swapped operands) ------------------
__global__ __launch_bounds__(256) void k_gemm1_mfma(
    const float* __restrict__ x, const unsigned short* __restrict__ Wt,
    const float* __restrict__ bl, const float* __restrict__ br,
    unsigned short* __restrict__ xlh, float* __restrict__ xr, int N) {
  int tid = threadIdx.x, lane = tid & 63, w = tid >> 6;
  int node0 = blockIdx.x * 64 + w * 16;
  int colbase = blockIdx.y * 128;
  int l16 = lane & 15, khi = lane >> 4;
  int koff = khi * 8;
  int arow = node0 + l16; if (arow >= N) arow = N - 1;
  const float* ap = x + (size_t)arow * IN_DIM + koff;
  bf16x8 b0 = f2bf8(ap);
  bf16x8 b1 = f2bf8(ap + 32);
  bf16x8 b2 = f2bf8(ap + 64);
  bf16x8 b3 = f2bf8(ap + 96);
  int node = node0 + l16;
  bool nok = node < N;
#pragma unroll
  for (int ct = 0; ct < 8; ct++) {
    int wrow = colbase + ct * 16 + l16;
    const unsigned short* wp = Wt + (size_t)wrow * IN_DIM + koff;
    f32x4 acc = {0.f, 0.f, 0.f, 0.f};
    acc = __builtin_amdgcn_mfma_f32_16x16x32_bf16(*(const bf16x8*)(wp), b0, acc, 0, 0, 0);
    acc = __builtin_amdgcn_mfma_f32_16x16x32_bf16(*(const bf16x8*)(wp + 32), b1, acc, 0, 0, 0);
    acc = __builtin_amdgcn_mfma_f32_16x16x32_bf16(*(const bf16x8*)(wp + 64), b2, acc, 0, 0, 0);
    acc = __builtin_amdgcn_mfma_f32_16x16x32_bf16(*(const bf16x8*)(wp + 96), b3, acc, 0, 0, 0);
    int cbase = colbase + ct * 16 + khi * 4;
    if (cbase < F1) {
      float4 bb = *(const float4*)(bl + cbase);
      if (nok) {
        ushort4 o;
        o.x = f2bf(acc[0] + bb.x); o.y = f2bf(acc[1] + bb.y);
        o.z = f2bf(acc[2] + bb.z); o.w = f2bf(acc[3] + bb.w);
        *(ushort4*)(xlh + (size_t)node * F1 + cbase) = o;
      }
    } else {
      float4 bb = *(const float4*)(br + cbase - F1);
      if (nok) {
        float4 o;
        o.x = acc[0] + bb.x; o.y = acc[1] + bb.y;
        o.z = acc[2] + bb.z; o.w = acc[3] + bb.w;
        *(float4*)(xr + (size_t)node * F1 + (cbase - F1)) = o;
      }
    }
  }
}

// ---------------- layer-2 GEMM via MFMA (swapped), halves merged ------------
__global__ __launch_bounds__(256) void k_gemm2_mfma(
    const float* __restrict__ z, const unsigned short* __restrict__ Wt2,
    const float* __restrict__ bl, const float* __restrict__ br,
    unsigned short* __restrict__ xl2h, float* __restrict__ xr2, int N) {
  int tid = threadIdx.x, lane = tid & 63, w = tid >> 6;
  int node0 = blockIdx.x * 64 + w * 16;
  int l16 = lane & 15, khi = lane >> 4;
  int koff = khi * 8;
  int arow = node0 + l16; if (arow >= N) arow = N - 1;
  const float* zp = z + (size_t)arow * F1 + koff;
  bf16x8 bfr[8];
#pragma unroll
  for (int t = 0; t < 8; t++) bfr[t] = f2bf8(zp + 32 * t);
  int node = node0 + l16;
  bool nok = node < N;
#pragma unroll
  for (int half = 0; half < 2; half++) {
    const unsigned short* Wbase = Wt2 + (size_t)half * OUTD * F1;
#pragma unroll
    for (int ct = 0; ct < 4; ct++) {
      int wrow = ct * 16 + l16;
      const unsigned short* wp = Wbase + (size_t)wrow * F1 + koff;
      f32x4 acc = {0.f, 0.f, 0.f, 0.f};
#pragma unroll
      for (int t = 0; t < 8; t++)
        acc = __builtin_amdgcn_mfma_f32_16x16x32_bf16(
            *(const bf16x8*)(wp + 32 * t), bfr[t], acc, 0, 0, 0);
      int cbase = ct * 16 + khi * 4;
      if (half == 0) {
        float4 bb = *(const float4*)(bl + cbase);
        if (nok) {
          ushort4 o;
          o.x = f2bf(acc[0] + bb.x); o.y = f2bf(acc[1] + bb.y);
          o.z = f2bf(acc[2] + bb.z); o.w = f2bf(acc[3] + bb.w);
          *(ushort4*)(xl2h + (size_t)node * OUTD + cbase) = o;
        }
      } else {
        float4 bb = *(const float4*)(br + cbase);
        if (nok) {
          float4 o;
          o.x = acc[0] + bb.x; o.y = acc[1] + bb.y;
          o.z = acc[2] + bb.z; o.w = acc[3] + bb.w;
          *(float4*)(xr2 + (size_t)node * OUTD + cbase) = o;
        }
      }
    }
  }
}

// ---------------- decoder uv GEMM via MFMA (swapped) ------------------------
__global__ __launch_bounds__(256) void k_uv_mfma(
    const float* __restrict__ z2, const unsigned short* __restrict__ Wuv,
    float* __restrict__ u, float* __restrict__ v, int N) {
  int tid = threadIdx.x, lane = tid & 63, w = tid >> 6;
  int node0 = blockIdx.x * 64 + w * 16;
  int half = blockIdx.y;
  int l16 = lane & 15, khi = lane >> 4;
  int koff = khi * 8;
  int arow = node0 + l16; if (arow >= N) arow = N - 1;
  const float* zp = z2 + (size_t)arow * OUTD + koff;
  bf16x8 b0 = f2bf8(zp);
  bf16x8 b1 = f2bf8(zp + 32);
  const unsigned short* Wbase = Wuv + (size_t)half * OUTD * OUTD;
  float* dst = half ? v : u;
  int node = node0 + l16;
  bool nok = node < N;
#pragma unroll
  for (int ct = 0; ct < 4; ct++) {
    int wrow = ct * 16 + l16;
    const unsigned short* wp = Wbase + (size_t)wrow * OUTD + koff;
    f32x4 acc = {0.f, 0.f, 0.f, 0.f};
    acc = __builtin_amdgcn_mfma_f32_16x16x32_bf16(*(const bf16x8*)(wp), b0, acc, 0, 0, 0);
    acc = __builtin_amdgcn_mfma_f32_16x16x32_bf16(*(const bf16x8*)(wp + 32), b1, acc, 0, 0, 0);
    int cbase = ct * 16 + khi * 4;
    if (nok) {
      float4 o;
      o.x = acc[0]; o.y = acc[1]; o.z = acc[2]; o.w = acc[3];
      *(float4*)(dst + (size_t)node * OUTD + cbase) = o;
    }
  }
}

// ---------------- CSR build: histogram -> 3-stage scan -> scatter ----------
__global__ __launch_bounds__(256) void k_hist(
    const int* __restrict__ ei, int E, int N, int* __restrict__ cnt) {
  int e = blockIdx.x * 256 + threadIdx.x;
  if (e >= E + N) return;
  int d = (e < E) ? ei[E + e] : (e - E);
  atomicAdd(&cnt[d], 1);
}

__global__ __launch_bounds__(256) void k_scan1(
    int* __restrict__ cnt, int N, int* __restrict__ blk_sum) {
  int t = threadIdx.x, lane = t & 63, wid = t >> 6;
  int base = blockIdx.x * 1024 + t * 4;
  int4 v = {0, 0, 0, 0};
  if (base + 3 < N) {
    v = *(const int4*)(cnt + base);
  } else {
    if (base + 0 < N) v.x = cnt[base + 0];
    if (base + 1 < N) v.y = cnt[base + 1];
    if (base + 2 < N) v.z = cnt[base + 2];
    if (base + 3 < N) v.w = cnt[base + 3];
  }
  int s = v.x + v.y + v.z + v.w;
  int inc = s;
#pragma unroll
  for (int off = 1; off < 64; off <<= 1) {
    int u = __shfl_up(inc, off, 64);
    if (lane >= off) inc += u;
  }
  __shared__ int wsum[4];
  if (lane == 63) wsum[wid] = inc;
  __syncthreads();
  int wofs = 0;
#pragma unroll
  for (int q = 0; q < 4; q++) if (q < wid) wofs += wsum[q];
  int excl = wofs + inc - s;
  int4 o;
  o.x = excl; o.y = excl + v.x; o.z = o.y + v.y; o.w = o.z + v.z;
  if (base + 3 < N) {
    *(int4*)(cnt + base) = o;
  } else {
    if (base + 0 < N) cnt[base + 0] = o.x;
    if (base + 1 < N) cnt[base + 1] = o.y;
    if (base + 2 < N) cnt[base + 2] = o.z;
    if (base + 3 < N) cnt[base + 3] = o.w;
  }
  if (t == 255) blk_sum[blockIdx.x] = wofs + inc;
}

__global__ void k_scan2(int* __restrict__ blk, int nblk) {
  int lane = threadIdx.x;
  int v = (lane < nblk) ? blk[lane] : 0;
  int inc = v;
#pragma unroll
  for (int off = 1; off < 64; off <<= 1) {
    int u = __shfl_up(inc, off, 64);
    if (lane >= off) inc += u;
  }
  if (lane < nblk) blk[lane] = inc - v;
}

__global__ __launch_bounds__(256) void k_scan3(
    const int* __restrict__ local_ps, const int* __restrict__ blk_sum,
    int N, int Etot, int* __restrict__ row_start, int* __restrict__ cursor) {
  int i = blockIdx.x * 256 + threadIdx.x;
  if (i < N) {
    int p = local_ps[i] + blk_sum[i >> 10];
    row_start[i] = p;
    cursor[i] = p;
  }
  if (i == 0) row_start[N] = Etot;
}

__global__ __launch_bounds__(256) void k_scatter(
    const int* __restrict__ ei, int E, int N,
    int* __restrict__ cursor, int* __restrict__ csr_src) {
  int e = blockIdx.x * 256 + threadIdx.x;
  if (e >= E + N) return;
  int s, d;
  if (e < E) { s = ei[e]; d = ei[E + e]; } else { s = e - E; d = s; }
  int pos = atomicAdd(&cursor[d], 1);
  csr_src[pos] = s;
}

// ---------------- DPP 16-lane butterfly sum (VALU-rate, no LDS pipe) --------
// quad_perm xor1 = 0xB1, xor2 = 0x4E; row_ror:4 = 0x124, row_ror:8 = 0x128.
#define DPP_ADD(p, ctrl)                                                     \
  p += __int_as_float(__builtin_amdgcn_update_dpp(                           \
      0, __float_as_int(p), ctrl, 0xF, 0xF, true))
#define RED16(p)  { DPP_ADD(p, 0xB1); DPP_ADD(p, 0x4E);                      \
                    DPP_ADD(p, 0x124); DPP_ADD(p, 0x128); }

#define BF4(dst, h)                                \
  dst.x = bf2f(h.x); dst.y = bf2f(h.y);            \
  dst.z = bf2f(h.z); dst.w = bf2f(h.w);

// p += sum_c t_c * (t_c>0 ? att_c : 0.2*att_c), t = xv + xri (att in log2e units)
#define DOTSEL(p, xv)                                              \
  { float t;                                                       \
    t = xv.x + xri.x; p = fmaf(t, t > 0.f ? a4.x : an4.x, p);      \
    t = xv.y + xri.y; p = fmaf(t, t > 0.f ? a4.y : an4.y, p);      \
    t = xv.z + xri.z; p = fmaf(t, t > 0.f ? a4.z : an4.z, p);      \
    t = xv.w + xri.w; p = fmaf(t, t > 0.f ? a4.w : an4.w, p); }

// ---------------- fused layer-1 ---------------------------------------------
__global__ __launch_bounds__(256) void k_fused1(
    const unsigned short* __restrict__ xlh, const float* xr,
    const int* __restrict__ row_start, const int* __restrict__ csr_src,
    const float* __restrict__ att, const float* __restrict__ bias,
    float* out, int N) {
  int tid = threadIdx.x, lane = tid & 63, w = tid >> 6;
  int i = blockIdx.x * 4 + w;
  if (i >= N) return;
  float4 xri = *(const float4*)(xr + (size_t)i * F1 + lane * 4);
  float4 a4  = *(const float4*)(att + lane * 4);
  a4.x *= LOG2E; a4.y *= LOG2E; a4.z *= LOG2E; a4.w *= LOG2E;
  float4 an4;
  an4.x = NEG * a4.x; an4.y = NEG * a4.y; an4.z = NEG * a4.z; an4.w = NEG * a4.w;
  float m = -1e30f, den = 0.f;
  float4 acc = {0.f, 0.f, 0.f, 0.f};
  int b = row_start[i], e = row_start[i + 1];
  int k = b;
  for (; k + 3 < e; k += 4) {
    int s0 = csr_src[k], s1 = csr_src[k + 1];
    int s2 = csr_src[k + 2], s3 = csr_src[k + 3];
    ushort4 h0 = *(const ushort4*)(xlh + (size_t)s0 * F1 + lane * 4);
    ushort4 h1 = *(const ushort4*)(xlh + (size_t)s1 * F1 + lane * 4);
    ushort4 h2 = *(const ushort4*)(xlh + (size_t)s2 * F1 + lane * 4);
    ushort4 h3 = *(const ushort4*)(xlh + (size_t)s3 * F1 + lane * 4);
    float4 x0, x1, x2, x3;
    BF4(x0, h0); BF4(x1, h1); BF4(x2, h2); BF4(x3, h3);
    float p0 = 0.f, p1 = 0.f, p2 = 0.f, p3 = 0.f;
    DOTSEL(p0, x0); DOTSEL(p1, x1); DOTSEL(p2, x2); DOTSEL(p3, x3);
    RED16(p0); RED16(p1); RED16(p2); RED16(p3);
    float mn = fmaxf(fmaxf(m, p0), fmaxf(fmaxf(p1, p2), p3));
    float cs = EXP2F(m - mn);
    float w0 = EXP2F(p0 - mn), w1 = EXP2F(p1 - mn);
    float w2 = EXP2F(p2 - mn), w3 = EXP2F(p3 - mn);
    den = den * cs + (w0 + w1) + (w2 + w3);
    acc.x = acc.x * cs + w0 * x0.x + w1 * x1.x + w2 * x2.x + w3 * x3.x;
    acc.y = acc.y * cs + w0 * x0.y + w1 * x1.y + w2 * x2.y + w3 * x3.y;
    acc.z = acc.z * cs + w0 * x0.z + w1 * x1.z + w2 * x2.z + w3 * x3.z;
    acc.w = acc.w * cs + w0 * x0.w + w1 * x1.w + w2 * x2.w + w3 * x3.w;
    m = mn;
  }
  for (; k < e; k++) {
    int s = csr_src[k];
    ushort4 hh = *(const ushort4*)(xlh + (size_t)s * F1 + lane * 4);
    float4 xs;
    BF4(xs, hh);
    float p = 0.f;
    DOTSEL(p, xs);
    RED16(p);
    float mn = fmaxf(m, p);
    float cs = EXP2F(m - mn);
    float wt = EXP2F(p - mn);
    den = den * cs + wt;
    acc.x = acc.x * cs + wt * xs.x;
    acc.y = acc.y * cs + wt * xs.y;
    acc.z = acc.z * cs + wt * xs.z;
    acc.w = acc.w * cs + wt * xs.w;
    m = mn;
  }
  float inv = 1.f / den;
  float4 bz = *(const float4*)(bias + lane * 4);
  float4 o;
  o.x = fmaxf(acc.x * inv + bz.x, 0.f);
  o.y = fmaxf(acc.y * inv + bz.y, 0.f);
  o.z = fmaxf(acc.z * inv + bz.z, 0.f);
  o.w = fmaxf(acc.w * inv + bz.w, 0.f);
  *(float4*)(out + (size_t)i * F1 + lane * 4) = o;
}

// ---------------- fused layer-2: 4x16-lane groups, 8 edges in flight --------
__global__ __launch_bounds__(256) void k_fused2(
    const unsigned short* __restrict__ xlh, const float* xr,
    const int* __restrict__ row_start, const int* __restrict__ csr_src,
    const float* __restrict__ att, const float* __restrict__ bias,
    float* out, int N) {
  int tid = threadIdx.x, lane = tid & 63, w = tid >> 6;
  int i = blockIdx.x * 4 + w;
  if (i >= N) return;
  int g = lane >> 4, l16 = lane & 15;
  float4 xri = *(const float4*)(xr + (size_t)i * OUTD + l16 * 4);
  float4 a4  = *(const float4*)(att + l16 * 4);
  a4.x *= LOG2E; a4.y *= LOG2E; a4.z *= LOG2E; a4.w *= LOG2E;
  float4 an4;
  an4.x = NEG * a4.x; an4.y = NEG * a4.y; an4.z = NEG * a4.z; an4.w = NEG * a4.w;
  float m = -1e30f, den = 0.f;
  float4 acc = {0.f, 0.f, 0.f, 0.f};
  int b = row_start[i], e = row_start[i + 1];
  for (int k = b; k < e; k += 8) {
    int ea = k + g, eb = k + 4 + g;
    int sa = csr_src[ea < e ? ea : (e - 1)];
    int sb = csr_src[eb < e ? eb : (e - 1)];
    ushort4 ha = *(const ushort4*)(xlh + (size_t)sa * OUTD + l16 * 4);
    ushort4 hb = *(const ushort4*)(xlh + (size_t)sb * OUTD + l16 * 4);
    float4 xa, xb;
    BF4(xa, ha); BF4(xb, hb);
    float pa = 0.f, pb = 0.f;
    DOTSEL(pa, xa); DOTSEL(pb, xb);
    RED16(pa); RED16(pb);
    if (ea >= e) pa = -1e30f;
    if (eb >= e) pb = -1e30f;
    float mn = fmaxf(m, fmaxf(pa, pb));
    float cs = EXP2F(m - mn);
    float wa = EXP2F(pa - mn), wb = EXP2F(pb - mn);
    den = den * cs + wa + wb;
    acc.x = acc.x * cs + wa * xa.x + wb * xb.x;
    acc.y = acc.y * cs + wa * xa.y + wb * xb.y;
    acc.z = acc.z * cs + wa * xa.z + wb * xb.z;
    acc.w = acc.w * cs + wa * xa.w + wb * xb.w;
    m = mn;
  }
  // merge the 4 groups' partial (m, den, acc) — once per node, shfl fine
#pragma unroll
  for (int off = 16; off <= 32; off <<= 1) {
    float om   = __shfl_xor(m, off, 64);
    float oden = __shfl_xor(den, off, 64);
    float4 oa;
    oa.x = __shfl_xor(acc.x, off, 64);
    oa.y = __shfl_xor(acc.y, off, 64);
    oa.z = __shfl_xor(acc.z, off, 64);
    oa.w = __shfl_xor(acc.w, off, 64);
    float mn = fmaxf(m, om);
    float cs = EXP2F(m - mn), co = EXP2F(om - mn);
    den = den * cs + oden * co;
    acc.x = acc.x * cs + oa.x * co;
    acc.y = acc.y * cs + oa.y * co;
    acc.z = acc.z * cs + oa.z * co;
    acc.w = acc.w * cs + oa.w * co;
    m = mn;
  }
  if (g == 0) {
    float inv = 1.f / den;
    float4 bz = *(const float4*)(bias + l16 * 4);
    float4 o;
    o.x = acc.x * inv + bz.x;
    o.y = acc.y * inv + bz.y;
    o.z = acc.z * inv + bz.z;
    o.w = acc.w * inv + bz.w;
    *(float4*)(out + (size_t)i * OUTD + l16 * 4) = o;
  }
}

// ---------------- decoder stage B ------------------------------------------
__global__ __launch_bounds__(256) void k_link(
    const float* __restrict__ u, const float* __restrict__ v,
    const int* __restrict__ eli, int EL,
    const float* __restrict__ bm1, const float* __restrict__ Wm2,
    const float* __restrict__ bm2, float* __restrict__ out) {
  int tid = threadIdx.x, lane = tid & 63, w = tid >> 6;
  int li = lane >> 4, c4 = (lane & 15) * 4;
  int l = (blockIdx.x * 4 + w) * 4 + li;
  if (l >= EL) return;
  int a = eli[l], b = eli[EL + l];
  float4 uu = *(const float4*)(u + (size_t)a * OUTD + c4);
  float4 vv = *(const float4*)(v + (size_t)b * OUTD + c4);
  float4 bb = *(const float4*)(bm1 + c4);
  float4 ww = *(const float4*)(Wm2 + c4);
  float p = fmaxf(uu.x + vv.x + bb.x, 0.f) * ww.x
          + fmaxf(uu.y + vv.y + bb.y, 0.f) * ww.y
          + fmaxf(uu.z + vv.z + bb.z, 0.f) * ww.z
          + fmaxf(uu.w + vv.w + bb.w, 0.f) * ww.w;
  RED16(p);
  if ((lane & 15) == 0) out[l] = p + bm2[0];
}

extern "C" void kernel_launch(void* const* d_in, const int* in_sizes, int n_in,
                              void* d_out, int out_size, void* d_ws, size_t ws_size,
                              hipStream_t stream) {
  const float* x     = (const float*)d_in[0];
  const int*   ei    = (const int*)d_in[1];
  const int*   eli   = (const int*)d_in[2];
  const float* W1l   = (const float*)d_in[3];
  const float* b1l   = (const float*)d_in[4];
  const float* W1r   = (const float*)d_in[5];
  const float* b1r   = (const float*)d_in[6];
  const float* att1  = (const float*)d_in[7];
  const float* bias1 = (const float*)d_in[8];
  const float* W2l   = (const float*)d_in[9];
  const float* b2l   = (const float*)d_in[10];
  const float* W2r   = (const float*)d_in[11];
  const float* b2r   = (const float*)d_in[12];
  const float* att2  = (const float*)d_in[13];
  const float* bias2 = (const float*)d_in[14];
  const float* Wm1   = (const float*)d_in[15];
  const float* bm1   = (const float*)d_in[16];
  const float* Wm2   = (const float*)d_in[17];
  const float* bm2   = (const float*)d_in[18];

  int N = in_sizes[0] / IN_DIM;   // 50000
  int E = in_sizes[1] / 2;        // 800000
  int EL = in_sizes[2] / 2;       // 200000
  int Etot = E + N;

  char* ws = (char*)d_ws;
  unsigned short* xl1h = (unsigned short*)(ws);
  unsigned short* Wt   = (unsigned short*)(ws + 38400000);
  unsigned short* Wt2  = (unsigned short*)(ws + 39000000);
  unsigned short* Wuv  = (unsigned short*)(ws + 39200000);
  float* bufB      = (float*)(ws + 51200000);
  int*   row_start = (int*)(ws + 102400000);
  int*   cursor    = (int*)(ws + 102700000);
  int*   csr_src   = (int*)(ws + 103000000);
  int*   blk_sum   = (int*)(ws + 103000000 + (size_t)Etot * 4 + 256);
  unsigned short* xl2h = (unsigned short*)(ws);
  float* xr2       = (float*)(ws + 12800000);
  float* u_buf     = (float*)(ws + 51200000);
  float* v_buf     = (float*)(ws + 64000000);

  int nblk = (N + 1023) / 1024;   // 49 (<=64 required by k_scan2)

  // ---- weight conversions + CSR build ----
  (void)hipMemsetAsync(cursor, 0, (size_t)N * 4, stream);
  k_cvt_w<<<(512 * IN_DIM + 255) / 256, 256, 0, stream>>>(W1l, W1r, Wt);
  k_cvt_w2<<<(128 * F1 + 255) / 256, 256, 0, stream>>>(W2l, W2r, Wt2);
  k_cvt_wuv<<<(128 * OUTD + 255) / 256, 256, 0, stream>>>(Wm1, Wuv);
  {
    dim3 g1((N + 63) / 64, 4);
    k_gemm1_mfma<<<g1, 256, 0, stream>>>(x, Wt, b1l, b1r, xl1h, bufB, N);
  }
  k_hist<<<(Etot + 255) / 256, 256, 0, stream>>>(ei, E, N, cursor);
  k_scan1<<<nblk, 256, 0, stream>>>(cursor, N, blk_sum);
  k_scan2<<<1, 64, 0, stream>>>(blk_sum, nblk);
  k_scan3<<<(N + 255) / 256, 256, 0, stream>>>(cursor, blk_sum, N, Etot,
                                               row_start, cursor);
  k_scatter<<<(Etot + 255) / 256, 256, 0, stream>>>(ei, E, N, cursor, csr_src);

  // ---- layer 1 (fused) ----
  k_fused1<<<(N + 3) / 4, 256, 0, stream>>>(xl1h, bufB, row_start, csr_src,
                                            att1, bias1, bufB, N);
  // ---- layer 2 ----
  k_gemm2_mfma<<<(N + 63) / 64, 256, 0, stream>>>(bufB, Wt2, b2l, b2r, xl2h, xr2, N);
  k_fused2<<<(N + 3) / 4, 256, 0, stream>>>(xl2h, xr2, row_start, csr_src,
                                            att2, bias2, xr2, N);
  // ---- decoder ----
  {
    dim3 g3((N + 63) / 64, 2);
    k_uv_mfma<<<g3, 256, 0, stream>>>(xr2, Wuv, u_buf, v_buf, N);
  }
  k_link<<<(EL + 15) / 16, 256, 0, stream>>>(u_buf, v_buf, eli, EL,
                                             bm1, Wm2, bm2, (float*)d_out);
}

// Round 15
// 342.566 us; speedup vs baseline: 5.4930x; 1.0016x over previous
//
#include <hip/hip_runtime.h>
#include <hip/hip_bf16.h>

#define IN_DIM 128
#define HID    64
#define NH     4
#define F1     256   // NH*HID
#define OUTD   64
#define NEG    0.2f
#define LOG2E  1.44269504088896f

#define EXP2F(x) __builtin_amdgcn_exp2f(x)

typedef __attribute__((ext_vector_type(8))) short bf16x8;
typedef __attribute__((ext_vector_type(4))) float f32x4;

__device__ __forceinline__ float bf2f(unsigned short h) {
  return __uint_as_float((unsigned)h << 16);
}
__device__ __forceinline__ unsigned short f2bf(float f) {
  unsigned u = __float_as_uint(f);
  u += 0x7fffu + ((u >> 16) & 1u);   // RTNE
  return (unsigned short)(u >> 16);
}
__device__ __forceinline__ bf16x8 f2bf8(const float* p) {
  float4 lo = *(const float4*)p;
  float4 hi = *(const float4*)(p + 4);
  bf16x8 r;
  r[0] = (short)f2bf(lo.x); r[1] = (short)f2bf(lo.y);
  r[2] = (short)f2bf(lo.z); r[3] = (short)f2bf(lo.w);
  r[4] = (short)f2bf(hi.x); r[5] = (short)f2bf(hi.y);
  r[6] = (short)f2bf(hi.z); r[7] = (short)f2bf(hi.w);
  return r;
}

// ---------------- weight conversions for MFMA GEMMs -------------------------
__global__ __launch_bounds__(256) void k_cvt_w(
    const float* __restrict__ Wl, const float* __restrict__ Wr,
    unsigned short* __restrict__ Wt) {
  int idx = blockIdx.x * 256 + threadIdx.x;   // 512*128 total
  if (idx >= 512 * IN_DIM) return;
  int c = idx >> 7, k = idx & 127;
  float v = (c < F1) ? Wl[k * F1 + c] : Wr[k * F1 + (c - F1)];
  Wt[idx] = f2bf(v);
}

__global__ __launch_bounds__(256) void k_cvt_w2(
    const float* __restrict__ Wl, const float* __restrict__ Wr,
    unsigned short* __restrict__ Wt2) {
  int idx = blockIdx.x * 256 + threadIdx.x;   // 128*256 total
  if (idx >= 128 * F1) return;
  int c = idx >> 8, k = idx & 255;
  float v = (c < OUTD) ? Wl[k * OUTD + c] : Wr[k * OUTD + (c - OUTD)];
  Wt2[idx] = f2bf(v);
}

__global__ __launch_bounds__(256) void k_cvt_wuv(
    const float* __restrict__ Wm1, unsigned short* __restrict__ Wuv) {
  int idx = blockIdx.x * 256 + threadIdx.x;   // 128*64 total
  if (idx >= 128 * OUTD) return;
  int c = idx >> 6, k = idx & 63;
  float v = (c < OUTD) ? Wm1[k * OUTD + c] : Wm1[(64 + k) * OUTD + (c - OUTD)];
  Wuv[idx] = f2bf(v);
}

// ---------------- layer-1 GEMM via MFMA (swapped operands) ------------------
// blockIdx.y in [0,2): y=0 -> xlh cols 0..255, y=1 -> xr cols 0..255.
__global__ __launch_bounds__(256) void k_gemm1_mfma(
    const float* __restrict__ x, const unsigned short* __restrict__ Wt,
    const float* __restrict__ bl, const float* __restrict__ br,
    unsigned short* __restrict__ xlh, float* __restrict__ xr, int N) {
  int tid = threadIdx.x, lane = tid & 63, w = tid >> 6;
  int node0 = blockIdx.x * 64 + w * 16;
  int colbase = blockIdx.y * 256;
  int l16 = lane & 15, khi = lane >> 4;
  int koff = khi * 8;
  int arow = node0 + l16; if (arow >= N) arow = N - 1;
  const float* ap = x + (size_t)arow * IN_DIM + koff;
  bf16x8 b0 = f2bf8(ap);
  bf16x8 b1 = f2bf8(ap + 32);
  bf16x8 b2 = f2bf8(ap + 64);
  bf16x8 b3 = f2bf8(ap + 96);
  int node = node0 + l16;
  bool nok = node < N;
#pragma unroll
  for (int ct = 0; ct < 16; ct++) {
    int wrow = colbase + ct * 16 + l16;
    const unsigned short* wp = Wt + (size_t)wrow * IN_DIM + koff;
    f32x4 acc = {0.f, 0.f, 0.f, 0.f};
    acc = __builtin_amdgcn_mfma_f32_16x16x32_bf16(*(const bf16x8*)(wp), b0, acc, 0, 0, 0);
    acc = __builtin_amdgcn_mfma_f32_16x16x32_bf16(*(const bf16x8*)(wp + 32), b1, acc, 0, 0, 0);
    acc = __builtin_amdgcn_mfma_f32_16x16x32_bf16(*(const bf16x8*)(wp + 64), b2, acc, 0, 0, 0);
    acc = __builtin_amdgcn_mfma_f32_16x16x32_bf16(*(const bf16x8*)(wp + 96), b3, acc, 0, 0, 0);
    int cbase = colbase + ct * 16 + khi * 4;
    if (cbase < F1) {
      float4 bb = *(const float4*)(bl + cbase);
      if (nok) {
        ushort4 o;
        o.x = f2bf(acc[0] + bb.x); o.y = f2bf(acc[1] + bb.y);
        o.z = f2bf(acc[2] + bb.z); o.w = f2bf(acc[3] + bb.w);
        *(ushort4*)(xlh + (size_t)node * F1 + cbase) = o;
      }
    } else {
      float4 bb = *(const float4*)(br + cbase - F1);
      if (nok) {
        float4 o;
        o.x = acc[0] + bb.x; o.y = acc[1] + bb.y;
        o.z = acc[2] + bb.z; o.w = acc[3] + bb.w;
        *(float4*)(xr + (size_t)node * F1 + (cbase - F1)) = o;
      }
    }
  }
}

// ---------------- layer-2 GEMM via MFMA (swapped), halves merged ------------
__global__ __launch_bounds__(256) void k_gemm2_mfma(
    const float* __restrict__ z, const unsigned short* __restrict__ Wt2,
    const float* __restrict__ bl, const float* __restrict__ br,
    unsigned short* __restrict__ xl2h, float* __restrict__ xr2, int N) {
  int tid = threadIdx.x, lane = tid & 63, w = tid >> 6;
  int node0 = blockIdx.x * 64 + w * 16;
  int l16 = lane & 15, khi = lane >> 4;
  int koff = khi * 8;
  int arow = node0 + l16; if (arow >= N) arow = N - 1;
  const float* zp = z + (size_t)arow * F1 + koff;
  bf16x8 bfr[8];
#pragma unroll
  for (int t = 0; t < 8; t++) bfr[t] = f2bf8(zp + 32 * t);
  int node = node0 + l16;
  bool nok = node < N;
#pragma unroll
  for (int half = 0; half < 2; half++) {
    const unsigned short* Wbase = Wt2 + (size_t)half * OUTD * F1;
#pragma unroll
    for (int ct = 0; ct < 4; ct++) {
      int wrow = ct * 16 + l16;
      const unsigned short* wp = Wbase + (size_t)wrow * F1 + koff;
      f32x4 acc = {0.f, 0.f, 0.f, 0.f};
#pragma unroll
      for (int t = 0; t < 8; t++)
        acc = __builtin_amdgcn_mfma_f32_16x16x32_bf16(
            *(const bf16x8*)(wp + 32 * t), bfr[t], acc, 0, 0, 0);
      int cbase = ct * 16 + khi * 4;
      if (half == 0) {
        float4 bb = *(const float4*)(bl + cbase);
        if (nok) {
          ushort4 o;
          o.x = f2bf(acc[0] + bb.x); o.y = f2bf(acc[1] + bb.y);
          o.z = f2bf(acc[2] + bb.z); o.w = f2bf(acc[3] + bb.w);
          *(ushort4*)(xl2h + (size_t)node * OUTD + cbase) = o;
        }
      } else {
        float4 bb = *(const float4*)(br + cbase);
        if (nok) {
          float4 o;
          o.x = acc[0] + bb.x; o.y = acc[1] + bb.y;
          o.z = acc[2] + bb.z; o.w = acc[3] + bb.w;
          *(float4*)(xr2 + (size_t)node * OUTD + cbase) = o;
        }
      }
    }
  }
}

// ---------------- decoder uv GEMM via MFMA (swapped) ------------------------
__global__ __launch_bounds__(256) void k_uv_mfma(
    const float* __restrict__ z2, const unsigned short* __restrict__ Wuv,
    float* __restrict__ u, float* __restrict__ v, int N) {
  int tid = threadIdx.x, lane = tid & 63, w = tid >> 6;
  int node0 = blockIdx.x * 64 + w * 16;
  int half = blockIdx.y;
  int l16 = lane & 15, khi = lane >> 4;
  int koff = khi * 8;
  int arow = node0 + l16; if (arow >= N) arow = N - 1;
  const float* zp = z2 + (size_t)arow * OUTD + koff;
  bf16x8 b0 = f2bf8(zp);
  bf16x8 b1 = f2bf8(zp + 32);
  const unsigned short* Wbase = Wuv + (size_t)half * OUTD * OUTD;
  float* dst = half ? v : u;
  int node = node0 + l16;
  bool nok = node < N;
#pragma unroll
  for (int ct = 0; ct < 4; ct++) {
    int wrow = ct * 16 + l16;
    const unsigned short* wp = Wbase + (size_t)wrow * OUTD + koff;
    f32x4 acc = {0.f, 0.f, 0.f, 0.f};
    acc = __builtin_amdgcn_mfma_f32_16x16x32_bf16(*(const bf16x8*)(wp), b0, acc, 0, 0, 0);
    acc = __builtin_amdgcn_mfma_f32_16x16x32_bf16(*(const bf16x8*)(wp + 32), b1, acc, 0, 0, 0);
    int cbase = ct * 16 + khi * 4;
    if (nok) {
      float4 o;
      o.x = acc[0]; o.y = acc[1]; o.z = acc[2]; o.w = acc[3];
      *(float4*)(dst + (size_t)node * OUTD + cbase) = o;
    }
  }
}

// ---------------- CSR build: histogram -> 3-stage scan -> scatter ----------
__global__ __launch_bounds__(256) void k_hist(
    const int* __restrict__ ei, int E, int N, int* __restrict__ cnt) {
  int e = blockIdx.x * 256 + threadIdx.x;
  if (e >= E + N) return;
  int d = (e < E) ? ei[E + e] : (e - E);
  atomicAdd(&cnt[d], 1);
}

__global__ __launch_bounds__(256) void k_scan1(
    int* __restrict__ cnt, int N, int* __restrict__ blk_sum) {
  int t = threadIdx.x, lane = t & 63, wid = t >> 6;
  int base = blockIdx.x * 1024 + t * 4;
  int4 v = {0, 0, 0, 0};
  if (base + 3 < N) {
    v = *(const int4*)(cnt + base);
  } else {
    if (base + 0 < N) v.x = cnt[base + 0];
    if (base + 1 < N) v.y = cnt[base + 1];
    if (base + 2 < N) v.z = cnt[base + 2];
    if (base + 3 < N) v.w = cnt[base + 3];
  }
  int s = v.x + v.y + v.z + v.w;
  int inc = s;
#pragma unroll
  for (int off = 1; off < 64; off <<= 1) {
    int u = __shfl_up(inc, off, 64);
    if (lane >= off) inc += u;
  }
  __shared__ int wsum[4];
  if (lane == 63) wsum[wid] = inc;
  __syncthreads();
  int wofs = 0;
#pragma unroll
  for (int q = 0; q < 4; q++) if (q < wid) wofs += wsum[q];
  int excl = wofs + inc - s;
  int4 o;
  o.x = excl; o.y = excl + v.x; o.z = o.y + v.y; o.w = o.z + v.z;
  if (base + 3 < N) {
    *(int4*)(cnt + base) = o;
  } else {
    if (base + 0 < N) cnt[base + 0] = o.x;
    if (base + 1 < N) cnt[base + 1] = o.y;
    if (base + 2 < N) cnt[base + 2] = o.z;
    if (base + 3 < N) cnt[base + 3] = o.w;
  }
  if (t == 255) blk_sum[blockIdx.x] = wofs + inc;
}

__global__ void k_scan2(int* __restrict__ blk, int nblk) {
  int lane = threadIdx.x;
  int v = (lane < nblk) ? blk[lane] : 0;
  int inc = v;
#pragma unroll
  for (int off = 1; off < 64; off <<= 1) {
    int u = __shfl_up(inc, off, 64);
    if (lane >= off) inc += u;
  }
  if (lane < nblk) blk[lane] = inc - v;
}

__global__ __launch_bounds__(256) void k_scan3(
    const int* __restrict__ local_ps, const int* __restrict__ blk_sum,
    int N, int Etot, int* __restrict__ row_start, int* __restrict__ cursor) {
  int i = blockIdx.x * 256 + threadIdx.x;
  if (i < N) {
    int p = local_ps[i] + blk_sum[i >> 10];
    row_start[i] = p;
    cursor[i] = p;
  }
  if (i == 0) row_start[N] = Etot;
}

__global__ __launch_bounds__(256) void k_scatter(
    const int* __restrict__ ei, int E, int N,
    int* __restrict__ cursor, int* __restrict__ csr_src) {
  int e = blockIdx.x * 256 + threadIdx.x;
  if (e >= E + N) return;
  int s, d;
  if (e < E) { s = ei[e]; d = ei[E + e]; } else { s = e - E; d = s; }
  int pos = atomicAdd(&cursor[d], 1);
  csr_src[pos] = s;
}

// ---------------- DPP 16-lane butterfly sum (VALU-rate, no LDS pipe) --------
#define DPP_ADD(p, ctrl)                                                     \
  p += __int_as_float(__builtin_amdgcn_update_dpp(                           \
      0, __float_as_int(p), ctrl, 0xF, 0xF, true))
#define RED16(p)  { DPP_ADD(p, 0xB1); DPP_ADD(p, 0x4E);                      \
                    DPP_ADD(p, 0x124); DPP_ADD(p, 0x128); }

#define BF4(dst, h)                                \
  dst.x = bf2f(h.x); dst.y = bf2f(h.y);            \
  dst.z = bf2f(h.z); dst.w = bf2f(h.w);

// p += sum_c t_c * (t_c>0 ? att_c : 0.2*att_c), t = xv + xri (att in log2e units)
#define DOTSEL(p, xv)                                              \
  { float t;                                                       \
    t = xv.x + xri.x; p = fmaf(t, t > 0.f ? a4.x : an4.x, p);      \
    t = xv.y + xri.y; p = fmaf(t, t > 0.f ? a4.y : an4.y, p);      \
    t = xv.z + xri.z; p = fmaf(t, t > 0.f ? a4.z : an4.z, p);      \
    t = xv.w + xri.w; p = fmaf(t, t > 0.f ? a4.w : an4.w, p); }

// ---------------- fused layer-1 (no-max softmax: shift-invariant) -----------
__global__ __launch_bounds__(256) void k_fused1(
    const unsigned short* __restrict__ xlh, const float* xr,
    const int* __restrict__ row_start, const int* __restrict__ csr_src,
    const float* __restrict__ att, const float* __restrict__ bias,
    float* out, int N) {
  int tid = threadIdx.x, lane = tid & 63, w = tid >> 6;
  int i = blockIdx.x * 4 + w;
  if (i >= N) return;
  float4 xri = *(const float4*)(xr + (size_t)i * F1 + lane * 4);
  float4 a4  = *(const float4*)(att + lane * 4);
  a4.x *= LOG2E; a4.y *= LOG2E; a4.z *= LOG2E; a4.w *= LOG2E;
  float4 an4;
  an4.x = NEG * a4.x; an4.y = NEG * a4.y; an4.z = NEG * a4.z; an4.w = NEG * a4.w;
  float den = 0.f;
  float4 acc = {0.f, 0.f, 0.f, 0.f};
  int b = row_start[i], e = row_start[i + 1];
  int k = b;
  for (; k + 3 < e; k += 4) {
    int s0 = csr_src[k], s1 = csr_src[k + 1];
    int s2 = csr_src[k + 2], s3 = csr_src[k + 3];
    ushort4 h0 = *(const ushort4*)(xlh + (size_t)s0 * F1 + lane * 4);
    ushort4 h1 = *(const ushort4*)(xlh + (size_t)s1 * F1 + lane * 4);
    ushort4 h2 = *(const ushort4*)(xlh + (size_t)s2 * F1 + lane * 4);
    ushort4 h3 = *(const ushort4*)(xlh + (size_t)s3 * F1 + lane * 4);
    float4 x0, x1, x2, x3;
    BF4(x0, h0); BF4(x1, h1); BF4(x2, h2); BF4(x3, h3);
    float p0 = 0.f, p1 = 0.f, p2 = 0.f, p3 = 0.f;
    DOTSEL(p0, x0); DOTSEL(p1, x1); DOTSEL(p2, x2); DOTSEL(p3, x3);
    RED16(p0); RED16(p1); RED16(p2); RED16(p3);
    float w0 = EXP2F(p0), w1 = EXP2F(p1);
    float w2 = EXP2F(p2), w3 = EXP2F(p3);
    den += (w0 + w1) + (w2 + w3);
    acc.x += w0 * x0.x + w1 * x1.x + w2 * x2.x + w3 * x3.x;
    acc.y += w0 * x0.y + w1 * x1.y + w2 * x2.y + w3 * x3.y;
    acc.z += w0 * x0.z + w1 * x1.z + w2 * x2.z + w3 * x3.z;
    acc.w += w0 * x0.w + w1 * x1.w + w2 * x2.w + w3 * x3.w;
  }
  for (; k < e; k++) {
    int s = csr_src[k];
    ushort4 hh = *(const ushort4*)(xlh + (size_t)s * F1 + lane * 4);
    float4 xs;
    BF4(xs, hh);
    float p = 0.f;
    DOTSEL(p, xs);
    RED16(p);
    float wt = EXP2F(p);
    den += wt;
    acc.x += wt * xs.x;
    acc.y += wt * xs.y;
    acc.z += wt * xs.z;
    acc.w += wt * xs.w;
  }
  float inv = 1.f / den;
  float4 bz = *(const float4*)(bias + lane * 4);
  float4 o;
  o.x = fmaxf(acc.x * inv + bz.x, 0.f);
  o.y = fmaxf(acc.y * inv + bz.y, 0.f);
  o.z = fmaxf(acc.z * inv + bz.z, 0.f);
  o.w = fmaxf(acc.w * inv + bz.w, 0.f);
  *(float4*)(out + (size_t)i * F1 + lane * 4) = o;
}

// ---------------- fused layer-2: 4x16-lane groups, no-max softmax ----------
__global__ __launch_bounds__(256) void k_fused2(
    const unsigned short* __restrict__ xlh, const float* xr,
    const int* __restrict__ row_start, const int* __restrict__ csr_src,
    const float* __restrict__ att, const float* __restrict__ bias,
    float* out, int N) {
  int tid = threadIdx.x, lane = tid & 63, w = tid >> 6;
  int i = blockIdx.x * 4 + w;
  if (i >= N) return;
  int g = lane >> 4, l16 = lane & 15;
  float4 xri = *(const float4*)(xr + (size_t)i * OUTD + l16 * 4);
  float4 a4  = *(const float4*)(att + l16 * 4);
  a4.x *= LOG2E; a4.y *= LOG2E; a4.z *= LOG2E; a4.w *= LOG2E;
  float4 an4;
  an4.x = NEG * a4.x; an4.y = NEG * a4.y; an4.z = NEG * a4.z; an4.w = NEG * a4.w;
  float den = 0.f;
  float4 acc = {0.f, 0.f, 0.f, 0.f};
  int b = row_start[i], e = row_start[i + 1];
  for (int k = b; k < e; k += 8) {
    int ea = k + g, eb = k + 4 + g;
    int sa = csr_src[ea < e ? ea : (e - 1)];
    int sb = csr_src[eb < e ? eb : (e - 1)];
    ushort4 ha = *(const ushort4*)(xlh + (size_t)sa * OUTD + l16 * 4);
    ushort4 hb = *(const ushort4*)(xlh + (size_t)sb * OUTD + l16 * 4);
    float4 xa, xb;
    BF4(xa, ha); BF4(xb, hb);
    float pa = 0.f, pb = 0.f;
    DOTSEL(pa, xa); DOTSEL(pb, xb);
    RED16(pa); RED16(pb);
    float wa = (ea < e) ? EXP2F(pa) : 0.f;
    float wb = (eb < e) ? EXP2F(pb) : 0.f;
    den += wa + wb;
    acc.x += wa * xa.x + wb * xb.x;
    acc.y += wa * xa.y + wb * xb.y;
    acc.z += wa * xa.z + wb * xb.z;
    acc.w += wa * xa.w + wb * xb.w;
  }
  // merge the 4 groups' partials (plain sums now)
#pragma unroll
  for (int off = 16; off <= 32; off <<= 1) {
    den   += __shfl_xor(den, off, 64);
    acc.x += __shfl_xor(acc.x, off, 64);
    acc.y += __shfl_xor(acc.y, off, 64);
    acc.z += __shfl_xor(acc.z, off, 64);
    acc.w += __shfl_xor(acc.w, off, 64);
  }
  if (g == 0) {
    float inv = 1.f / den;
    float4 bz = *(const float4*)(bias + l16 * 4);
    float4 o;
    o.x = acc.x * inv + bz.x;
    o.y = acc.y * inv + bz.y;
    o.z = acc.z * inv + bz.z;
    o.w = acc.w * inv + bz.w;
    *(float4*)(out + (size_t)i * OUTD + l16 * 4) = o;
  }
}

// ---------------- decoder stage B ------------------------------------------
__global__ __launch_bounds__(256) void k_link(
    const float* __restrict__ u, const float* __restrict__ v,
    const int* __restrict__ eli, int EL,
    const float* __restrict__ bm1, const float* __restrict__ Wm2,
    const float* __restrict__ bm2, float* __restrict__ out) {
  int tid = threadIdx.x, lane = tid & 63, w = tid >> 6;
  int li = lane >> 4, c4 = (lane & 15) * 4;
  int l = (blockIdx.x * 4 + w) * 4 + li;
  if (l >= EL) return;
  int a = eli[l], b = eli[EL + l];
  float4 uu = *(const float4*)(u + (size_t)a * OUTD + c4);
  float4 vv = *(const float4*)(v + (size_t)b * OUTD + c4);
  float4 bb = *(const float4*)(bm1 + c4);
  float4 ww = *(const float4*)(Wm2 + c4);
  float p = fmaxf(uu.x + vv.x + bb.x, 0.f) * ww.x
          + fmaxf(uu.y + vv.y + bb.y, 0.f) * ww.y
          + fmaxf(uu.z + vv.z + bb.z, 0.f) * ww.z
          + fmaxf(uu.w + vv.w + bb.w, 0.f) * ww.w;
  RED16(p);
  if ((lane & 15) == 0) out[l] = p + bm2[0];
}

extern "C" void kernel_launch(void* const* d_in, const int* in_sizes, int n_in,
                              void* d_out, int out_size, void* d_ws, size_t ws_size,
                              hipStream_t stream) {
  const float* x     = (const float*)d_in[0];
  const int*   ei    = (const int*)d_in[1];
  const int*   eli   = (const int*)d_in[2];
  const float* W1l   = (const float*)d_in[3];
  const float* b1l   = (const float*)d_in[4];
  const float* W1r   = (const float*)d_in[5];
  const float* b1r   = (const float*)d_in[6];
  const float* att1  = (const float*)d_in[7];
  const float* bias1 = (const float*)d_in[8];
  const float* W2l   = (const float*)d_in[9];
  const float* b2l   = (const float*)d_in[10];
  const float* W2r   = (const float*)d_in[11];
  const float* b2r   = (const float*)d_in[12];
  const float* att2  = (const float*)d_in[13];
  const float* bias2 = (const float*)d_in[14];
  const float* Wm1   = (const float*)d_in[15];
  const float* bm1   = (const float*)d_in[16];
  const float* Wm2   = (const float*)d_in[17];
  const float* bm2   = (const float*)d_in[18];

  int N = in_sizes[0] / IN_DIM;   // 50000
  int E = in_sizes[1] / 2;        // 800000
  int EL = in_sizes[2] / 2;       // 200000
  int Etot = E + N;

  char* ws = (char*)d_ws;
  unsigned short* xl1h = (unsigned short*)(ws);
  unsigned short* Wt   = (unsigned short*)(ws + 38400000);
  unsigned short* Wt2  = (unsigned short*)(ws + 39000000);
  unsigned short* Wuv  = (unsigned short*)(ws + 39200000);
  float* bufB      = (float*)(ws + 51200000);
  int*   row_start = (int*)(ws + 102400000);
  int*   cursor    = (int*)(ws + 102700000);
  int*   csr_src   = (int*)(ws + 103000000);
  int*   blk_sum   = (int*)(ws + 103000000 + (size_t)Etot * 4 + 256);
  unsigned short* xl2h = (unsigned short*)(ws);
  float* xr2       = (float*)(ws + 12800000);
  float* u_buf     = (float*)(ws + 51200000);
  float* v_buf     = (float*)(ws + 64000000);

  int nblk = (N + 1023) / 1024;   // 49 (<=64 required by k_scan2)

  // ---- weight conversions + CSR build ----
  (void)hipMemsetAsync(cursor, 0, (size_t)N * 4, stream);
  k_cvt_w<<<(512 * IN_DIM + 255) / 256, 256, 0, stream>>>(W1l, W1r, Wt);
  k_cvt_w2<<<(128 * F1 + 255) / 256, 256, 0, stream>>>(W2l, W2r, Wt2);
  k_cvt_wuv<<<(128 * OUTD + 255) / 256, 256, 0, stream>>>(Wm1, Wuv);
  {
    dim3 g1((N + 63) / 64, 2);
    k_gemm1_mfma<<<g1, 256, 0, stream>>>(x, Wt, b1l, b1r, xl1h, bufB, N);
  }
  k_hist<<<(Etot + 255) / 256, 256, 0, stream>>>(ei, E, N, cursor);
  k_scan1<<<nblk, 256, 0, stream>>>(cursor, N, blk_sum);
  k_scan2<<<1, 64, 0, stream>>>(blk_sum, nblk);
  k_scan3<<<(N + 255) / 256, 256, 0, stream>>>(cursor, blk_sum, N, Etot,
                                               row_start, cursor);
  k_scatter<<<(Etot + 255) / 256, 256, 0, stream>>>(ei, E, N, cursor, csr_src);

  // ---- layer 1 (fused) ----
  k_fused1<<<(N + 3) / 4, 256, 0, stream>>>(xl1h, bufB, row_start, csr_src,
                                            att1, bias1, bufB, N);
  // ---- layer 2 ----
  k_gemm2_mfma<<<(N + 63) / 64, 256, 0, stream>>>(bufB, Wt2, b2l, b2r, xl2h, xr2, N);
  k_fused2<<<(N + 3) / 4, 256, 0, stream>>>(xl2h, xr2, row_start, csr_src,
                                            att2, bias2, xr2, N);
  // ---- decoder ----
  {
    dim3 g3((N + 63) / 64, 2);
    k_uv_mfma<<<g3, 256, 0, stream>>>(xr2, Wuv, u_buf, v_buf, N);
  }
  k_link<<<(EL + 15) / 16, 256, 0, stream>>>(u_buf, v_buf, eli, EL,
                                             bm1, Wm2, bm2, (float*)d_out);
}